// Round 1
// baseline (922.778 us; speedup 1.0000x reference)
//
#include <hip/hip_runtime.h>
#include <math.h>

// ---------------------------------------------------------------------------
// DeepONet with GAT branches, gather-based (CSR) attention aggregation.
// N nodes, E directed edges, B=64 graphs, fp32 throughout.
// ---------------------------------------------------------------------------

__device__ __forceinline__ float leaky02(float x){ return x >= 0.f ? x : 0.2f * x; }
__device__ __forceinline__ float elu1(float x){ return x > 0.f ? x : expm1f(x); }

// xl1 = x @ W1  [N,128]; es1/ed1 = per-head attention logits [N,2]
__global__ void feat1_kernel(const float* __restrict__ x, const float* __restrict__ W1,
                             const float* __restrict__ a1s, const float* __restrict__ a1d,
                             float* __restrict__ xl1, float* __restrict__ es1,
                             float* __restrict__ ed1, int N){
    int n = (blockIdx.x << 2) + (threadIdx.x >> 6);
    int lane = threadIdx.x & 63;
    if (n >= N) return;
    float2 xv = ((const float2*)x)[n];                 // x[n,0], x[n,1]
    float2 w0 = ((const float2*)W1)[lane];             // W1[0, 2l..2l+1]
    float2 w1 = ((const float2*)(W1 + 128))[lane];     // W1[1, 2l..2l+1]
    float2 xl;
    xl.x = xv.x * w0.x + xv.y * w1.x;
    xl.y = xv.x * w0.y + xv.y * w1.y;
    ((float2*)xl1)[(size_t)n * 64 + lane] = xl;
    float2 as = ((const float2*)a1s)[lane];
    float2 ad = ((const float2*)a1d)[lane];
    float ps = xl.x * as.x + xl.y * as.y;
    float pd = xl.x * ad.x + xl.y * ad.y;
    #pragma unroll
    for (int m = 16; m >= 1; m >>= 1){ ps += __shfl_xor(ps, m, 64); pd += __shfl_xor(pd, m, 64); }
    if ((lane & 31) == 0){
        int h = lane >> 5;                              // lanes 0-31: head0, 32-63: head1
        es1[n * 2 + h] = ps;
        ed1[n * 2 + h] = pd;
    }
}

__global__ void hist_kernel(const int* __restrict__ dst, int* __restrict__ cnt, int E){
    int t = blockIdx.x * blockDim.x + threadIdx.x;
    if (t < E) atomicAdd(&cnt[dst[t]], 1);
}

// single-block exclusive scan, 8 elements/thread
__global__ void scan_kernel(const int* __restrict__ cnt, int* __restrict__ rs,
                            int* __restrict__ cur, int n){
    __shared__ int sm[1024];
    __shared__ int carry;
    int t = threadIdx.x;
    if (t == 0) carry = 0;
    __syncthreads();
    for (int base = 0; base < n; base += 8192){
        int idx0 = base + t * 8;
        int v[8]; int s = 0;
        #pragma unroll
        for (int i = 0; i < 8; ++i){ int id = idx0 + i; v[i] = (id < n) ? cnt[id] : 0; s += v[i]; }
        sm[t] = s;
        __syncthreads();
        for (int off = 1; off < 1024; off <<= 1){
            int add = (t >= off) ? sm[t - off] : 0;
            __syncthreads();
            sm[t] += add;
            __syncthreads();
        }
        int run = sm[t] - s + carry;
        #pragma unroll
        for (int i = 0; i < 8; ++i){ int id = idx0 + i; if (id < n){ rs[id] = run; cur[id] = run; } run += v[i]; }
        __syncthreads();
        if (t == 1023) carry += sm[1023];
        __syncthreads();
    }
    if (t == 0) rs[n] = carry;
}

__global__ void fill_kernel(const int* __restrict__ src, const int* __restrict__ dst,
                            int* __restrict__ cur, int* __restrict__ csr, int E){
    int t = blockIdx.x * blockDim.x + threadIdx.x;
    if (t < E){
        int d = dst[t];
        int pos = atomicAdd(&cur[d], 1);
        csr[pos] = src[t];
    }
}

// GAT layer-1 aggregation (H=2, C=64): one wave per node, float2 channels/lane.
__global__ void agg1_kernel(const float* __restrict__ xl1, const float* __restrict__ es1,
                            const float* __restrict__ ed1, const int* __restrict__ csr,
                            const int* __restrict__ rs, const float* __restrict__ b1,
                            float* __restrict__ h1, int N){
    int n = (blockIdx.x << 2) + (threadIdx.x >> 6);
    int lane = threadIdx.x & 63;
    if (n >= N) return;
    int h = lane >> 5;
    float edn = ed1[n * 2 + h];
    float eself = leaky02(es1[n * 2 + h] + edn);
    int beg = __builtin_amdgcn_readfirstlane(rs[n]);
    int end = __builtin_amdgcn_readfirstlane(rs[n + 1]);
    float m = eself;
    for (int j = beg; j < end; ++j){
        int s = csr[j];
        m = fmaxf(m, leaky02(es1[s * 2 + h] + edn));
    }
    float denom = expf(eself - m);
    float2 xv = ((const float2*)xl1)[(size_t)n * 64 + lane];
    float2 acc; acc.x = denom * xv.x; acc.y = denom * xv.y;
    for (int j = beg; j < end; ++j){
        int s = csr[j];
        float a = expf(leaky02(es1[s * 2 + h] + edn) - m);
        denom += a;
        float2 sv = ((const float2*)xl1)[(size_t)s * 64 + lane];
        acc.x += a * sv.x; acc.y += a * sv.y;
    }
    float inv = 1.f / denom;
    int c = lane * 2;
    h1[(size_t)n * 128 + c]     = elu1(acc.x * inv + b1[c]);
    h1[(size_t)n * 128 + c + 1] = elu1(acc.y * inv + b1[c + 1]);
}

// xl2 = h1 @ W2  [N,64]; es2/ed2 [N,1]
__global__ void feat2_kernel(const float* __restrict__ h1, const float* __restrict__ W2,
                             const float* __restrict__ a2s, const float* __restrict__ a2d,
                             float* __restrict__ xl2, float* __restrict__ es2,
                             float* __restrict__ ed2, int N){
    __shared__ float rows[4][128];
    int w = threadIdx.x >> 6;
    int n = (blockIdx.x << 2) + w;
    int lane = threadIdx.x & 63;
    bool act = n < N;
    if (act){
        rows[w][lane]      = h1[(size_t)n * 128 + lane];
        rows[w][lane + 64] = h1[(size_t)n * 128 + 64 + lane];
    }
    __syncthreads();
    if (!act) return;
    float acc = 0.f;
    #pragma unroll 8
    for (int k = 0; k < 128; ++k) acc += rows[w][k] * W2[k * 64 + lane];
    xl2[(size_t)n * 64 + lane] = acc;
    float ps = acc * a2s[lane];
    float pd = acc * a2d[lane];
    #pragma unroll
    for (int m = 32; m >= 1; m >>= 1){ ps += __shfl_xor(ps, m, 64); pd += __shfl_xor(pd, m, 64); }
    if (lane == 0){ es2[n] = ps; ed2[n] = pd; }
}

// GAT layer-2 aggregation (H=1, C=64)
__global__ void agg2_kernel(const float* __restrict__ xl2, const float* __restrict__ es2,
                            const float* __restrict__ ed2, const int* __restrict__ csr,
                            const int* __restrict__ rs, const float* __restrict__ b2,
                            float* __restrict__ h2, int N){
    int n = (blockIdx.x << 2) + (threadIdx.x >> 6);
    int lane = threadIdx.x & 63;
    if (n >= N) return;
    float edn = ed2[n];
    float eself = leaky02(es2[n] + edn);
    int beg = __builtin_amdgcn_readfirstlane(rs[n]);
    int end = __builtin_amdgcn_readfirstlane(rs[n + 1]);
    float m = eself;
    for (int j = beg; j < end; ++j) m = fmaxf(m, leaky02(es2[csr[j]] + edn));
    float denom = expf(eself - m);
    float acc = denom * xl2[(size_t)n * 64 + lane];
    for (int j = beg; j < end; ++j){
        int s = csr[j];
        float a = expf(leaky02(es2[s] + edn) - m);
        denom += a;
        acc += a * xl2[(size_t)s * 64 + lane];
    }
    h2[(size_t)n * 64 + lane] = elu1(acc / denom + b2[lane]);
}

// mean-pool per graph (batch is sorted): 1 wave / 32-node tile, run-length flush
__global__ void pool_kernel(const float* __restrict__ h2, const int* __restrict__ batch,
                            float* __restrict__ pooled, float* __restrict__ cnt, int N){
    int lane = threadIdx.x;
    int n0 = blockIdx.x * 32;
    float acc = 0.f; int grun = -1; float crun = 0.f;
    for (int i = 0; i < 32; ++i){
        int n = n0 + i;
        if (n >= N) break;
        int g = batch[n];
        if (g != grun){
            if (grun >= 0){
                atomicAdd(&pooled[grun * 64 + lane], acc);
                if (lane == 0) atomicAdd(&cnt[grun], crun);
            }
            grun = g; acc = 0.f; crun = 0.f;
        }
        acc += h2[(size_t)n * 64 + lane];
        crun += 1.f;
    }
    if (grun >= 0){
        atomicAdd(&pooled[grun * 64 + lane], acc);
        if (lane == 0) atomicAdd(&cnt[grun], crun);
    }
}

// per-branch MLP: relu(pooled/cnt @ M1w + M1b) @ M2w + M2b  -> [64,64]
__global__ void mlp_kernel(const float* __restrict__ pooled, const float* __restrict__ cnt,
                           const float* __restrict__ M1w, const float* __restrict__ M1b,
                           const float* __restrict__ M2w, const float* __restrict__ M2b,
                           float* __restrict__ out){
    __shared__ float P[4096];
    __shared__ float H[4096];
    int t = threadIdx.x;
    for (int idx = t; idx < 4096; idx += 1024){
        int r = idx >> 6;
        P[idx] = pooled[idx] / fmaxf(cnt[r], 1.f);
    }
    __syncthreads();
    for (int idx = t; idx < 4096; idx += 1024){
        int r = idx >> 6, c = idx & 63;
        float acc = M1b[c];
        #pragma unroll 8
        for (int k = 0; k < 64; ++k) acc += P[(r << 6) + k] * M1w[(k << 6) + c];
        H[idx] = fmaxf(acc, 0.f);
    }
    __syncthreads();
    for (int idx = t; idx < 4096; idx += 1024){
        int r = idx >> 6, c = idx & 63;
        float acc = M2b[c];
        #pragma unroll 8
        for (int k = 0; k < 64; ++k) acc += H[(r << 6) + k] * M2w[(k << 6) + c];
        out[idx] = acc;
    }
}

// tanh(relu((bb*tt) @ Fw1 + Fb1) @ Fw2 + Fb2)  -> [64,2]
__global__ void final_kernel(const float* __restrict__ bb, const float* __restrict__ tt,
                             const float* __restrict__ Fw1, const float* __restrict__ Fb1,
                             const float* __restrict__ Fw2, const float* __restrict__ Fb2,
                             float* __restrict__ out){
    __shared__ float C[4096];
    __shared__ float H[4096];
    int t = threadIdx.x;
    for (int idx = t; idx < 4096; idx += 1024) C[idx] = bb[idx] * tt[idx];
    __syncthreads();
    for (int idx = t; idx < 4096; idx += 1024){
        int r = idx >> 6, c = idx & 63;
        float acc = Fb1[c];
        #pragma unroll 8
        for (int k = 0; k < 64; ++k) acc += C[(r << 6) + k] * Fw1[(k << 6) + c];
        H[idx] = fmaxf(acc, 0.f);
    }
    __syncthreads();
    if (t < 128){
        int r = t >> 1, j = t & 1;
        float acc = Fb2[j];
        #pragma unroll 8
        for (int k = 0; k < 64; ++k) acc += H[(r << 6) + k] * Fw2[k * 2 + j];
        out[t] = tanhf(acc);
    }
}

extern "C" void kernel_launch(void* const* d_in, const int* in_sizes, int n_in,
                              void* d_out, int out_size, void* d_ws, size_t ws_size,
                              hipStream_t stream){
    const int N = in_sizes[0] / 2;
    const int E = in_sizes[1] / 2;

    char* ws = (char*)d_ws;
    size_t off = 0;
    auto alloc = [&](size_t bytes) -> char* {
        char* p = ws + off;
        off += (bytes + 255) & ~(size_t)255;
        return p;
    };
    float* XL1 = (float*)alloc((size_t)N * 128 * 4);  // later re-used: XL2 [N*64] + H2 [N*64]
    float* H1  = (float*)alloc((size_t)N * 128 * 4);
    float* ES1 = (float*)alloc((size_t)N * 2 * 4);
    float* ED1 = (float*)alloc((size_t)N * 2 * 4);
    float* ES2 = (float*)alloc((size_t)N * 4);
    float* ED2 = (float*)alloc((size_t)N * 4);
    int*   CNT = (int*)alloc((size_t)N * 4);
    int*   RS  = (int*)alloc((size_t)(N + 1) * 4);
    int*   CUR = (int*)alloc((size_t)N * 4);
    int*   CSR = (int*)alloc((size_t)E * 4);
    float* POOL= (float*)alloc((64 * 64 + 64) * 4);   // pooled + cnt
    float* PC  = POOL + 64 * 64;
    float* BB  = (float*)alloc(64 * 64 * 4);
    float* TT  = (float*)alloc(64 * 64 * 4);
    float* XL2 = XL1;                 // alias: XL1 dead once agg1 finished
    float* H2  = XL1 + (size_t)N * 64;

    const int nodeBlocks = (N + 3) / 4;
    const int edgeBlocks = (E + 255) / 256;

    for (int br = 0; br < 2; ++br){
        int base = br * 15;
        const float* x    = (const float*)d_in[base + 0];
        const int*   ei   = (const int*)  d_in[base + 1];
        const int*   batch= (const int*)  d_in[base + 2];
        const float* W1   = (const float*)d_in[base + 3];
        const float* a1s  = (const float*)d_in[base + 4];
        const float* a1d  = (const float*)d_in[base + 5];
        const float* b1   = (const float*)d_in[base + 6];
        const float* W2   = (const float*)d_in[base + 7];
        const float* a2s  = (const float*)d_in[base + 8];
        const float* a2d  = (const float*)d_in[base + 9];
        const float* b2   = (const float*)d_in[base + 10];
        const float* M1w  = (const float*)d_in[base + 11];
        const float* M1b  = (const float*)d_in[base + 12];
        const float* M2w  = (const float*)d_in[base + 13];
        const float* M2b  = (const float*)d_in[base + 14];
        const int* srcI = ei;
        const int* dstI = ei + E;
        float* OUTV = (br == 0) ? BB : TT;

        hipMemsetAsync(CNT, 0, (size_t)N * 4, stream);
        hipMemsetAsync(POOL, 0, (64 * 64 + 64) * 4, stream);

        feat1_kernel<<<nodeBlocks, 256, 0, stream>>>(x, W1, a1s, a1d, XL1, ES1, ED1, N);
        hist_kernel<<<edgeBlocks, 256, 0, stream>>>(dstI, CNT, E);
        scan_kernel<<<1, 1024, 0, stream>>>(CNT, RS, CUR, N);
        fill_kernel<<<edgeBlocks, 256, 0, stream>>>(srcI, dstI, CUR, CSR, E);
        agg1_kernel<<<nodeBlocks, 256, 0, stream>>>(XL1, ES1, ED1, CSR, RS, b1, H1, N);
        feat2_kernel<<<nodeBlocks, 256, 0, stream>>>(H1, W2, a2s, a2d, XL2, ES2, ED2, N);
        agg2_kernel<<<nodeBlocks, 256, 0, stream>>>(XL2, ES2, ED2, CSR, RS, b2, H2, N);
        pool_kernel<<<(N + 31) / 32, 64, 0, stream>>>(H2, batch, POOL, PC, N);
        mlp_kernel<<<1, 1024, 0, stream>>>(POOL, PC, M1w, M1b, M2w, M2b, OUTV);
    }

    const float* Fw1 = (const float*)d_in[30];
    const float* Fb1 = (const float*)d_in[31];
    const float* Fw2 = (const float*)d_in[32];
    const float* Fb2 = (const float*)d_in[33];
    final_kernel<<<1, 1024, 0, stream>>>(BB, TT, Fw1, Fb1, Fw2, Fb2, (float*)d_out);
}

// Round 2
// 569.349 us; speedup vs baseline: 1.6208x; 1.6208x over previous
//
#include <hip/hip_runtime.h>
#include <math.h>

// ---------------------------------------------------------------------------
// DeepONet/GAT: both branches processed per kernel, bf16 gather tables,
// single-pass (no-max) softmax aggregation, CSR built via hist+scan+fill.
// ---------------------------------------------------------------------------

__device__ __forceinline__ float leaky02(float x){ return fmaxf(x, 0.2f * x); }
__device__ __forceinline__ float elu1(float x){ return x > 0.f ? x : expm1f(x); }
__device__ __forceinline__ unsigned f2bf(float a){
    unsigned u = __float_as_uint(a);
    return (u + 0x7FFFu + ((u >> 16) & 1u)) >> 16;
}
__device__ __forceinline__ unsigned packbf(float a, float b){ return f2bf(a) | (f2bf(b) << 16); }
__device__ __forceinline__ float bflo(unsigned p){ return __uint_as_float(p << 16); }
__device__ __forceinline__ float bfhi(unsigned p){ return __uint_as_float(p & 0xFFFF0000u); }
__device__ __forceinline__ float bfs(unsigned short s){ return __uint_as_float(((unsigned)s) << 16); }

// feat1 (both branches) + degree histogram (both branches), grid-split.
__global__ __launch_bounds__(256) void pre_kernel(
    const float* __restrict__ xb, const float* __restrict__ xt,
    const float* __restrict__ W1b, const float* __restrict__ W1t,
    const float* __restrict__ a1sb, const float* __restrict__ a1st,
    const float* __restrict__ a1db, const float* __restrict__ a1dt,
    const int* __restrict__ eib, const int* __restrict__ eit,
    unsigned* __restrict__ xl1u, float* __restrict__ es1, float* __restrict__ ed1,
    int* __restrict__ cntArr, int N, int E, int nodeBlocks, int edgeBlocks){
    int bid = blockIdx.x;
    if (bid < 2 * edgeBlocks){
        int br = (bid >= edgeBlocks) ? 1 : 0;
        const int* dst = (br ? eit : eib) + E;
        int t = (bid - br * edgeBlocks) * 256 + threadIdx.x;
        if (t < E) atomicAdd(&cntArr[br * N + dst[t]], 1);
        return;
    }
    bid -= 2 * edgeBlocks;
    int br = (bid >= nodeBlocks) ? 1 : 0;
    int nb = bid - br * nodeBlocks;
    int n = (nb << 2) + (threadIdx.x >> 6);
    int lane = threadIdx.x & 63;
    if (n >= N) return;
    const float* x   = br ? xt   : xb;
    const float* W1  = br ? W1t  : W1b;
    const float* a1s = br ? a1st : a1sb;
    const float* a1d = br ? a1dt : a1db;
    float2 xv = ((const float2*)x)[n];
    float2 w0 = ((const float2*)W1)[lane];          // W1[0, 2l..2l+1]
    float2 w1 = ((const float2*)(W1 + 128))[lane];  // W1[1, 2l..2l+1]
    float xla = xv.x * w0.x + xv.y * w1.x;
    float xlb = xv.x * w0.y + xv.y * w1.y;
    xl1u[(size_t)br * N * 64 + (size_t)n * 64 + lane] = packbf(xla, xlb);
    float2 as = ((const float2*)a1s)[lane];
    float2 ad = ((const float2*)a1d)[lane];
    float ps = xla * as.x + xlb * as.y;
    float pd = xla * ad.x + xlb * ad.y;
    #pragma unroll
    for (int m = 16; m >= 1; m >>= 1){ ps += __shfl_xor(ps, m, 64); pd += __shfl_xor(pd, m, 64); }
    if ((lane & 31) == 0){
        int h = lane >> 5;
        es1[(size_t)br * N * 2 + n * 2 + h] = ps;
        ed1[(size_t)br * N * 2 + n * 2 + h] = pd;
    }
}

// exclusive scan of per-node degree -> row starts; 2 blocks (one per branch)
__global__ __launch_bounds__(1024) void scan_kernel(const int* __restrict__ cntArr,
                                                    int* __restrict__ rs, int* __restrict__ cur, int N){
    int br = blockIdx.x;
    const int* cnt = cntArr + (size_t)br * N;
    int* rsb  = rs  + (size_t)br * (N + 1);
    int* curb = cur + (size_t)br * N;
    __shared__ int wsum[16];
    __shared__ int carry;
    int t = threadIdx.x, wid = t >> 6, lane = t & 63;
    if (t == 0) carry = 0;
    __syncthreads();
    for (int base = 0; base < N; base += 8192){
        int idx0 = base + t * 8;
        int v[8]; int s = 0;
        #pragma unroll
        for (int i = 0; i < 8; ++i){ int id = idx0 + i; v[i] = (id < N) ? cnt[id] : 0; s += v[i]; }
        int inc = s;
        #pragma unroll
        for (int d = 1; d < 64; d <<= 1){ int u = __shfl_up(inc, (unsigned)d, 64); if (lane >= d) inc += u; }
        if (lane == 63) wsum[wid] = inc;
        __syncthreads();
        int wbase = 0;
        for (int wl = 0; wl < wid; ++wl) wbase += wsum[wl];
        int run = carry + wbase + (inc - s);
        #pragma unroll
        for (int i = 0; i < 8; ++i){
            int id = idx0 + i;
            if (id < N){ rsb[id] = run; curb[id] = run; }
            run += v[i];
        }
        __syncthreads();
        if (t == 1023) carry += wbase + inc;
        __syncthreads();
    }
    if (t == 0) rsb[N] = carry;
}

__global__ __launch_bounds__(256) void fill_kernel(const int* __restrict__ eib, const int* __restrict__ eit,
                                                   int* __restrict__ cur, int* __restrict__ csr,
                                                   int N, int E, int edgeBlocks){
    int bid = blockIdx.x;
    int br = (bid >= edgeBlocks) ? 1 : 0;
    const int* ei = br ? eit : eib;
    int t = (bid - br * edgeBlocks) * 256 + threadIdx.x;
    if (t < E){
        int s = ei[t];
        int d = ei[E + t];
        int pos = atomicAdd(&cur[br * N + d], 1);
        csr[(size_t)br * E + pos] = s;
    }
}

// GAT layer-1 aggregation (H=2,C=64), single pass (no max-shift), bf16 gathers.
__global__ __launch_bounds__(256) void agg1_kernel(
    const unsigned* __restrict__ xl1u, const float* __restrict__ es1, const float* __restrict__ ed1,
    const int* __restrict__ csr, const int* __restrict__ rs,
    const float* __restrict__ b1b, const float* __restrict__ b1t,
    unsigned* __restrict__ h1u, int N, int E, int nodeBlocks){
    int bid = blockIdx.x;
    int br = (bid >= nodeBlocks) ? 1 : 0;
    int n = ((bid - br * nodeBlocks) << 2) + (threadIdx.x >> 6);
    int lane = threadIdx.x & 63;
    if (n >= N) return;
    const unsigned* xl = xl1u + (size_t)br * N * 64;
    const float* es = es1 + (size_t)br * N * 2;
    const float* ed = ed1 + (size_t)br * N * 2;
    const int* cs = csr + (size_t)br * E;
    const int* rsb = rs + (size_t)br * (N + 1);
    const float* b1 = br ? b1t : b1b;
    int h = lane >> 5;
    float edn = ed[n * 2 + h];
    float wself = __expf(leaky02(es[n * 2 + h] + edn));
    unsigned pself = xl[(size_t)n * 64 + lane];
    float denom = wself;
    float ax = wself * bflo(pself);
    float ay = wself * bfhi(pself);
    int beg = __builtin_amdgcn_readfirstlane(rsb[n]);
    int end = __builtin_amdgcn_readfirstlane(rsb[n + 1]);
    int j = beg;
    for (; j + 4 <= end; j += 4){
        int s0 = cs[j], s1 = cs[j + 1], s2 = cs[j + 2], s3 = cs[j + 3];
        float e0 = es[s0 * 2 + h], e1 = es[s1 * 2 + h], e2 = es[s2 * 2 + h], e3 = es[s3 * 2 + h];
        unsigned p0 = xl[(size_t)s0 * 64 + lane];
        unsigned p1 = xl[(size_t)s1 * 64 + lane];
        unsigned p2 = xl[(size_t)s2 * 64 + lane];
        unsigned p3 = xl[(size_t)s3 * 64 + lane];
        float w0 = __expf(leaky02(e0 + edn));
        float w1 = __expf(leaky02(e1 + edn));
        float w2 = __expf(leaky02(e2 + edn));
        float w3 = __expf(leaky02(e3 + edn));
        denom += (w0 + w1) + (w2 + w3);
        ax += w0 * bflo(p0); ay += w0 * bfhi(p0);
        ax += w1 * bflo(p1); ay += w1 * bfhi(p1);
        ax += w2 * bflo(p2); ay += w2 * bfhi(p2);
        ax += w3 * bflo(p3); ay += w3 * bfhi(p3);
    }
    for (; j < end; ++j){
        int s = cs[j];
        float w = __expf(leaky02(es[s * 2 + h] + edn));
        unsigned p = xl[(size_t)s * 64 + lane];
        denom += w;
        ax += w * bflo(p); ay += w * bfhi(p);
    }
    float inv = 1.f / denom;
    int c = lane << 1;
    float h0 = elu1(ax * inv + b1[c]);
    float h1v = elu1(ay * inv + b1[c + 1]);
    h1u[(size_t)br * N * 64 + (size_t)n * 64 + lane] = packbf(h0, h1v);
}

// xl2 = h1 @ W2 (both branches), W2 staged bf16-packed in LDS, 4 nodes/wave.
__global__ __launch_bounds__(256) void feat2_kernel(
    const unsigned* __restrict__ h1u,
    const float* __restrict__ W2b, const float* __restrict__ W2t,
    const float* __restrict__ a2sb, const float* __restrict__ a2st,
    const float* __restrict__ a2db, const float* __restrict__ a2dt,
    unsigned short* __restrict__ xl2h, float* __restrict__ es2, float* __restrict__ ed2,
    int N, int blocksPer){
    int bid = blockIdx.x;
    int br = (bid >= blocksPer) ? 1 : 0;
    int nbase = (bid - br * blocksPer) * 16;
    const float* W2  = br ? W2t  : W2b;
    const float* a2s = br ? a2st : a2sb;
    const float* a2d = br ? a2dt : a2db;
    __shared__ unsigned w2s[4096];   // [k2=64][c=64] packed (W2[2k2,c], W2[2k2+1,c])
    __shared__ unsigned hst[1024];   // 16 nodes x 64 packed h1 pairs
    int t = threadIdx.x;
    for (int i = t; i < 4096; i += 256){
        int k2 = i >> 6, c = i & 63;
        w2s[i] = packbf(W2[(k2 * 2) * 64 + c], W2[(k2 * 2 + 1) * 64 + c]);
    }
    const unsigned* h1 = h1u + (size_t)br * N * 64;
    for (int i = t; i < 1024; i += 256){
        int n = nbase + (i >> 6);
        hst[i] = (n < N) ? h1[(size_t)n * 64 + (i & 63)] : 0u;
    }
    __syncthreads();
    int wid = t >> 6, lane = t & 63;
    int hbase = wid * 4 * 64;
    float acc0 = 0.f, acc1 = 0.f, acc2 = 0.f, acc3 = 0.f;
    #pragma unroll 4
    for (int k2 = 0; k2 < 64; ++k2){
        unsigned wv = w2s[k2 * 64 + lane];
        float wlo = bflo(wv), whi = bfhi(wv);
        unsigned h0 = hst[hbase + k2];
        unsigned h1x = hst[hbase + 64 + k2];
        unsigned h2x = hst[hbase + 128 + k2];
        unsigned h3x = hst[hbase + 192 + k2];
        acc0 += bflo(h0) * wlo + bfhi(h0) * whi;
        acc1 += bflo(h1x) * wlo + bfhi(h1x) * whi;
        acc2 += bflo(h2x) * wlo + bfhi(h2x) * whi;
        acc3 += bflo(h3x) * wlo + bfhi(h3x) * whi;
    }
    float a2sv = a2s[lane], a2dv = a2d[lane];
    #define DO_NODE(jj, accv) { \
        int n = nbase + wid * 4 + jj; \
        if (n < N){ \
            xl2h[(size_t)br * N * 64 + (size_t)n * 64 + lane] = (unsigned short)f2bf(accv); \
            float ps = accv * a2sv, pd = accv * a2dv; \
            _Pragma("unroll") \
            for (int m = 32; m >= 1; m >>= 1){ ps += __shfl_xor(ps, m, 64); pd += __shfl_xor(pd, m, 64); } \
            if (lane == 0){ es2[(size_t)br * N + n] = ps; ed2[(size_t)br * N + n] = pd; } \
        } }
    DO_NODE(0, acc0) DO_NODE(1, acc1) DO_NODE(2, acc2) DO_NODE(3, acc3)
    #undef DO_NODE
}

// GAT layer-2 aggregation (H=1,C=64), bf16 gathers, single pass.
__global__ __launch_bounds__(256) void agg2_kernel(
    const unsigned short* __restrict__ xl2h, const float* __restrict__ es2, const float* __restrict__ ed2,
    const int* __restrict__ csr, const int* __restrict__ rs,
    const float* __restrict__ b2b, const float* __restrict__ b2t,
    unsigned short* __restrict__ h2h, int N, int E, int nodeBlocks){
    int bid = blockIdx.x;
    int br = (bid >= nodeBlocks) ? 1 : 0;
    int n = ((bid - br * nodeBlocks) << 2) + (threadIdx.x >> 6);
    int lane = threadIdx.x & 63;
    if (n >= N) return;
    const unsigned short* xl = xl2h + (size_t)br * N * 64;
    const float* es = es2 + (size_t)br * N;
    const float* ed = ed2 + (size_t)br * N;
    const int* cs = csr + (size_t)br * E;
    const int* rsb = rs + (size_t)br * (N + 1);
    const float* b2 = br ? b2t : b2b;
    float edn = ed[n];
    float wself = __expf(leaky02(es[n] + edn));
    float denom = wself;
    float acc = wself * bfs(xl[(size_t)n * 64 + lane]);
    int beg = __builtin_amdgcn_readfirstlane(rsb[n]);
    int end = __builtin_amdgcn_readfirstlane(rsb[n + 1]);
    int j = beg;
    for (; j + 4 <= end; j += 4){
        int s0 = cs[j], s1 = cs[j + 1], s2 = cs[j + 2], s3 = cs[j + 3];
        float e0 = es[s0], e1 = es[s1], e2 = es[s2], e3 = es[s3];
        float v0 = bfs(xl[(size_t)s0 * 64 + lane]);
        float v1 = bfs(xl[(size_t)s1 * 64 + lane]);
        float v2 = bfs(xl[(size_t)s2 * 64 + lane]);
        float v3 = bfs(xl[(size_t)s3 * 64 + lane]);
        float w0 = __expf(leaky02(e0 + edn));
        float w1 = __expf(leaky02(e1 + edn));
        float w2 = __expf(leaky02(e2 + edn));
        float w3 = __expf(leaky02(e3 + edn));
        denom += (w0 + w1) + (w2 + w3);
        acc += w0 * v0 + w1 * v1;
        acc += w2 * v2 + w3 * v3;
    }
    for (; j < end; ++j){
        int s = cs[j];
        float w = __expf(leaky02(es[s] + edn));
        denom += w;
        acc += w * bfs(xl[(size_t)s * 64 + lane]);
    }
    h2h[(size_t)br * N * 64 + (size_t)n * 64 + lane] = (unsigned short)f2bf(elu1(acc / denom + b2[lane]));
}

// segmented mean-pool: one block per (branch, graph), binary search on sorted batch
__global__ __launch_bounds__(256) void pool_kernel(
    const unsigned short* __restrict__ h2h,
    const int* __restrict__ batchb, const int* __restrict__ batcht,
    float* __restrict__ pooled, float* __restrict__ pcnt, int N){
    int br = blockIdx.x >> 6, g = blockIdx.x & 63;
    const int* batch = br ? batcht : batchb;
    int lo = 0, hi = N;
    while (lo < hi){ int mid = (lo + hi) >> 1; if (batch[mid] < g) lo = mid + 1; else hi = mid; }
    int beg = lo;
    hi = N;
    while (lo < hi){ int mid = (lo + hi) >> 1; if (batch[mid] < g + 1) lo = mid + 1; else hi = mid; }
    int end = lo;
    int t = threadIdx.x, wid = t >> 6, lane = t & 63;
    const unsigned short* h2 = h2h + (size_t)br * N * 64;
    float acc = 0.f;
    for (int n = beg + wid; n < end; n += 4) acc += bfs(h2[(size_t)n * 64 + lane]);
    __shared__ float red[256];
    red[t] = acc;
    __syncthreads();
    if (wid == 0){
        float s = red[lane] + red[64 + lane] + red[128 + lane] + red[192 + lane];
        pooled[((size_t)br * 64 + g) * 64 + lane] = s;
        if (lane == 0) pcnt[br * 64 + g] = (float)(end - beg);
    }
}

// both branch MLPs + combine + final head, one block
__global__ __launch_bounds__(1024) void tail_kernel(
    const float* __restrict__ pooled, const float* __restrict__ pcnt,
    const float* __restrict__ M1wb, const float* __restrict__ M1bb,
    const float* __restrict__ M2wb, const float* __restrict__ M2bb,
    const float* __restrict__ M1wt, const float* __restrict__ M1bt,
    const float* __restrict__ M2wt, const float* __restrict__ M2bt,
    const float* __restrict__ Fw1, const float* __restrict__ Fb1,
    const float* __restrict__ Fw2, const float* __restrict__ Fb2,
    float* __restrict__ out){
    __shared__ float P[8192];
    __shared__ float H[8192];
    int t = threadIdx.x;
    for (int i = t; i < 8192; i += 1024){
        int br = i >> 12, g = (i >> 6) & 63;
        P[i] = pooled[i] / fmaxf(pcnt[br * 64 + g], 1.f);
    }
    __syncthreads();
    for (int i = t; i < 8192; i += 1024){
        int br = i >> 12, r = (i >> 6) & 63, c = i & 63;
        const float* M1w = br ? M1wt : M1wb;
        const float* M1b = br ? M1bt : M1bb;
        float acc = M1b[c];
        int pb = (br << 12) + (r << 6);
        #pragma unroll 8
        for (int k = 0; k < 64; ++k) acc += P[pb + k] * M1w[(k << 6) + c];
        H[i] = fmaxf(acc, 0.f);
    }
    __syncthreads();
    for (int i = t; i < 8192; i += 1024){
        int br = i >> 12, r = (i >> 6) & 63, c = i & 63;
        const float* M2w = br ? M2wt : M2wb;
        const float* M2b = br ? M2bt : M2bb;
        float acc = M2b[c];
        int hb = (br << 12) + (r << 6);
        #pragma unroll 8
        for (int k = 0; k < 64; ++k) acc += H[hb + k] * M2w[(k << 6) + c];
        P[i] = acc;
    }
    __syncthreads();
    for (int i = t; i < 4096; i += 1024) H[i] = P[i] * P[4096 + i];
    __syncthreads();
    for (int i = t; i < 4096; i += 1024){
        int r = i >> 6, c = i & 63;
        float acc = Fb1[c];
        #pragma unroll 8
        for (int k = 0; k < 64; ++k) acc += H[(r << 6) + k] * Fw1[(k << 6) + c];
        P[i] = fmaxf(acc, 0.f);
    }
    __syncthreads();
    if (t < 128){
        int r = t >> 1, jc = t & 1;
        float acc = Fb2[jc];
        #pragma unroll 8
        for (int k = 0; k < 64; ++k) acc += P[(r << 6) + k] * Fw2[k * 2 + jc];
        out[t] = tanhf(acc);
    }
}

extern "C" void kernel_launch(void* const* d_in, const int* in_sizes, int n_in,
                              void* d_out, int out_size, void* d_ws, size_t ws_size,
                              hipStream_t stream){
    const int N = in_sizes[0] / 2;
    const int E = in_sizes[1] / 2;

    char* ws = (char*)d_ws;
    size_t off = 0;
    auto alloc = [&](size_t bytes) -> char* {
        char* p = ws + off;
        off += (bytes + 255) & ~(size_t)255;
        return p;
    };
    unsigned* XL1u = (unsigned*)alloc((size_t)2 * N * 64 * 4);  // bf16-pair packed; later aliased by XL2h
    unsigned* H1u  = (unsigned*)alloc((size_t)2 * N * 64 * 4);  // bf16-pair packed; later aliased by H2h
    float* ES1 = (float*)alloc((size_t)2 * N * 2 * 4);
    float* ED1 = (float*)alloc((size_t)2 * N * 2 * 4);
    float* ES2 = (float*)alloc((size_t)2 * N * 4);
    float* ED2 = (float*)alloc((size_t)2 * N * 4);
    int* CNT = (int*)alloc((size_t)2 * N * 4);
    int* RS  = (int*)alloc((size_t)2 * (N + 1) * 4);
    int* CUR = (int*)alloc((size_t)2 * N * 4);
    int* CSR = (int*)alloc((size_t)2 * E * 4);
    float* POOLED = (float*)alloc(8192 * 4);
    float* PCNT   = (float*)alloc(128 * 4);
    unsigned short* XL2h = (unsigned short*)XL1u;  // alias (XL1u dead after agg1)
    unsigned short* H2h  = (unsigned short*)H1u;   // alias (H1u dead after feat2)

    const float* xb   = (const float*)d_in[0];
    const int*   eib  = (const int*)  d_in[1];
    const int*   batchb = (const int*)d_in[2];
    const float* W1b  = (const float*)d_in[3];
    const float* a1sb = (const float*)d_in[4];
    const float* a1db = (const float*)d_in[5];
    const float* b1b  = (const float*)d_in[6];
    const float* W2b  = (const float*)d_in[7];
    const float* a2sb = (const float*)d_in[8];
    const float* a2db = (const float*)d_in[9];
    const float* b2b  = (const float*)d_in[10];
    const float* M1wb = (const float*)d_in[11];
    const float* M1bb = (const float*)d_in[12];
    const float* M2wb = (const float*)d_in[13];
    const float* M2bb = (const float*)d_in[14];
    const float* xt   = (const float*)d_in[15];
    const int*   eit  = (const int*)  d_in[16];
    const int*   batcht = (const int*)d_in[17];
    const float* W1t  = (const float*)d_in[18];
    const float* a1st = (const float*)d_in[19];
    const float* a1dt = (const float*)d_in[20];
    const float* b1t  = (const float*)d_in[21];
    const float* W2t  = (const float*)d_in[22];
    const float* a2st = (const float*)d_in[23];
    const float* a2dt = (const float*)d_in[24];
    const float* b2t  = (const float*)d_in[25];
    const float* M1wt = (const float*)d_in[26];
    const float* M1bt = (const float*)d_in[27];
    const float* M2wt = (const float*)d_in[28];
    const float* M2bt = (const float*)d_in[29];
    const float* Fw1  = (const float*)d_in[30];
    const float* Fb1  = (const float*)d_in[31];
    const float* Fw2  = (const float*)d_in[32];
    const float* Fb2  = (const float*)d_in[33];

    const int nodeBlocks = (N + 3) / 4;
    const int edgeBlocks = (E + 255) / 256;
    const int f2Blocks   = (N + 15) / 16;

    hipMemsetAsync(CNT, 0, (size_t)2 * N * 4, stream);
    pre_kernel<<<2 * edgeBlocks + 2 * nodeBlocks, 256, 0, stream>>>(
        xb, xt, W1b, W1t, a1sb, a1st, a1db, a1dt, eib, eit,
        XL1u, ES1, ED1, CNT, N, E, nodeBlocks, edgeBlocks);
    scan_kernel<<<2, 1024, 0, stream>>>(CNT, RS, CUR, N);
    fill_kernel<<<2 * edgeBlocks, 256, 0, stream>>>(eib, eit, CUR, CSR, N, E, edgeBlocks);
    agg1_kernel<<<2 * nodeBlocks, 256, 0, stream>>>(
        XL1u, ES1, ED1, CSR, RS, b1b, b1t, H1u, N, E, nodeBlocks);
    feat2_kernel<<<2 * f2Blocks, 256, 0, stream>>>(
        H1u, W2b, W2t, a2sb, a2st, a2db, a2dt, XL2h, ES2, ED2, N, f2Blocks);
    agg2_kernel<<<2 * nodeBlocks, 256, 0, stream>>>(
        XL2h, ES2, ED2, CSR, RS, b2b, b2t, H2h, N, E, nodeBlocks);
    pool_kernel<<<128, 256, 0, stream>>>(H2h, batchb, batcht, POOLED, PCNT, N);
    tail_kernel<<<1, 1024, 0, stream>>>(POOLED, PCNT,
        M1wb, M1bb, M2wb, M2bb, M1wt, M1bt, M2wt, M2bt,
        Fw1, Fb1, Fw2, Fb2, (float*)d_out);
}

// Round 3
// 387.262 us; speedup vs baseline: 2.3828x; 1.4702x over previous
//
#include <hip/hip_runtime.h>
#include <math.h>

// ---------------------------------------------------------------------------
// DeepONet/GAT: bf16 gather tables, single-pass softmax aggregation.
// CSR built via bucket-sort: bucket-hist (in pre) -> bin (LDS counting sort,
// coalesced flush) -> per-bucket CSR (L2-window-local scatter).
// Buckets: 512 nodes each (BUCKET_SHIFT=9), NB <= 128 assumed (N <= 65536).
// ---------------------------------------------------------------------------

#define BSH 9
#define CHUNK 4096

__device__ __forceinline__ float leaky02(float x){ return fmaxf(x, 0.2f * x); }
__device__ __forceinline__ float elu1(float x){ return x > 0.f ? x : expm1f(x); }
__device__ __forceinline__ unsigned f2bf(float a){
    unsigned u = __float_as_uint(a);
    return (u + 0x7FFFu + ((u >> 16) & 1u)) >> 16;
}
__device__ __forceinline__ unsigned packbf(float a, float b){ return f2bf(a) | (f2bf(b) << 16); }
__device__ __forceinline__ float bflo(unsigned p){ return __uint_as_float(p << 16); }
__device__ __forceinline__ float bfhi(unsigned p){ return __uint_as_float(p & 0xFFFF0000u); }
__device__ __forceinline__ float bfs(unsigned short s){ return __uint_as_float(((unsigned)s) << 16); }

__device__ __forceinline__ int wave_incl_scan(int v, int lane){
    #pragma unroll
    for (int d = 1; d < 64; d <<= 1){ int u = __shfl_up(v, (unsigned)d, 64); if (lane >= d) v += u; }
    return v;
}

// feat1 (both branches) + bucket histogram (both branches), grid-split.
__global__ __launch_bounds__(256) void pre_kernel(
    const float* __restrict__ xb, const float* __restrict__ xt,
    const float* __restrict__ W1b, const float* __restrict__ W1t,
    const float* __restrict__ a1sb, const float* __restrict__ a1st,
    const float* __restrict__ a1db, const float* __restrict__ a1dt,
    const int* __restrict__ eib, const int* __restrict__ eit,
    unsigned* __restrict__ xl1u, float* __restrict__ es1, float* __restrict__ ed1,
    int* __restrict__ bcnt, int N, int E, int NB, int nodeBlocks, int histBlocks){
    int bid = blockIdx.x;
    int tid = threadIdx.x;
    if (bid < 2 * histBlocks){
        int br = (bid >= histBlocks) ? 1 : 0;
        int cb = bid - br * histBlocks;
        const int* dstp = (br ? eit : eib) + E;
        __shared__ int hist[128];
        for (int i = tid; i < 128; i += 256) hist[i] = 0;
        __syncthreads();
        int start = cb * CHUNK, cnt = min(CHUNK, E - start);
        for (int i = tid; i < cnt; i += 256) atomicAdd(&hist[dstp[start + i] >> BSH], 1);
        __syncthreads();
        if (tid < NB && hist[tid]) atomicAdd(&bcnt[br * NB + tid], hist[tid]);
        return;
    }
    bid -= 2 * histBlocks;
    int br = (bid >= nodeBlocks) ? 1 : 0;
    int nb = bid - br * nodeBlocks;
    int n = (nb << 2) + (tid >> 6);
    int lane = tid & 63;
    if (n >= N) return;
    const float* x   = br ? xt   : xb;
    const float* W1  = br ? W1t  : W1b;
    const float* a1s = br ? a1st : a1sb;
    const float* a1d = br ? a1dt : a1db;
    float2 xv = ((const float2*)x)[n];
    float2 w0 = ((const float2*)W1)[lane];
    float2 w1 = ((const float2*)(W1 + 128))[lane];
    float xla = xv.x * w0.x + xv.y * w1.x;
    float xlb = xv.x * w0.y + xv.y * w1.y;
    xl1u[(size_t)br * N * 64 + (size_t)n * 64 + lane] = packbf(xla, xlb);
    float2 as = ((const float2*)a1s)[lane];
    float2 ad = ((const float2*)a1d)[lane];
    float ps = xla * as.x + xlb * as.y;
    float pd = xla * ad.x + xlb * ad.y;
    #pragma unroll
    for (int m = 16; m >= 1; m >>= 1){ ps += __shfl_xor(ps, m, 64); pd += __shfl_xor(pd, m, 64); }
    if ((lane & 31) == 0){
        int h = lane >> 5;
        es1[(size_t)br * N * 2 + n * 2 + h] = ps;
        ed1[(size_t)br * N * 2 + n * 2 + h] = pd;
    }
}

// counting-sort 4096-edge chunks by bucket in LDS, flush contiguous runs.
__global__ __launch_bounds__(256) void bin_kernel(
    const int* __restrict__ eib, const int* __restrict__ eit,
    const int* __restrict__ bcnt, int* __restrict__ bcur,
    uint2* __restrict__ epair, int N, int E, int NB, int blocksPer){
    int bid = blockIdx.x;
    int br = (bid >= blocksPer) ? 1 : 0;
    int cb = bid - br * blocksPer;
    const int* ei = br ? eit : eib;
    int start = cb * CHUNK;
    int cnt = min(CHUNK, E - start);
    __shared__ int base[128], hist[128], lbase[128], cur[128], gpos[128];
    __shared__ uint2 sbuf[CHUNK];
    int tid = threadIdx.x, lane = tid & 63, wid = tid >> 6;
    for (int i = tid; i < 128; i += 256) hist[i] = 0;
    __syncthreads();
    uint2 er[CHUNK / 256];
    int mycount = 0;
    #pragma unroll
    for (int k = 0; k < CHUNK / 256; ++k){
        int li = k * 256 + tid;
        if (li < cnt){
            int idx = start + li;
            er[k].x = (unsigned)ei[idx];
            er[k].y = (unsigned)ei[E + idx];
            atomicAdd(&hist[er[k].y >> BSH], 1);
            mycount = k + 1;
        }
    }
    __syncthreads();
    if (wid == 0){
        int h0 = hist[lane], h1 = hist[64 + lane];
        int s0 = wave_incl_scan(h0, lane); int t0 = __shfl(s0, 63, 64);
        int s1 = wave_incl_scan(h1, lane);
        lbase[lane] = s0 - h0; lbase[64 + lane] = t0 + s1 - h1;
        int b0 = (lane < NB) ? bcnt[br * NB + lane] : 0;
        int b1 = (64 + lane < NB) ? bcnt[br * NB + 64 + lane] : 0;
        int g0 = wave_incl_scan(b0, lane); int gt = __shfl(g0, 63, 64);
        int g1 = wave_incl_scan(b1, lane);
        base[lane] = g0 - b0; base[64 + lane] = gt + g1 - b1;
    }
    __syncthreads();
    for (int i = tid; i < 128; i += 256) cur[i] = lbase[i];
    if (tid < NB && hist[tid] > 0)
        gpos[tid] = base[tid] + atomicAdd(&bcur[br * NB + tid], hist[tid]);
    __syncthreads();
    for (int k = 0; k < mycount; ++k){
        int b = er[k].y >> BSH;
        int slot = atomicAdd(&cur[b], 1);
        sbuf[slot] = er[k];
    }
    __syncthreads();
    uint2* ep = epair + (size_t)br * E;
    for (int i = tid; i < cnt; i += 256){
        uint2 p = sbuf[i];
        int b = (int)(p.y >> BSH);
        ep[gpos[b] + (i - lbase[b])] = p;
    }
}

// per-bucket CSR: local degrees -> row starts (writes rs), scatter src.
__global__ __launch_bounds__(256) void csr_kernel(
    const int* __restrict__ bcnt, const uint2* __restrict__ epair,
    int* __restrict__ rs, int* __restrict__ csr, int N, int E, int NB){
    int bid = blockIdx.x;
    int br = (bid >= NB) ? 1 : 0;
    int b = bid - br * NB;
    __shared__ int base2[128];
    __shared__ int deg[512], st[512];
    int tid = threadIdx.x, lane = tid & 63, wid = tid >> 6;
    if (wid == 0){
        int b0 = (lane < NB) ? bcnt[br * NB + lane] : 0;
        int b1 = (64 + lane < NB) ? bcnt[br * NB + 64 + lane] : 0;
        int g0 = wave_incl_scan(b0, lane); int gt = __shfl(g0, 63, 64);
        int g1 = wave_incl_scan(b1, lane);
        base2[lane] = g0 - b0; base2[64 + lane] = gt + g1 - b1;
    }
    for (int i = tid; i < 512; i += 256) deg[i] = 0;
    __syncthreads();
    int ebase = base2[b];
    int ecnt = bcnt[br * NB + b];
    int n0 = b << BSH;
    int nodes = min(512, N - n0);
    const uint2* ep = epair + (size_t)br * E + ebase;
    for (int i = tid; i < ecnt; i += 256) atomicAdd(&deg[(int)ep[i].y - n0], 1);
    __syncthreads();
    if (wid == 0){
        int carry = 0;
        #pragma unroll
        for (int c = 0; c < 8; ++c){
            int v = deg[c * 64 + lane];
            int s = wave_incl_scan(v, lane);
            st[c * 64 + lane] = carry + s - v;
            carry += __shfl(s, 63, 64);
        }
    }
    __syncthreads();
    int* rsb = rs + (size_t)br * (N + 1);
    for (int i = tid; i < nodes; i += 256) rsb[n0 + i] = ebase + st[i];
    if (b == NB - 1 && tid == 0) rsb[N] = ebase + ecnt;
    for (int i = tid; i < 512; i += 256) deg[i] = st[i];
    __syncthreads();
    int* csrb = csr + (size_t)br * E + ebase;
    for (int i = tid; i < ecnt; i += 256){
        uint2 p = ep[i];
        int pos = atomicAdd(&deg[(int)p.y - n0], 1);
        csrb[pos] = (int)p.x;
    }
}

// GAT layer-1 aggregation (H=2,C=64), single pass (no max-shift), bf16 gathers.
__global__ __launch_bounds__(256) void agg1_kernel(
    const unsigned* __restrict__ xl1u, const float* __restrict__ es1, const float* __restrict__ ed1,
    const int* __restrict__ csr, const int* __restrict__ rs,
    const float* __restrict__ b1b, const float* __restrict__ b1t,
    unsigned* __restrict__ h1u, int N, int E, int nodeBlocks){
    int bid = blockIdx.x;
    int br = (bid >= nodeBlocks) ? 1 : 0;
    int n = ((bid - br * nodeBlocks) << 2) + (threadIdx.x >> 6);
    int lane = threadIdx.x & 63;
    if (n >= N) return;
    const unsigned* xl = xl1u + (size_t)br * N * 64;
    const float* es = es1 + (size_t)br * N * 2;
    const float* ed = ed1 + (size_t)br * N * 2;
    const int* cs = csr + (size_t)br * E;
    const int* rsb = rs + (size_t)br * (N + 1);
    const float* b1 = br ? b1t : b1b;
    int h = lane >> 5;
    float edn = ed[n * 2 + h];
    float wself = __expf(leaky02(es[n * 2 + h] + edn));
    unsigned pself = xl[(size_t)n * 64 + lane];
    float denom = wself;
    float ax = wself * bflo(pself);
    float ay = wself * bfhi(pself);
    int beg = __builtin_amdgcn_readfirstlane(rsb[n]);
    int end = __builtin_amdgcn_readfirstlane(rsb[n + 1]);
    int j = beg;
    for (; j + 4 <= end; j += 4){
        int s0 = cs[j], s1 = cs[j + 1], s2 = cs[j + 2], s3 = cs[j + 3];
        float e0 = es[s0 * 2 + h], e1 = es[s1 * 2 + h], e2 = es[s2 * 2 + h], e3 = es[s3 * 2 + h];
        unsigned p0 = xl[(size_t)s0 * 64 + lane];
        unsigned p1 = xl[(size_t)s1 * 64 + lane];
        unsigned p2 = xl[(size_t)s2 * 64 + lane];
        unsigned p3 = xl[(size_t)s3 * 64 + lane];
        float w0 = __expf(leaky02(e0 + edn));
        float w1 = __expf(leaky02(e1 + edn));
        float w2 = __expf(leaky02(e2 + edn));
        float w3 = __expf(leaky02(e3 + edn));
        denom += (w0 + w1) + (w2 + w3);
        ax += w0 * bflo(p0); ay += w0 * bfhi(p0);
        ax += w1 * bflo(p1); ay += w1 * bfhi(p1);
        ax += w2 * bflo(p2); ay += w2 * bfhi(p2);
        ax += w3 * bflo(p3); ay += w3 * bfhi(p3);
    }
    for (; j < end; ++j){
        int s = cs[j];
        float w = __expf(leaky02(es[s * 2 + h] + edn));
        unsigned p = xl[(size_t)s * 64 + lane];
        denom += w;
        ax += w * bflo(p); ay += w * bfhi(p);
    }
    float inv = 1.f / denom;
    int c = lane << 1;
    float h0 = elu1(ax * inv + b1[c]);
    float h1v = elu1(ay * inv + b1[c + 1]);
    h1u[(size_t)br * N * 64 + (size_t)n * 64 + lane] = packbf(h0, h1v);
}

// xl2 = h1 @ W2 (both branches), W2 staged bf16-packed in LDS, 4 nodes/wave.
__global__ __launch_bounds__(256) void feat2_kernel(
    const unsigned* __restrict__ h1u,
    const float* __restrict__ W2b, const float* __restrict__ W2t,
    const float* __restrict__ a2sb, const float* __restrict__ a2st,
    const float* __restrict__ a2db, const float* __restrict__ a2dt,
    unsigned short* __restrict__ xl2h, float* __restrict__ es2, float* __restrict__ ed2,
    int N, int blocksPer){
    int bid = blockIdx.x;
    int br = (bid >= blocksPer) ? 1 : 0;
    int nbase = (bid - br * blocksPer) * 16;
    const float* W2  = br ? W2t  : W2b;
    const float* a2s = br ? a2st : a2sb;
    const float* a2d = br ? a2dt : a2db;
    __shared__ unsigned w2s[4096];
    __shared__ unsigned hst[1024];
    int t = threadIdx.x;
    for (int i = t; i < 4096; i += 256){
        int k2 = i >> 6, c = i & 63;
        w2s[i] = packbf(W2[(k2 * 2) * 64 + c], W2[(k2 * 2 + 1) * 64 + c]);
    }
    const unsigned* h1 = h1u + (size_t)br * N * 64;
    for (int i = t; i < 1024; i += 256){
        int n = nbase + (i >> 6);
        hst[i] = (n < N) ? h1[(size_t)n * 64 + (i & 63)] : 0u;
    }
    __syncthreads();
    int wid = t >> 6, lane = t & 63;
    int hbase = wid * 4 * 64;
    float acc0 = 0.f, acc1 = 0.f, acc2 = 0.f, acc3 = 0.f;
    #pragma unroll 4
    for (int k2 = 0; k2 < 64; ++k2){
        unsigned wv = w2s[k2 * 64 + lane];
        float wlo = bflo(wv), whi = bfhi(wv);
        unsigned h0 = hst[hbase + k2];
        unsigned h1x = hst[hbase + 64 + k2];
        unsigned h2x = hst[hbase + 128 + k2];
        unsigned h3x = hst[hbase + 192 + k2];
        acc0 += bflo(h0) * wlo + bfhi(h0) * whi;
        acc1 += bflo(h1x) * wlo + bfhi(h1x) * whi;
        acc2 += bflo(h2x) * wlo + bfhi(h2x) * whi;
        acc3 += bflo(h3x) * wlo + bfhi(h3x) * whi;
    }
    float a2sv = a2s[lane], a2dv = a2d[lane];
    #define DO_NODE(jj, accv) { \
        int n = nbase + wid * 4 + jj; \
        if (n < N){ \
            xl2h[(size_t)br * N * 64 + (size_t)n * 64 + lane] = (unsigned short)f2bf(accv); \
            float ps = accv * a2sv, pd = accv * a2dv; \
            _Pragma("unroll") \
            for (int m = 32; m >= 1; m >>= 1){ ps += __shfl_xor(ps, m, 64); pd += __shfl_xor(pd, m, 64); } \
            if (lane == 0){ es2[(size_t)br * N + n] = ps; ed2[(size_t)br * N + n] = pd; } \
        } }
    DO_NODE(0, acc0) DO_NODE(1, acc1) DO_NODE(2, acc2) DO_NODE(3, acc3)
    #undef DO_NODE
}

// GAT layer-2 aggregation (H=1,C=64), bf16 gathers, single pass.
__global__ __launch_bounds__(256) void agg2_kernel(
    const unsigned short* __restrict__ xl2h, const float* __restrict__ es2, const float* __restrict__ ed2,
    const int* __restrict__ csr, const int* __restrict__ rs,
    const float* __restrict__ b2b, const float* __restrict__ b2t,
    unsigned short* __restrict__ h2h, int N, int E, int nodeBlocks){
    int bid = blockIdx.x;
    int br = (bid >= nodeBlocks) ? 1 : 0;
    int n = ((bid - br * nodeBlocks) << 2) + (threadIdx.x >> 6);
    int lane = threadIdx.x & 63;
    if (n >= N) return;
    const unsigned short* xl = xl2h + (size_t)br * N * 64;
    const float* es = es2 + (size_t)br * N;
    const float* ed = ed2 + (size_t)br * N;
    const int* cs = csr + (size_t)br * E;
    const int* rsb = rs + (size_t)br * (N + 1);
    const float* b2 = br ? b2t : b2b;
    float edn = ed[n];
    float wself = __expf(leaky02(es[n] + edn));
    float denom = wself;
    float acc = wself * bfs(xl[(size_t)n * 64 + lane]);
    int beg = __builtin_amdgcn_readfirstlane(rsb[n]);
    int end = __builtin_amdgcn_readfirstlane(rsb[n + 1]);
    int j = beg;
    for (; j + 4 <= end; j += 4){
        int s0 = cs[j], s1 = cs[j + 1], s2 = cs[j + 2], s3 = cs[j + 3];
        float e0 = es[s0], e1 = es[s1], e2 = es[s2], e3 = es[s3];
        float v0 = bfs(xl[(size_t)s0 * 64 + lane]);
        float v1 = bfs(xl[(size_t)s1 * 64 + lane]);
        float v2 = bfs(xl[(size_t)s2 * 64 + lane]);
        float v3 = bfs(xl[(size_t)s3 * 64 + lane]);
        float w0 = __expf(leaky02(e0 + edn));
        float w1 = __expf(leaky02(e1 + edn));
        float w2 = __expf(leaky02(e2 + edn));
        float w3 = __expf(leaky02(e3 + edn));
        denom += (w0 + w1) + (w2 + w3);
        acc += w0 * v0 + w1 * v1;
        acc += w2 * v2 + w3 * v3;
    }
    for (; j < end; ++j){
        int s = cs[j];
        float w = __expf(leaky02(es[s] + edn));
        denom += w;
        acc += w * bfs(xl[(size_t)s * 64 + lane]);
    }
    h2h[(size_t)br * N * 64 + (size_t)n * 64 + lane] = (unsigned short)f2bf(elu1(acc / denom + b2[lane]));
}

// segmented mean-pool: one block per (branch, graph), binary search on sorted batch
__global__ __launch_bounds__(256) void pool_kernel(
    const unsigned short* __restrict__ h2h,
    const int* __restrict__ batchb, const int* __restrict__ batcht,
    float* __restrict__ pooled, float* __restrict__ pcnt, int N){
    int br = blockIdx.x >> 6, g = blockIdx.x & 63;
    const int* batch = br ? batcht : batchb;
    int lo = 0, hi = N;
    while (lo < hi){ int mid = (lo + hi) >> 1; if (batch[mid] < g) lo = mid + 1; else hi = mid; }
    int beg = lo;
    hi = N;
    while (lo < hi){ int mid = (lo + hi) >> 1; if (batch[mid] < g + 1) lo = mid + 1; else hi = mid; }
    int end = lo;
    int t = threadIdx.x, wid = t >> 6, lane = t & 63;
    const unsigned short* h2 = h2h + (size_t)br * N * 64;
    float acc = 0.f;
    for (int n = beg + wid; n < end; n += 4) acc += bfs(h2[(size_t)n * 64 + lane]);
    __shared__ float red[256];
    red[t] = acc;
    __syncthreads();
    if (wid == 0){
        float s = red[lane] + red[64 + lane] + red[128 + lane] + red[192 + lane];
        pooled[((size_t)br * 64 + g) * 64 + lane] = s;
        if (lane == 0) pcnt[br * 64 + g] = (float)(end - beg);
    }
}

// both branch MLPs + combine + final head, one block
__global__ __launch_bounds__(1024) void tail_kernel(
    const float* __restrict__ pooled, const float* __restrict__ pcnt,
    const float* __restrict__ M1wb, const float* __restrict__ M1bb,
    const float* __restrict__ M2wb, const float* __restrict__ M2bb,
    const float* __restrict__ M1wt, const float* __restrict__ M1bt,
    const float* __restrict__ M2wt, const float* __restrict__ M2bt,
    const float* __restrict__ Fw1, const float* __restrict__ Fb1,
    const float* __restrict__ Fw2, const float* __restrict__ Fb2,
    float* __restrict__ out){
    __shared__ float P[8192];
    __shared__ float H[8192];
    int t = threadIdx.x;
    for (int i = t; i < 8192; i += 1024){
        int br = i >> 12, g = (i >> 6) & 63;
        P[i] = pooled[i] / fmaxf(pcnt[br * 64 + g], 1.f);
    }
    __syncthreads();
    for (int i = t; i < 8192; i += 1024){
        int br = i >> 12, r = (i >> 6) & 63, c = i & 63;
        const float* M1w = br ? M1wt : M1wb;
        const float* M1b = br ? M1bt : M1bb;
        float acc = M1b[c];
        int pb = (br << 12) + (r << 6);
        #pragma unroll 8
        for (int k = 0; k < 64; ++k) acc += P[pb + k] * M1w[(k << 6) + c];
        H[i] = fmaxf(acc, 0.f);
    }
    __syncthreads();
    for (int i = t; i < 8192; i += 1024){
        int br = i >> 12, r = (i >> 6) & 63, c = i & 63;
        const float* M2w = br ? M2wt : M2wb;
        const float* M2b = br ? M2bt : M2bb;
        float acc = M2b[c];
        int hb = (br << 12) + (r << 6);
        #pragma unroll 8
        for (int k = 0; k < 64; ++k) acc += H[hb + k] * M2w[(k << 6) + c];
        P[i] = acc;
    }
    __syncthreads();
    for (int i = t; i < 4096; i += 1024) H[i] = P[i] * P[4096 + i];
    __syncthreads();
    for (int i = t; i < 4096; i += 1024){
        int r = i >> 6, c = i & 63;
        float acc = Fb1[c];
        #pragma unroll 8
        for (int k = 0; k < 64; ++k) acc += H[(r << 6) + k] * Fw1[(k << 6) + c];
        P[i] = fmaxf(acc, 0.f);
    }
    __syncthreads();
    if (t < 128){
        int r = t >> 1, jc = t & 1;
        float acc = Fb2[jc];
        #pragma unroll 8
        for (int k = 0; k < 64; ++k) acc += P[(r << 6) + k] * Fw2[k * 2 + jc];
        out[t] = tanhf(acc);
    }
}

extern "C" void kernel_launch(void* const* d_in, const int* in_sizes, int n_in,
                              void* d_out, int out_size, void* d_ws, size_t ws_size,
                              hipStream_t stream){
    const int N = in_sizes[0] / 2;
    const int E = in_sizes[1] / 2;
    const int NB = (N + 511) >> BSH;   // nodes-per-bucket = 512, NB <= 128

    char* ws = (char*)d_ws;
    size_t off = 0;
    auto alloc = [&](size_t bytes) -> char* {
        char* p = ws + off;
        off += (bytes + 255) & ~(size_t)255;
        return p;
    };
    unsigned* XL1u = (unsigned*)alloc((size_t)2 * N * 64 * 4);  // aliased by XL2h later
    unsigned* H1u  = (unsigned*)alloc((size_t)2 * N * 64 * 4);  // aliased by EPAIR first, H2h later
    float* ES1 = (float*)alloc((size_t)2 * N * 2 * 4);
    float* ED1 = (float*)alloc((size_t)2 * N * 2 * 4);
    float* ES2 = (float*)alloc((size_t)2 * N * 4);
    float* ED2 = (float*)alloc((size_t)2 * N * 4);
    int* RS  = (int*)alloc((size_t)2 * (N + 1) * 4);
    int* CSR = (int*)alloc((size_t)2 * E * 4);
    int* BC  = (int*)alloc((size_t)4 * NB * 4);       // BCNT(2*NB) + BCUR(2*NB)
    int* BCNT = BC;
    int* BCUR = BC + 2 * NB;
    float* POOLED = (float*)alloc(8192 * 4);
    float* PCNT   = (float*)alloc(128 * 4);
    uint2* EPAIR = (uint2*)H1u;                        // dead before agg1 writes H1u
    unsigned short* XL2h = (unsigned short*)XL1u;      // alias (XL1u dead after agg1)
    unsigned short* H2h  = (unsigned short*)H1u;       // alias (H1u dead after feat2)

    const float* xb   = (const float*)d_in[0];
    const int*   eib  = (const int*)  d_in[1];
    const int*   batchb = (const int*)d_in[2];
    const float* W1b  = (const float*)d_in[3];
    const float* a1sb = (const float*)d_in[4];
    const float* a1db = (const float*)d_in[5];
    const float* b1b  = (const float*)d_in[6];
    const float* W2b  = (const float*)d_in[7];
    const float* a2sb = (const float*)d_in[8];
    const float* a2db = (const float*)d_in[9];
    const float* b2b  = (const float*)d_in[10];
    const float* M1wb = (const float*)d_in[11];
    const float* M1bb = (const float*)d_in[12];
    const float* M2wb = (const float*)d_in[13];
    const float* M2bb = (const float*)d_in[14];
    const float* xt   = (const float*)d_in[15];
    const int*   eit  = (const int*)  d_in[16];
    const int*   batcht = (const int*)d_in[17];
    const float* W1t  = (const float*)d_in[18];
    const float* a1st = (const float*)d_in[19];
    const float* a1dt = (const float*)d_in[20];
    const float* b1t  = (const float*)d_in[21];
    const float* W2t  = (const float*)d_in[22];
    const float* a2st = (const float*)d_in[23];
    const float* a2dt = (const float*)d_in[24];
    const float* b2t  = (const float*)d_in[25];
    const float* M1wt = (const float*)d_in[26];
    const float* M1bt = (const float*)d_in[27];
    const float* M2wt = (const float*)d_in[28];
    const float* M2bt = (const float*)d_in[29];
    const float* Fw1  = (const float*)d_in[30];
    const float* Fb1  = (const float*)d_in[31];
    const float* Fw2  = (const float*)d_in[32];
    const float* Fb2  = (const float*)d_in[33];

    const int nodeBlocks = (N + 3) / 4;
    const int histBlocks = (E + CHUNK - 1) / CHUNK;
    const int f2Blocks   = (N + 15) / 16;

    hipMemsetAsync(BC, 0, (size_t)4 * NB * 4, stream);
    pre_kernel<<<2 * histBlocks + 2 * nodeBlocks, 256, 0, stream>>>(
        xb, xt, W1b, W1t, a1sb, a1st, a1db, a1dt, eib, eit,
        XL1u, ES1, ED1, BCNT, N, E, NB, nodeBlocks, histBlocks);
    bin_kernel<<<2 * histBlocks, 256, 0, stream>>>(
        eib, eit, BCNT, BCUR, EPAIR, N, E, NB, histBlocks);
    csr_kernel<<<2 * NB, 256, 0, stream>>>(BCNT, EPAIR, RS, CSR, N, E, NB);
    agg1_kernel<<<2 * nodeBlocks, 256, 0, stream>>>(
        XL1u, ES1, ED1, CSR, RS, b1b, b1t, H1u, N, E, nodeBlocks);
    feat2_kernel<<<2 * f2Blocks, 256, 0, stream>>>(
        H1u, W2b, W2t, a2sb, a2st, a2db, a2dt, XL2h, ES2, ED2, N, f2Blocks);
    agg2_kernel<<<2 * nodeBlocks, 256, 0, stream>>>(
        XL2h, ES2, ED2, CSR, RS, b2b, b2t, H2h, N, E, nodeBlocks);
    pool_kernel<<<128, 256, 0, stream>>>(H2h, batchb, batcht, POOLED, PCNT, N);
    tail_kernel<<<1, 1024, 0, stream>>>(POOLED, PCNT,
        M1wb, M1bb, M2wb, M2bb, M1wt, M1bt, M2wt, M2bt,
        Fw1, Fb1, Fw2, Fb2, (float*)d_out);
}

// Round 4
// 338.290 us; speedup vs baseline: 2.7278x; 1.1448x over previous
//
#include <hip/hip_runtime.h>
#include <math.h>

// ---------------------------------------------------------------------------
// DeepONet/GAT: bf16 gather tables, single-pass softmax aggregation.
// CSR build: bucket-hist (in pre) -> bin (slot = LDS hist atomic, packed 4B
// bucket scatter, L2 write-combined) -> per-bucket CSR (window-local scatter).
// feat2 (h1 @ W2) runs on MFMA 16x16x32 bf16.
// Buckets: 512 nodes (BSH=9), NB <= 128 (N <= 65536). N assumed < 2^17.
// ---------------------------------------------------------------------------

#define BSH 9
#define CHUNK 4096

using short8v = __attribute__((ext_vector_type(8))) short;
using f32x4  = __attribute__((ext_vector_type(4))) float;

__device__ __forceinline__ float leaky02(float x){ return fmaxf(x, 0.2f * x); }
__device__ __forceinline__ float elu1(float x){ return x > 0.f ? x : expm1f(x); }
__device__ __forceinline__ unsigned f2bf(float a){
    unsigned u = __float_as_uint(a);
    return (u + 0x7FFFu + ((u >> 16) & 1u)) >> 16;
}
__device__ __forceinline__ unsigned packbf(float a, float b){ return f2bf(a) | (f2bf(b) << 16); }
__device__ __forceinline__ float bflo(unsigned p){ return __uint_as_float(p << 16); }
__device__ __forceinline__ float bfhi(unsigned p){ return __uint_as_float(p & 0xFFFF0000u); }
__device__ __forceinline__ float bfs(unsigned short s){ return __uint_as_float(((unsigned)s) << 16); }

__device__ __forceinline__ int wave_incl_scan(int v, int lane){
    #pragma unroll
    for (int d = 1; d < 64; d <<= 1){ int u = __shfl_up(v, (unsigned)d, 64); if (lane >= d) v += u; }
    return v;
}

// feat1 (both branches) + bucket histogram (both branches), grid-split.
__global__ __launch_bounds__(256) void pre_kernel(
    const float* __restrict__ xb, const float* __restrict__ xt,
    const float* __restrict__ W1b, const float* __restrict__ W1t,
    const float* __restrict__ a1sb, const float* __restrict__ a1st,
    const float* __restrict__ a1db, const float* __restrict__ a1dt,
    const int* __restrict__ eib, const int* __restrict__ eit,
    unsigned* __restrict__ xl1u, float* __restrict__ es1, float* __restrict__ ed1,
    int* __restrict__ bcnt, int N, int E, int NB, int nodeBlocks, int histBlocks){
    int bid = blockIdx.x;
    int tid = threadIdx.x;
    if (bid < 2 * histBlocks){
        int br = (bid >= histBlocks) ? 1 : 0;
        int cb = bid - br * histBlocks;
        const int* dstp = (br ? eit : eib) + E;
        __shared__ int hist[128];
        for (int i = tid; i < 128; i += 256) hist[i] = 0;
        __syncthreads();
        int start = cb * CHUNK, cnt = min(CHUNK, E - start);
        for (int i = tid; i < cnt; i += 256) atomicAdd(&hist[dstp[start + i] >> BSH], 1);
        __syncthreads();
        if (tid < NB && hist[tid]) atomicAdd(&bcnt[br * NB + tid], hist[tid]);
        return;
    }
    bid -= 2 * histBlocks;
    int br = (bid >= nodeBlocks) ? 1 : 0;
    int nb = bid - br * nodeBlocks;
    int n = (nb << 2) + (tid >> 6);
    int lane = tid & 63;
    if (n >= N) return;
    const float* x   = br ? xt   : xb;
    const float* W1  = br ? W1t  : W1b;
    const float* a1s = br ? a1st : a1sb;
    const float* a1d = br ? a1dt : a1db;
    float2 xv = ((const float2*)x)[n];
    float2 w0 = ((const float2*)W1)[lane];
    float2 w1 = ((const float2*)(W1 + 128))[lane];
    float xla = xv.x * w0.x + xv.y * w1.x;
    float xlb = xv.x * w0.y + xv.y * w1.y;
    xl1u[(size_t)br * N * 64 + (size_t)n * 64 + lane] = packbf(xla, xlb);
    float2 as = ((const float2*)a1s)[lane];
    float2 ad = ((const float2*)a1d)[lane];
    float ps = xla * as.x + xlb * as.y;
    float pd = xla * ad.x + xlb * ad.y;
    #pragma unroll
    for (int m = 16; m >= 1; m >>= 1){ ps += __shfl_xor(ps, m, 64); pd += __shfl_xor(pd, m, 64); }
    if ((lane & 31) == 0){
        int h = lane >> 5;
        es1[(size_t)br * N * 2 + n * 2 + h] = ps;
        ed1[(size_t)br * N * 2 + n * 2 + h] = pd;
    }
}

// slot = LDS hist atomic; packed (src<<9|dstlow) 4B scatter into bucket runs.
__global__ __launch_bounds__(256) void bin_kernel(
    const int* __restrict__ eib, const int* __restrict__ eit,
    const int* __restrict__ bcnt, int* __restrict__ bcur,
    unsigned* __restrict__ epair, int N, int E, int NB, int blocksPer){
    int bid = blockIdx.x;
    int br = (bid >= blocksPer) ? 1 : 0;
    int cb = bid - br * blocksPer;
    const int* ei = br ? eit : eib;
    int start = cb * CHUNK;
    int cnt = min(CHUNK, E - start);
    __shared__ int hist[128], gpos[128];
    __shared__ int slots[CHUNK];
    int tid = threadIdx.x, lane = tid & 63, wid = tid >> 6;
    for (int i = tid; i < 128; i += 256) hist[i] = 0;
    __syncthreads();
    const int* dstp = ei + E + start;
    const int* srcp = ei + start;
    for (int li = tid; li < cnt; li += 256){
        int b = dstp[li] >> BSH;
        slots[li] = atomicAdd(&hist[b], 1);
    }
    __syncthreads();
    if (wid == 0){
        int b0 = (lane < NB) ? bcnt[br * NB + lane] : 0;
        int b1 = (64 + lane < NB) ? bcnt[br * NB + 64 + lane] : 0;
        int g0 = wave_incl_scan(b0, lane); int gt = __shfl(g0, 63, 64);
        int g1 = wave_incl_scan(b1, lane);
        int base0 = g0 - b0, base1 = gt + g1 - b1;
        int h0 = hist[lane], h1v = hist[64 + lane];
        gpos[lane] = (h0 > 0) ? base0 + atomicAdd(&bcur[br * NB + lane], h0) : 0;
        gpos[64 + lane] = (h1v > 0) ? base1 + atomicAdd(&bcur[br * NB + 64 + lane], h1v) : 0;
    }
    __syncthreads();
    unsigned* ep = epair + (size_t)br * E;
    for (int li = tid; li < cnt; li += 256){
        int d = dstp[li];
        int b = d >> BSH;
        ep[gpos[b] + slots[li]] = ((unsigned)srcp[li] << BSH) | (unsigned)(d & ((1 << BSH) - 1));
    }
}

// per-bucket CSR: local degrees -> row starts (writes rs), scatter src.
__global__ __launch_bounds__(256) void csr_kernel(
    const int* __restrict__ bcnt, const unsigned* __restrict__ epair,
    int* __restrict__ rs, int* __restrict__ csr, int N, int E, int NB){
    int bid = blockIdx.x;
    int br = (bid >= NB) ? 1 : 0;
    int b = bid - br * NB;
    __shared__ int base2[128];
    __shared__ int deg[512], st[512];
    int tid = threadIdx.x, lane = tid & 63, wid = tid >> 6;
    if (wid == 0){
        int b0 = (lane < NB) ? bcnt[br * NB + lane] : 0;
        int b1 = (64 + lane < NB) ? bcnt[br * NB + 64 + lane] : 0;
        int g0 = wave_incl_scan(b0, lane); int gt = __shfl(g0, 63, 64);
        int g1 = wave_incl_scan(b1, lane);
        base2[lane] = g0 - b0; base2[64 + lane] = gt + g1 - b1;
    }
    for (int i = tid; i < 512; i += 256) deg[i] = 0;
    __syncthreads();
    int ebase = base2[b];
    int ecnt = bcnt[br * NB + b];
    int n0 = b << BSH;
    int nodes = min(512, N - n0);
    const unsigned* ep = epair + (size_t)br * E + ebase;
    for (int i = tid; i < ecnt; i += 256) atomicAdd(&deg[ep[i] & 511u], 1);
    __syncthreads();
    if (wid == 0){
        int carry = 0;
        #pragma unroll
        for (int c = 0; c < 8; ++c){
            int v = deg[c * 64 + lane];
            int s = wave_incl_scan(v, lane);
            st[c * 64 + lane] = carry + s - v;
            carry += __shfl(s, 63, 64);
        }
    }
    __syncthreads();
    int* rsb = rs + (size_t)br * (N + 1);
    for (int i = tid; i < nodes; i += 256) rsb[n0 + i] = ebase + st[i];
    if (b == NB - 1 && tid == 0) rsb[N] = ebase + ecnt;
    for (int i = tid; i < 512; i += 256) deg[i] = st[i];
    __syncthreads();
    int* csrb = csr + (size_t)br * E + ebase;
    for (int i = tid; i < ecnt; i += 256){
        unsigned p = ep[i];
        int pos = atomicAdd(&deg[p & 511u], 1);
        csrb[pos] = (int)(p >> BSH);
    }
}

// GAT layer-1 aggregation (H=2,C=64), single pass (no max-shift), bf16 gathers.
__global__ __launch_bounds__(256) void agg1_kernel(
    const unsigned* __restrict__ xl1u, const float* __restrict__ es1, const float* __restrict__ ed1,
    const int* __restrict__ csr, const int* __restrict__ rs,
    const float* __restrict__ b1b, const float* __restrict__ b1t,
    unsigned* __restrict__ h1u, int N, int E, int nodeBlocks){
    int bid = blockIdx.x;
    int br = (bid >= nodeBlocks) ? 1 : 0;
    int n = ((bid - br * nodeBlocks) << 2) + (threadIdx.x >> 6);
    int lane = threadIdx.x & 63;
    if (n >= N) return;
    const unsigned* xl = xl1u + (size_t)br * N * 64;
    const float* es = es1 + (size_t)br * N * 2;
    const float* ed = ed1 + (size_t)br * N * 2;
    const int* cs = csr + (size_t)br * E;
    const int* rsb = rs + (size_t)br * (N + 1);
    const float* b1 = br ? b1t : b1b;
    int h = lane >> 5;
    float edn = ed[n * 2 + h];
    float wself = __expf(leaky02(es[n * 2 + h] + edn));
    unsigned pself = xl[(size_t)n * 64 + lane];
    float denom = wself;
    float ax = wself * bflo(pself);
    float ay = wself * bfhi(pself);
    int beg = __builtin_amdgcn_readfirstlane(rsb[n]);
    int end = __builtin_amdgcn_readfirstlane(rsb[n + 1]);
    int j = beg;
    for (; j + 4 <= end; j += 4){
        int s0 = cs[j], s1 = cs[j + 1], s2 = cs[j + 2], s3 = cs[j + 3];
        float e0 = es[s0 * 2 + h], e1 = es[s1 * 2 + h], e2 = es[s2 * 2 + h], e3 = es[s3 * 2 + h];
        unsigned p0 = xl[(size_t)s0 * 64 + lane];
        unsigned p1 = xl[(size_t)s1 * 64 + lane];
        unsigned p2 = xl[(size_t)s2 * 64 + lane];
        unsigned p3 = xl[(size_t)s3 * 64 + lane];
        float w0 = __expf(leaky02(e0 + edn));
        float w1 = __expf(leaky02(e1 + edn));
        float w2 = __expf(leaky02(e2 + edn));
        float w3 = __expf(leaky02(e3 + edn));
        denom += (w0 + w1) + (w2 + w3);
        ax += w0 * bflo(p0); ay += w0 * bfhi(p0);
        ax += w1 * bflo(p1); ay += w1 * bfhi(p1);
        ax += w2 * bflo(p2); ay += w2 * bfhi(p2);
        ax += w3 * bflo(p3); ay += w3 * bfhi(p3);
    }
    for (; j < end; ++j){
        int s = cs[j];
        float w = __expf(leaky02(es[s * 2 + h] + edn));
        unsigned p = xl[(size_t)s * 64 + lane];
        denom += w;
        ax += w * bflo(p); ay += w * bfhi(p);
    }
    float inv = 1.f / denom;
    int c = lane << 1;
    float h0 = elu1(ax * inv + b1[c]);
    float h1v = elu1(ay * inv + b1[c + 1]);
    h1u[(size_t)br * N * 64 + (size_t)n * 64 + lane] = packbf(h0, h1v);
}

// xl2 = h1 @ W2 via MFMA 16x16x32 bf16. h1 is row-major bf16 [N][128].
// A-frag: lane l -> row (l&15), k=(l>>4)*8..+7 (one 16B global load).
// B-frag: W2 bf16 in LDS, held in regs across tiles. C/D: col=l&15, row=(l>>4)*4+reg.
__global__ __launch_bounds__(256) void feat2_kernel(
    const unsigned short* __restrict__ h1h,
    const float* __restrict__ W2b, const float* __restrict__ W2t,
    const float* __restrict__ a2sb, const float* __restrict__ a2st,
    const float* __restrict__ a2db, const float* __restrict__ a2dt,
    unsigned short* __restrict__ xl2h, float* __restrict__ es2, float* __restrict__ ed2,
    int N, int blocksPer){
    int bid = blockIdx.x;
    int br = (bid >= blocksPer) ? 1 : 0;
    int lb = bid - br * blocksPer;
    const float* W2  = br ? W2t  : W2b;
    const float* a2s = br ? a2st : a2sb;
    const float* a2d = br ? a2dt : a2db;
    __shared__ unsigned short w2s[128 * 64];
    __shared__ float a2sl[64], a2dl[64];
    int tid = threadIdx.x;
    for (int i = tid; i < 8192; i += 256) w2s[i] = (unsigned short)f2bf(W2[i]);
    if (tid < 64) a2sl[tid] = a2s[tid];
    else if (tid < 128) a2dl[tid - 64] = a2d[tid - 64];
    __syncthreads();
    int wid = tid >> 6, lane = tid & 63;
    int lr = lane & 15, lq = lane >> 4;
    // B fragments: bfr[ct][ks][j] = W2bf[ks*32 + lq*8 + j][ct*16 + lr]
    short8v bfr[4][4];
    #pragma unroll
    for (int ct = 0; ct < 4; ++ct)
        #pragma unroll
        for (int ks = 0; ks < 4; ++ks)
            #pragma unroll
            for (int j = 0; j < 8; ++j)
                bfr[ct][ks][j] = (short)w2s[(ks * 32 + lq * 8 + j) * 64 + ct * 16 + lr];
    const unsigned short* h1 = h1h + (size_t)br * N * 128;
    float s0 = a2sl[lr], s1 = a2sl[16 + lr], s2 = a2sl[32 + lr], s3 = a2sl[48 + lr];
    float d0 = a2dl[lr], d1 = a2dl[16 + lr], d2 = a2dl[32 + lr], d3 = a2dl[48 + lr];
    int ntiles = (N + 15) >> 4;
    int totalWaves = blocksPer * 4;
    for (int t = lb * 4 + wid; t < ntiles; t += totalWaves){
        int n0 = t << 4;
        int arow = n0 + lr;
        const short8v* ap = (const short8v*)(h1 + (size_t)min(arow, N - 1) * 128);
        short8v a0 = ap[lq], a1 = ap[4 + lq], a2v = ap[8 + lq], a3 = ap[12 + lq];
        f32x4 ac0 = {0.f, 0.f, 0.f, 0.f}, ac1 = ac0, ac2 = ac0, ac3 = ac0;
        #define MF(ACC, CT) \
            ACC = __builtin_amdgcn_mfma_f32_16x16x32_bf16(a0, bfr[CT][0], ACC, 0, 0, 0); \
            ACC = __builtin_amdgcn_mfma_f32_16x16x32_bf16(a1, bfr[CT][1], ACC, 0, 0, 0); \
            ACC = __builtin_amdgcn_mfma_f32_16x16x32_bf16(a2v, bfr[CT][2], ACC, 0, 0, 0); \
            ACC = __builtin_amdgcn_mfma_f32_16x16x32_bf16(a3, bfr[CT][3], ACC, 0, 0, 0);
        MF(ac0, 0) MF(ac1, 1) MF(ac2, 2) MF(ac3, 3)
        #undef MF
        #pragma unroll
        for (int reg = 0; reg < 4; ++reg){
            int n = n0 + lq * 4 + reg;
            bool ok = n < N;
            float v0 = ac0[reg], v1 = ac1[reg], v2 = ac2[reg], v3 = ac3[reg];
            if (ok){
                size_t o = (size_t)br * N * 64 + (size_t)n * 64;
                xl2h[o + lr]      = (unsigned short)f2bf(v0);
                xl2h[o + 16 + lr] = (unsigned short)f2bf(v1);
                xl2h[o + 32 + lr] = (unsigned short)f2bf(v2);
                xl2h[o + 48 + lr] = (unsigned short)f2bf(v3);
            }
            float ps = v0 * s0 + v1 * s1 + v2 * s2 + v3 * s3;
            float pd = v0 * d0 + v1 * d1 + v2 * d2 + v3 * d3;
            ps += __shfl_xor(ps, 1, 64); ps += __shfl_xor(ps, 2, 64);
            ps += __shfl_xor(ps, 4, 64); ps += __shfl_xor(ps, 8, 64);
            pd += __shfl_xor(pd, 1, 64); pd += __shfl_xor(pd, 2, 64);
            pd += __shfl_xor(pd, 4, 64); pd += __shfl_xor(pd, 8, 64);
            if (ok && lr == 0){
                es2[(size_t)br * N + n] = ps;
                ed2[(size_t)br * N + n] = pd;
            }
        }
    }
}

// GAT layer-2 aggregation (H=1,C=64), bf16 gathers, single pass.
__global__ __launch_bounds__(256) void agg2_kernel(
    const unsigned short* __restrict__ xl2h, const float* __restrict__ es2, const float* __restrict__ ed2,
    const int* __restrict__ csr, const int* __restrict__ rs,
    const float* __restrict__ b2b, const float* __restrict__ b2t,
    unsigned short* __restrict__ h2h, int N, int E, int nodeBlocks){
    int bid = blockIdx.x;
    int br = (bid >= nodeBlocks) ? 1 : 0;
    int n = ((bid - br * nodeBlocks) << 2) + (threadIdx.x >> 6);
    int lane = threadIdx.x & 63;
    if (n >= N) return;
    const unsigned short* xl = xl2h + (size_t)br * N * 64;
    const float* es = es2 + (size_t)br * N;
    const float* ed = ed2 + (size_t)br * N;
    const int* cs = csr + (size_t)br * E;
    const int* rsb = rs + (size_t)br * (N + 1);
    const float* b2 = br ? b2t : b2b;
    float edn = ed[n];
    float wself = __expf(leaky02(es[n] + edn));
    float denom = wself;
    float acc = wself * bfs(xl[(size_t)n * 64 + lane]);
    int beg = __builtin_amdgcn_readfirstlane(rsb[n]);
    int end = __builtin_amdgcn_readfirstlane(rsb[n + 1]);
    int j = beg;
    for (; j + 4 <= end; j += 4){
        int s0 = cs[j], s1 = cs[j + 1], s2 = cs[j + 2], s3 = cs[j + 3];
        float e0 = es[s0], e1 = es[s1], e2 = es[s2], e3 = es[s3];
        float v0 = bfs(xl[(size_t)s0 * 64 + lane]);
        float v1 = bfs(xl[(size_t)s1 * 64 + lane]);
        float v2 = bfs(xl[(size_t)s2 * 64 + lane]);
        float v3 = bfs(xl[(size_t)s3 * 64 + lane]);
        float w0 = __expf(leaky02(e0 + edn));
        float w1 = __expf(leaky02(e1 + edn));
        float w2 = __expf(leaky02(e2 + edn));
        float w3 = __expf(leaky02(e3 + edn));
        denom += (w0 + w1) + (w2 + w3);
        acc += w0 * v0 + w1 * v1;
        acc += w2 * v2 + w3 * v3;
    }
    for (; j < end; ++j){
        int s = cs[j];
        float w = __expf(leaky02(es[s] + edn));
        denom += w;
        acc += w * bfs(xl[(size_t)s * 64 + lane]);
    }
    h2h[(size_t)br * N * 64 + (size_t)n * 64 + lane] = (unsigned short)f2bf(elu1(acc / denom + b2[lane]));
}

// segmented mean-pool: one block per (branch, graph), binary search on sorted batch
__global__ __launch_bounds__(256) void pool_kernel(
    const unsigned short* __restrict__ h2h,
    const int* __restrict__ batchb, const int* __restrict__ batcht,
    float* __restrict__ pooled, float* __restrict__ pcnt, int N){
    int br = blockIdx.x >> 6, g = blockIdx.x & 63;
    const int* batch = br ? batcht : batchb;
    int lo = 0, hi = N;
    while (lo < hi){ int mid = (lo + hi) >> 1; if (batch[mid] < g) lo = mid + 1; else hi = mid; }
    int beg = lo;
    hi = N;
    while (lo < hi){ int mid = (lo + hi) >> 1; if (batch[mid] < g + 1) lo = mid + 1; else hi = mid; }
    int end = lo;
    int t = threadIdx.x, wid = t >> 6, lane = t & 63;
    const unsigned short* h2 = h2h + (size_t)br * N * 64;
    float acc = 0.f;
    for (int n = beg + wid; n < end; n += 4) acc += bfs(h2[(size_t)n * 64 + lane]);
    __shared__ float red[256];
    red[t] = acc;
    __syncthreads();
    if (wid == 0){
        float s = red[lane] + red[64 + lane] + red[128 + lane] + red[192 + lane];
        pooled[((size_t)br * 64 + g) * 64 + lane] = s;
        if (lane == 0) pcnt[br * 64 + g] = (float)(end - beg);
    }
}

// both branch MLPs + combine + final head, one block
__global__ __launch_bounds__(1024) void tail_kernel(
    const float* __restrict__ pooled, const float* __restrict__ pcnt,
    const float* __restrict__ M1wb, const float* __restrict__ M1bb,
    const float* __restrict__ M2wb, const float* __restrict__ M2bb,
    const float* __restrict__ M1wt, const float* __restrict__ M1bt,
    const float* __restrict__ M2wt, const float* __restrict__ M2bt,
    const float* __restrict__ Fw1, const float* __restrict__ Fb1,
    const float* __restrict__ Fw2, const float* __restrict__ Fb2,
    float* __restrict__ out){
    __shared__ float P[8192];
    __shared__ float H[8192];
    int t = threadIdx.x;
    for (int i = t; i < 8192; i += 1024){
        int br = i >> 12, g = (i >> 6) & 63;
        P[i] = pooled[i] / fmaxf(pcnt[br * 64 + g], 1.f);
    }
    __syncthreads();
    for (int i = t; i < 8192; i += 1024){
        int br = i >> 12, r = (i >> 6) & 63, c = i & 63;
        const float* M1w = br ? M1wt : M1wb;
        const float* M1b = br ? M1bt : M1bb;
        float acc = M1b[c];
        int pb = (br << 12) + (r << 6);
        #pragma unroll 8
        for (int k = 0; k < 64; ++k) acc += P[pb + k] * M1w[(k << 6) + c];
        H[i] = fmaxf(acc, 0.f);
    }
    __syncthreads();
    for (int i = t; i < 8192; i += 1024){
        int br = i >> 12, r = (i >> 6) & 63, c = i & 63;
        const float* M2w = br ? M2wt : M2wb;
        const float* M2b = br ? M2bt : M2bb;
        float acc = M2b[c];
        int hb = (br << 12) + (r << 6);
        #pragma unroll 8
        for (int k = 0; k < 64; ++k) acc += H[hb + k] * M2w[(k << 6) + c];
        P[i] = acc;
    }
    __syncthreads();
    for (int i = t; i < 4096; i += 1024) H[i] = P[i] * P[4096 + i];
    __syncthreads();
    for (int i = t; i < 4096; i += 1024){
        int r = i >> 6, c = i & 63;
        float acc = Fb1[c];
        #pragma unroll 8
        for (int k = 0; k < 64; ++k) acc += H[(r << 6) + k] * Fw1[(k << 6) + c];
        P[i] = fmaxf(acc, 0.f);
    }
    __syncthreads();
    if (t < 128){
        int r = t >> 1, jc = t & 1;
        float acc = Fb2[jc];
        #pragma unroll 8
        for (int k = 0; k < 64; ++k) acc += P[(r << 6) + k] * Fw2[k * 2 + jc];
        out[t] = tanhf(acc);
    }
}

extern "C" void kernel_launch(void* const* d_in, const int* in_sizes, int n_in,
                              void* d_out, int out_size, void* d_ws, size_t ws_size,
                              hipStream_t stream){
    const int N = in_sizes[0] / 2;
    const int E = in_sizes[1] / 2;
    const int NB = (N + 511) >> BSH;   // nodes-per-bucket = 512, NB <= 128

    char* ws = (char*)d_ws;
    size_t off = 0;
    auto alloc = [&](size_t bytes) -> char* {
        char* p = ws + off;
        off += (bytes + 255) & ~(size_t)255;
        return p;
    };
    unsigned* XL1u = (unsigned*)alloc((size_t)2 * N * 64 * 4);  // aliased by XL2h later
    unsigned* H1u  = (unsigned*)alloc((size_t)2 * N * 64 * 4);  // aliased by EPAIR first, H2h later
    float* ES1 = (float*)alloc((size_t)2 * N * 2 * 4);
    float* ED1 = (float*)alloc((size_t)2 * N * 2 * 4);
    float* ES2 = (float*)alloc((size_t)2 * N * 4);
    float* ED2 = (float*)alloc((size_t)2 * N * 4);
    int* RS  = (int*)alloc((size_t)2 * (N + 1) * 4);
    int* CSR = (int*)alloc((size_t)2 * E * 4);
    int* BC  = (int*)alloc((size_t)4 * NB * 4);       // BCNT(2*NB) + BCUR(2*NB)
    int* BCNT = BC;
    int* BCUR = BC + 2 * NB;
    float* POOLED = (float*)alloc(8192 * 4);
    float* PCNT   = (float*)alloc(128 * 4);
    unsigned* EPAIR = (unsigned*)H1u;                  // dead before agg1 writes H1u
    unsigned short* XL2h = (unsigned short*)XL1u;      // alias (XL1u dead after agg1)
    unsigned short* H2h  = (unsigned short*)H1u;       // alias (H1u dead after feat2)

    const float* xb   = (const float*)d_in[0];
    const int*   eib  = (const int*)  d_in[1];
    const int*   batchb = (const int*)d_in[2];
    const float* W1b  = (const float*)d_in[3];
    const float* a1sb = (const float*)d_in[4];
    const float* a1db = (const float*)d_in[5];
    const float* b1b  = (const float*)d_in[6];
    const float* W2b  = (const float*)d_in[7];
    const float* a2sb = (const float*)d_in[8];
    const float* a2db = (const float*)d_in[9];
    const float* b2b  = (const float*)d_in[10];
    const float* M1wb = (const float*)d_in[11];
    const float* M1bb = (const float*)d_in[12];
    const float* M2wb = (const float*)d_in[13];
    const float* M2bb = (const float*)d_in[14];
    const float* xt   = (const float*)d_in[15];
    const int*   eit  = (const int*)  d_in[16];
    const int*   batcht = (const int*)d_in[17];
    const float* W1t  = (const float*)d_in[18];
    const float* a1st = (const float*)d_in[19];
    const float* a1dt = (const float*)d_in[20];
    const float* b1t  = (const float*)d_in[21];
    const float* W2t  = (const float*)d_in[22];
    const float* a2st = (const float*)d_in[23];
    const float* a2dt = (const float*)d_in[24];
    const float* b2t  = (const float*)d_in[25];
    const float* M1wt = (const float*)d_in[26];
    const float* M1bt = (const float*)d_in[27];
    const float* M2wt = (const float*)d_in[28];
    const float* M2bt = (const float*)d_in[29];
    const float* Fw1  = (const float*)d_in[30];
    const float* Fb1  = (const float*)d_in[31];
    const float* Fw2  = (const float*)d_in[32];
    const float* Fb2  = (const float*)d_in[33];

    const int nodeBlocks = (N + 3) / 4;
    const int histBlocks = (E + CHUNK - 1) / CHUNK;
    const int F2B = 64;   // feat2 blocks per branch

    hipMemsetAsync(BC, 0, (size_t)4 * NB * 4, stream);
    pre_kernel<<<2 * histBlocks + 2 * nodeBlocks, 256, 0, stream>>>(
        xb, xt, W1b, W1t, a1sb, a1st, a1db, a1dt, eib, eit,
        XL1u, ES1, ED1, BCNT, N, E, NB, nodeBlocks, histBlocks);
    bin_kernel<<<2 * histBlocks, 256, 0, stream>>>(
        eib, eit, BCNT, BCUR, EPAIR, N, E, NB, histBlocks);
    csr_kernel<<<2 * NB, 256, 0, stream>>>(BCNT, EPAIR, RS, CSR, N, E, NB);
    agg1_kernel<<<2 * nodeBlocks, 256, 0, stream>>>(
        XL1u, ES1, ED1, CSR, RS, b1b, b1t, H1u, N, E, nodeBlocks);
    feat2_kernel<<<2 * F2B, 256, 0, stream>>>(
        (const unsigned short*)H1u, W2b, W2t, a2sb, a2st, a2db, a2dt,
        XL2h, ES2, ED2, N, F2B);
    agg2_kernel<<<2 * nodeBlocks, 256, 0, stream>>>(
        XL2h, ES2, ED2, CSR, RS, b2b, b2t, H2h, N, E, nodeBlocks);
    pool_kernel<<<128, 256, 0, stream>>>(H2h, batchb, batcht, POOLED, PCNT, N);
    tail_kernel<<<1, 1024, 0, stream>>>(POOLED, PCNT,
        M1wb, M1bb, M2wb, M2bb, M1wt, M1bt, M2wt, M2bt,
        Fw1, Fb1, Fw2, Fb2, (float*)d_out);
}

// Round 5
// 301.473 us; speedup vs baseline: 3.0609x; 1.1221x over previous
//
#include <hip/hip_runtime.h>
#include <math.h>

// ---------------------------------------------------------------------------
// DeepONet/GAT, fused pipeline:
//   pre   : feat1 (x@W1 -> xl1 bf16) + attention logits + bucket histogram
//   bin   : edge bucket-sort (LDS slot alloc, packed 4B scatter)
//   csr   : per-bucket CSR build (window-local scatter)
//   a1f2  : GAT1 aggregation (gather, softmax-free-max) -> h1 in LDS
//           -> MFMA h1@W2 -> xl2 bf16 + layer-2 logits   (h1 never global)
//   a2pl  : GAT2 aggregation -> per-graph pooled sums via block atomics
//   tail  : counts via binary search + branch MLPs + combine + final head
// Buckets: 512 nodes (BSH=9), NB <= 128 (N <= 65536).
// ---------------------------------------------------------------------------

#define BSH 9
#define CHUNK 4096

using short8v = __attribute__((ext_vector_type(8))) short;
using f32x4  = __attribute__((ext_vector_type(4))) float;

__device__ __forceinline__ float leaky02(float x){ return fmaxf(x, 0.2f * x); }
__device__ __forceinline__ float elu1(float x){ return x > 0.f ? x : expm1f(x); }
__device__ __forceinline__ unsigned f2bf(float a){
    unsigned u = __float_as_uint(a);
    return (u + 0x7FFFu + ((u >> 16) & 1u)) >> 16;
}
__device__ __forceinline__ unsigned packbf(float a, float b){ return f2bf(a) | (f2bf(b) << 16); }
__device__ __forceinline__ float bflo(unsigned p){ return __uint_as_float(p << 16); }
__device__ __forceinline__ float bfhi(unsigned p){ return __uint_as_float(p & 0xFFFF0000u); }
__device__ __forceinline__ float bfs(unsigned short s){ return __uint_as_float(((unsigned)s) << 16); }

__device__ __forceinline__ int wave_incl_scan(int v, int lane){
    #pragma unroll
    for (int d = 1; d < 64; d <<= 1){ int u = __shfl_up(v, (unsigned)d, 64); if (lane >= d) v += u; }
    return v;
}

// feat1 (both branches) + bucket histogram (both branches), grid-split.
__global__ __launch_bounds__(256) void pre_kernel(
    const float* __restrict__ xb, const float* __restrict__ xt,
    const float* __restrict__ W1b, const float* __restrict__ W1t,
    const float* __restrict__ a1sb, const float* __restrict__ a1st,
    const float* __restrict__ a1db, const float* __restrict__ a1dt,
    const int* __restrict__ eib, const int* __restrict__ eit,
    unsigned* __restrict__ xl1u, float* __restrict__ es1, float* __restrict__ ed1,
    int* __restrict__ bcnt, int N, int E, int NB, int nodeBlocks, int histBlocks){
    int bid = blockIdx.x;
    int tid = threadIdx.x;
    if (bid < 2 * histBlocks){
        int br = (bid >= histBlocks) ? 1 : 0;
        int cb = bid - br * histBlocks;
        const int* dstp = (br ? eit : eib) + E;
        __shared__ int hist[128];
        for (int i = tid; i < 128; i += 256) hist[i] = 0;
        __syncthreads();
        int start = cb * CHUNK, cnt = min(CHUNK, E - start);
        for (int i = tid; i < cnt; i += 256) atomicAdd(&hist[dstp[start + i] >> BSH], 1);
        __syncthreads();
        if (tid < NB && hist[tid]) atomicAdd(&bcnt[br * NB + tid], hist[tid]);
        return;
    }
    bid -= 2 * histBlocks;
    int br = (bid >= nodeBlocks) ? 1 : 0;
    int nb = bid - br * nodeBlocks;
    int n = (nb << 2) + (tid >> 6);
    int lane = tid & 63;
    if (n >= N) return;
    const float* x   = br ? xt   : xb;
    const float* W1  = br ? W1t  : W1b;
    const float* a1s = br ? a1st : a1sb;
    const float* a1d = br ? a1dt : a1db;
    float2 xv = ((const float2*)x)[n];
    float2 w0 = ((const float2*)W1)[lane];
    float2 w1 = ((const float2*)(W1 + 128))[lane];
    float xla = xv.x * w0.x + xv.y * w1.x;
    float xlb = xv.x * w0.y + xv.y * w1.y;
    xl1u[(size_t)br * N * 64 + (size_t)n * 64 + lane] = packbf(xla, xlb);
    float2 as = ((const float2*)a1s)[lane];
    float2 ad = ((const float2*)a1d)[lane];
    float ps = xla * as.x + xlb * as.y;
    float pd = xla * ad.x + xlb * ad.y;
    #pragma unroll
    for (int m = 16; m >= 1; m >>= 1){ ps += __shfl_xor(ps, m, 64); pd += __shfl_xor(pd, m, 64); }
    if ((lane & 31) == 0){
        int h = lane >> 5;
        es1[(size_t)br * N * 2 + n * 2 + h] = ps;
        ed1[(size_t)br * N * 2 + n * 2 + h] = pd;
    }
}

// slot = LDS hist atomic; packed (src<<9|dstlow) 4B scatter into bucket runs.
__global__ __launch_bounds__(256) void bin_kernel(
    const int* __restrict__ eib, const int* __restrict__ eit,
    const int* __restrict__ bcnt, int* __restrict__ bcur,
    unsigned* __restrict__ epair, int N, int E, int NB, int blocksPer){
    int bid = blockIdx.x;
    int br = (bid >= blocksPer) ? 1 : 0;
    int cb = bid - br * blocksPer;
    const int* ei = br ? eit : eib;
    int start = cb * CHUNK;
    int cnt = min(CHUNK, E - start);
    __shared__ int hist[128], gpos[128];
    __shared__ int slots[CHUNK];
    int tid = threadIdx.x, lane = tid & 63, wid = tid >> 6;
    for (int i = tid; i < 128; i += 256) hist[i] = 0;
    __syncthreads();
    const int* dstp = ei + E + start;
    const int* srcp = ei + start;
    for (int li = tid; li < cnt; li += 256){
        int b = dstp[li] >> BSH;
        slots[li] = atomicAdd(&hist[b], 1);
    }
    __syncthreads();
    if (wid == 0){
        int b0 = (lane < NB) ? bcnt[br * NB + lane] : 0;
        int b1 = (64 + lane < NB) ? bcnt[br * NB + 64 + lane] : 0;
        int g0 = wave_incl_scan(b0, lane); int gt = __shfl(g0, 63, 64);
        int g1 = wave_incl_scan(b1, lane);
        int base0 = g0 - b0, base1 = gt + g1 - b1;
        int h0 = hist[lane], h1v = hist[64 + lane];
        gpos[lane] = (h0 > 0) ? base0 + atomicAdd(&bcur[br * NB + lane], h0) : 0;
        gpos[64 + lane] = (h1v > 0) ? base1 + atomicAdd(&bcur[br * NB + 64 + lane], h1v) : 0;
    }
    __syncthreads();
    unsigned* ep = epair + (size_t)br * E;
    for (int li = tid; li < cnt; li += 256){
        int d = dstp[li];
        int b = d >> BSH;
        ep[gpos[b] + slots[li]] = ((unsigned)srcp[li] << BSH) | (unsigned)(d & ((1 << BSH) - 1));
    }
}

// per-bucket CSR: local degrees -> row starts (writes rs), scatter src.
__global__ __launch_bounds__(256) void csr_kernel(
    const int* __restrict__ bcnt, const unsigned* __restrict__ epair,
    int* __restrict__ rs, int* __restrict__ csr, int N, int E, int NB){
    int bid = blockIdx.x;
    int br = (bid >= NB) ? 1 : 0;
    int b = bid - br * NB;
    __shared__ int base2[128];
    __shared__ int deg[512], st[512];
    int tid = threadIdx.x, lane = tid & 63, wid = tid >> 6;
    if (wid == 0){
        int b0 = (lane < NB) ? bcnt[br * NB + lane] : 0;
        int b1 = (64 + lane < NB) ? bcnt[br * NB + 64 + lane] : 0;
        int g0 = wave_incl_scan(b0, lane); int gt = __shfl(g0, 63, 64);
        int g1 = wave_incl_scan(b1, lane);
        base2[lane] = g0 - b0; base2[64 + lane] = gt + g1 - b1;
    }
    for (int i = tid; i < 512; i += 256) deg[i] = 0;
    __syncthreads();
    int ebase = base2[b];
    int ecnt = bcnt[br * NB + b];
    int n0 = b << BSH;
    int nodes = min(512, N - n0);
    const unsigned* ep = epair + (size_t)br * E + ebase;
    for (int i = tid; i < ecnt; i += 256) atomicAdd(&deg[ep[i] & 511u], 1);
    __syncthreads();
    if (wid == 0){
        int carry = 0;
        #pragma unroll
        for (int c = 0; c < 8; ++c){
            int v = deg[c * 64 + lane];
            int s = wave_incl_scan(v, lane);
            st[c * 64 + lane] = carry + s - v;
            carry += __shfl(s, 63, 64);
        }
    }
    __syncthreads();
    int* rsb = rs + (size_t)br * (N + 1);
    for (int i = tid; i < nodes; i += 256) rsb[n0 + i] = ebase + st[i];
    if (b == NB - 1 && tid == 0) rsb[N] = ebase + ecnt;
    for (int i = tid; i < 512; i += 256) deg[i] = st[i];
    __syncthreads();
    int* csrb = csr + (size_t)br * E + ebase;
    for (int i = tid; i < ecnt; i += 256){
        unsigned p = ep[i];
        int pos = atomicAdd(&deg[p & 511u], 1);
        csrb[pos] = (int)(p >> BSH);
    }
}

// Fused GAT1 aggregation + (h1 @ W2) MFMA + layer-2 logits.
// Block = 16 nodes: 4 waves x 4 nodes serial agg (h1 -> LDS), then each wave
// computes a 16-col tile of xl2 via mfma_f32_16x16x32_bf16.
__global__ __launch_bounds__(256) void a1f2_kernel(
    const unsigned* __restrict__ xl1u, const float* __restrict__ es1, const float* __restrict__ ed1,
    const int* __restrict__ csr, const int* __restrict__ rs,
    const float* __restrict__ b1b, const float* __restrict__ b1t,
    const float* __restrict__ W2b, const float* __restrict__ W2t,
    const float* __restrict__ a2sb, const float* __restrict__ a2st,
    const float* __restrict__ a2db, const float* __restrict__ a2dt,
    unsigned short* __restrict__ xl2h, float* __restrict__ es2, float* __restrict__ ed2,
    int N, int E, int tilesPer){
    int bid = blockIdx.x;
    int br = (bid >= tilesPer) ? 1 : 0;
    int n0 = (bid - br * tilesPer) << 4;
    const unsigned* xl = xl1u + (size_t)br * N * 64;
    const float* es = es1 + (size_t)br * N * 2;
    const float* ed = ed1 + (size_t)br * N * 2;
    const int* cs = csr + (size_t)br * E;
    const int* rsb = rs + (size_t)br * (N + 1);
    const float* b1 = br ? b1t : b1b;
    const float* W2 = br ? W2t : W2b;
    const float* a2s = br ? a2st : a2sb;
    const float* a2d = br ? a2dt : a2db;

    __shared__ unsigned short w2s[8192];     // W2 bf16 [128][64]
    __shared__ unsigned hl[16][64];          // h1 tile, packed bf16 pairs
    __shared__ float psa[4][16], pda[4][16];
    int tid = threadIdx.x, lane = tid & 63, w = tid >> 6;
    for (int i = tid; i < 8192; i += 256) w2s[i] = (unsigned short)f2bf(W2[i]);

    int h = lane >> 5;
    int c = lane << 1;
    float b1lo = b1[c], b1hi = b1[c + 1];
    #pragma unroll
    for (int nn = 0; nn < 4; ++nn){
        int row = w * 4 + nn;
        int n = n0 + row;
        if (n >= N){ hl[row][lane] = 0u; continue; }
        float edn = ed[n * 2 + h];
        float wself = __expf(leaky02(es[n * 2 + h] + edn));
        unsigned pself = xl[(size_t)n * 64 + lane];
        float denom = wself;
        float ax = wself * bflo(pself);
        float ay = wself * bfhi(pself);
        int beg = __builtin_amdgcn_readfirstlane(rsb[n]);
        int end = __builtin_amdgcn_readfirstlane(rsb[n + 1]);
        int j = beg;
        for (; j + 8 <= end; j += 8){
            int ss[8]; unsigned pp[8]; float ee[8];
            #pragma unroll
            for (int q = 0; q < 8; ++q) ss[q] = cs[j + q];
            #pragma unroll
            for (int q = 0; q < 8; ++q){
                ee[q] = es[ss[q] * 2 + h];
                pp[q] = xl[(size_t)ss[q] * 64 + lane];
            }
            #pragma unroll
            for (int q = 0; q < 8; ++q){
                float wq = __expf(leaky02(ee[q] + edn));
                denom += wq;
                ax += wq * bflo(pp[q]);
                ay += wq * bfhi(pp[q]);
            }
        }
        for (; j < end; ++j){
            int s = cs[j];
            float wq = __expf(leaky02(es[s * 2 + h] + edn));
            unsigned p = xl[(size_t)s * 64 + lane];
            denom += wq;
            ax += wq * bflo(p);
            ay += wq * bfhi(p);
        }
        float inv = 1.f / denom;
        hl[row][lane] = packbf(elu1(ax * inv + b1lo), elu1(ay * inv + b1hi));
    }
    __syncthreads();

    int lr = lane & 15, lq = lane >> 4;
    // B fragments for this wave's 16-col tile
    short8v bfr[4];
    #pragma unroll
    for (int ks = 0; ks < 4; ++ks)
        #pragma unroll
        for (int j = 0; j < 8; ++j)
            bfr[ks][j] = (short)w2s[(ks * 32 + lq * 8 + j) * 64 + w * 16 + lr];
    f32x4 ac = {0.f, 0.f, 0.f, 0.f};
    #pragma unroll
    for (int ks = 0; ks < 4; ++ks){
        short8v av = *(const short8v*)&hl[lr][ks * 16 + lq * 4];
        ac = __builtin_amdgcn_mfma_f32_16x16x32_bf16(av, bfr[ks], ac, 0, 0, 0);
    }
    float a2sv = a2s[w * 16 + lr];
    float a2dv = a2d[w * 16 + lr];
    #pragma unroll
    for (int reg = 0; reg < 4; ++reg){
        int r = lq * 4 + reg;
        int n = n0 + r;
        float v = ac[reg];
        if (n < N)
            xl2h[((size_t)br * N + n) * 64 + w * 16 + lr] = (unsigned short)f2bf(v);
        float ps = v * a2sv, pd = v * a2dv;
        ps += __shfl_xor(ps, 1, 64); ps += __shfl_xor(ps, 2, 64);
        ps += __shfl_xor(ps, 4, 64); ps += __shfl_xor(ps, 8, 64);
        pd += __shfl_xor(pd, 1, 64); pd += __shfl_xor(pd, 2, 64);
        pd += __shfl_xor(pd, 4, 64); pd += __shfl_xor(pd, 8, 64);
        if (lr == 0){ psa[w][r] = ps; pda[w][r] = pd; }
    }
    __syncthreads();
    if (tid < 16){
        int n = n0 + tid;
        if (n < N)
            es2[(size_t)br * N + n] = psa[0][tid] + psa[1][tid] + psa[2][tid] + psa[3][tid];
    } else if (tid < 32){
        int r = tid - 16;
        int n = n0 + r;
        if (n < N)
            ed2[(size_t)br * N + n] = pda[0][r] + pda[1][r] + pda[2][r] + pda[3][r];
    }
}

// Fused GAT2 aggregation + per-graph pooled sums (block-level atomics).
__global__ __launch_bounds__(256) void a2pl_kernel(
    const unsigned short* __restrict__ xl2h, const float* __restrict__ es2, const float* __restrict__ ed2,
    const int* __restrict__ csr, const int* __restrict__ rs,
    const float* __restrict__ b2b, const float* __restrict__ b2t,
    const int* __restrict__ batchb, const int* __restrict__ batcht,
    float* __restrict__ pooled, int N, int E, int nodeBlocks){
    int bid = blockIdx.x;
    int br = (bid >= nodeBlocks) ? 1 : 0;
    int tid = threadIdx.x, lane = tid & 63, w = tid >> 6;
    int n = ((bid - br * nodeBlocks) << 2) + w;
    const unsigned short* xlt = xl2h + (size_t)br * N * 64;
    const float* es = es2 + (size_t)br * N;
    const float* ed = ed2 + (size_t)br * N;
    const int* cs = csr + (size_t)br * E;
    const int* rsb = rs + (size_t)br * (N + 1);
    const float* b2 = br ? b2t : b2b;
    const int* batch = br ? batcht : batchb;
    float hv = 0.f;
    int g = -1;
    if (n < N){
        float edn = ed[n];
        float wself = __expf(leaky02(es[n] + edn));
        float denom = wself;
        float acc = wself * bfs(xlt[(size_t)n * 64 + lane]);
        int beg = __builtin_amdgcn_readfirstlane(rsb[n]);
        int end = __builtin_amdgcn_readfirstlane(rsb[n + 1]);
        int j = beg;
        for (; j + 8 <= end; j += 8){
            int ss[8]; float ee[8], vv[8];
            #pragma unroll
            for (int q = 0; q < 8; ++q) ss[q] = cs[j + q];
            #pragma unroll
            for (int q = 0; q < 8; ++q){
                ee[q] = es[ss[q]];
                vv[q] = bfs(xlt[(size_t)ss[q] * 64 + lane]);
            }
            #pragma unroll
            for (int q = 0; q < 8; ++q){
                float wq = __expf(leaky02(ee[q] + edn));
                denom += wq;
                acc += wq * vv[q];
            }
        }
        for (; j < end; ++j){
            int s = cs[j];
            float wq = __expf(leaky02(es[s] + edn));
            denom += wq;
            acc += wq * bfs(xlt[(size_t)s * 64 + lane]);
        }
        hv = elu1(acc / denom + b2[lane]);
        g = batch[n];
    }
    __shared__ float red[4][64];
    __shared__ int gid[4];
    red[w][lane] = hv;
    if (lane == 0) gid[w] = g;
    __syncthreads();
    if (w == 0){
        int g0 = gid[0], g1 = gid[1], g2 = gid[2], g3 = gid[3];
        float* pb = pooled + (size_t)br * 4096;
        if (g0 >= 0 && g0 == g1 && g1 == g2 && g2 == g3){
            float s = (red[0][lane] + red[1][lane]) + (red[2][lane] + red[3][lane]);
            atomicAdd(&pb[g0 * 64 + lane], s);
        } else {
            #pragma unroll
            for (int q = 0; q < 4; ++q)
                if (gid[q] >= 0) atomicAdd(&pb[gid[q] * 64 + lane], red[q][lane]);
        }
    }
}

// counts (binary search on sorted batch) + branch MLPs + combine + final head
__global__ __launch_bounds__(1024) void tail_kernel(
    const float* __restrict__ pooled,
    const int* __restrict__ batchb, const int* __restrict__ batcht,
    const float* __restrict__ M1wb, const float* __restrict__ M1bb,
    const float* __restrict__ M2wb, const float* __restrict__ M2bb,
    const float* __restrict__ M1wt, const float* __restrict__ M1bt,
    const float* __restrict__ M2wt, const float* __restrict__ M2bt,
    const float* __restrict__ Fw1, const float* __restrict__ Fb1,
    const float* __restrict__ Fw2, const float* __restrict__ Fb2,
    float* __restrict__ out, int N){
    __shared__ float P[8192];
    __shared__ float H[8192];
    __shared__ float cl[128];
    int t = threadIdx.x;
    if (t < 128){
        int br = t >> 6, g = t & 63;
        const int* batch = br ? batcht : batchb;
        int lo = 0, hi = N;
        while (lo < hi){ int mid = (lo + hi) >> 1; if (batch[mid] < g) lo = mid + 1; else hi = mid; }
        int beg = lo;
        hi = N;
        while (lo < hi){ int mid = (lo + hi) >> 1; if (batch[mid] < g + 1) lo = mid + 1; else hi = mid; }
        cl[t] = (float)(lo - beg);
    }
    __syncthreads();
    for (int i = t; i < 8192; i += 1024)
        P[i] = pooled[i] / fmaxf(cl[i >> 6], 1.f);
    __syncthreads();
    for (int i = t; i < 8192; i += 1024){
        int br = i >> 12, r = (i >> 6) & 63, c = i & 63;
        const float* M1w = br ? M1wt : M1wb;
        const float* M1b = br ? M1bt : M1bb;
        float acc = M1b[c];
        int pb = (br << 12) + (r << 6);
        #pragma unroll 8
        for (int k = 0; k < 64; ++k) acc += P[pb + k] * M1w[(k << 6) + c];
        H[i] = fmaxf(acc, 0.f);
    }
    __syncthreads();
    for (int i = t; i < 8192; i += 1024){
        int br = i >> 12, r = (i >> 6) & 63, c = i & 63;
        const float* M2w = br ? M2wt : M2wb;
        const float* M2b = br ? M2bt : M2bb;
        float acc = M2b[c];
        int hb = (br << 12) + (r << 6);
        #pragma unroll 8
        for (int k = 0; k < 64; ++k) acc += H[hb + k] * M2w[(k << 6) + c];
        P[i] = acc;
    }
    __syncthreads();
    for (int i = t; i < 4096; i += 1024) H[i] = P[i] * P[4096 + i];
    __syncthreads();
    for (int i = t; i < 4096; i += 1024){
        int r = i >> 6, c = i & 63;
        float acc = Fb1[c];
        #pragma unroll 8
        for (int k = 0; k < 64; ++k) acc += H[(r << 6) + k] * Fw1[(k << 6) + c];
        P[i] = fmaxf(acc, 0.f);
    }
    __syncthreads();
    if (t < 128){
        int r = t >> 1, jc = t & 1;
        float acc = Fb2[jc];
        #pragma unroll 8
        for (int k = 0; k < 64; ++k) acc += P[(r << 6) + k] * Fw2[k * 2 + jc];
        out[t] = tanhf(acc);
    }
}

extern "C" void kernel_launch(void* const* d_in, const int* in_sizes, int n_in,
                              void* d_out, int out_size, void* d_ws, size_t ws_size,
                              hipStream_t stream){
    const int N = in_sizes[0] / 2;
    const int E = in_sizes[1] / 2;
    const int NB = (N + 511) >> BSH;   // nodes-per-bucket = 512, NB <= 128

    char* ws = (char*)d_ws;
    size_t off = 0;
    auto alloc = [&](size_t bytes) -> char* {
        char* p = ws + off;
        off += (bytes + 255) & ~(size_t)255;
        return p;
    };
    unsigned* XL1u = (unsigned*)alloc((size_t)2 * N * 64 * 4);
    unsigned short* XL2h = (unsigned short*)alloc((size_t)2 * N * 64 * 2);  // EPAIR aliases this
    float* ES1 = (float*)alloc((size_t)2 * N * 2 * 4);
    float* ED1 = (float*)alloc((size_t)2 * N * 2 * 4);
    float* ES2 = (float*)alloc((size_t)2 * N * 4);
    float* ED2 = (float*)alloc((size_t)2 * N * 4);
    int* RS  = (int*)alloc((size_t)2 * (N + 1) * 4);
    int* CSR = (int*)alloc((size_t)2 * E * 4);
    int* BC  = (int*)alloc((size_t)4 * NB * 4);       // BCNT(2*NB) + BCUR(2*NB)
    int* BCNT = BC;
    int* BCUR = BC + 2 * NB;
    float* POOLED = (float*)alloc(8192 * 4);
    unsigned* EPAIR = (unsigned*)XL2h;   // dead after csr; xl2h written later

    const float* xb   = (const float*)d_in[0];
    const int*   eib  = (const int*)  d_in[1];
    const int*   batchb = (const int*)d_in[2];
    const float* W1b  = (const float*)d_in[3];
    const float* a1sb = (const float*)d_in[4];
    const float* a1db = (const float*)d_in[5];
    const float* b1b  = (const float*)d_in[6];
    const float* W2b  = (const float*)d_in[7];
    const float* a2sb = (const float*)d_in[8];
    const float* a2db = (const float*)d_in[9];
    const float* b2b  = (const float*)d_in[10];
    const float* M1wb = (const float*)d_in[11];
    const float* M1bb = (const float*)d_in[12];
    const float* M2wb = (const float*)d_in[13];
    const float* M2bb = (const float*)d_in[14];
    const float* xt   = (const float*)d_in[15];
    const int*   eit  = (const int*)  d_in[16];
    const int*   batcht = (const int*)d_in[17];
    const float* W1t  = (const float*)d_in[18];
    const float* a1st = (const float*)d_in[19];
    const float* a1dt = (const float*)d_in[20];
    const float* b1t  = (const float*)d_in[21];
    const float* W2t  = (const float*)d_in[22];
    const float* a2st = (const float*)d_in[23];
    const float* a2dt = (const float*)d_in[24];
    const float* b2t  = (const float*)d_in[25];
    const float* M1wt = (const float*)d_in[26];
    const float* M1bt = (const float*)d_in[27];
    const float* M2wt = (const float*)d_in[28];
    const float* M2bt = (const float*)d_in[29];
    const float* Fw1  = (const float*)d_in[30];
    const float* Fb1  = (const float*)d_in[31];
    const float* Fw2  = (const float*)d_in[32];
    const float* Fb2  = (const float*)d_in[33];

    const int nodeBlocks = (N + 3) / 4;
    const int histBlocks = (E + CHUNK - 1) / CHUNK;
    const int tilesPer   = (N + 15) / 16;

    hipMemsetAsync(BC, 0, (size_t)4 * NB * 4, stream);
    hipMemsetAsync(POOLED, 0, 8192 * 4, stream);
    pre_kernel<<<2 * histBlocks + 2 * nodeBlocks, 256, 0, stream>>>(
        xb, xt, W1b, W1t, a1sb, a1st, a1db, a1dt, eib, eit,
        XL1u, ES1, ED1, BCNT, N, E, NB, nodeBlocks, histBlocks);
    bin_kernel<<<2 * histBlocks, 256, 0, stream>>>(
        eib, eit, BCNT, BCUR, EPAIR, N, E, NB, histBlocks);
    csr_kernel<<<2 * NB, 256, 0, stream>>>(BCNT, EPAIR, RS, CSR, N, E, NB);
    a1f2_kernel<<<2 * tilesPer, 256, 0, stream>>>(
        XL1u, ES1, ED1, CSR, RS, b1b, b1t, W2b, W2t,
        a2sb, a2st, a2db, a2dt, XL2h, ES2, ED2, N, E, tilesPer);
    a2pl_kernel<<<2 * nodeBlocks, 256, 0, stream>>>(
        XL2h, ES2, ED2, CSR, RS, b2b, b2t, batchb, batcht, POOLED, N, E, nodeBlocks);
    tail_kernel<<<1, 1024, 0, stream>>>(POOLED, batchb, batcht,
        M1wb, M1bb, M2wb, M2bb, M1wt, M1bt, M2wt, M2bt,
        Fw1, Fb1, Fw2, Fb2, (float*)d_out, N);
}

// Round 6
// 289.588 us; speedup vs baseline: 3.1865x; 1.0410x over previous
//
#include <hip/hip_runtime.h>
#include <math.h>

// ---------------------------------------------------------------------------
// DeepONet/GAT, fused pipeline:
//   pre   : feat1 (x@W1 -> xl1 bf16) + logits + bucket hist + W2->bf16^T
//   bin   : edge bucket-sort (LDS slot alloc, packed 4B scatter)
//   csr   : per-bucket CSR build (window-local scatter)
//   a1f2  : GAT1 aggregation -> h1 in LDS -> MFMA h1@W2T -> xl2 + logits2
//   a2pl  : GAT2 aggregation -> per-graph pooled sums via block atomics
//   tail  : counts + branch MLPs + combine + final head
// Buckets: 512 nodes (BSH=9), NB <= 128 (N <= 65536).
// Gather kernels use br = bid&1 so each branch maps to one XCD parity class.
// ---------------------------------------------------------------------------

#define BSH 9
#define CHUNK 4096

using short8v = __attribute__((ext_vector_type(8))) short;
using f32x4  = __attribute__((ext_vector_type(4))) float;

__device__ __forceinline__ float leaky02(float x){ return fmaxf(x, 0.2f * x); }
__device__ __forceinline__ float elu1(float x){ return x > 0.f ? x : expm1f(x); }
__device__ __forceinline__ unsigned f2bf(float a){
    unsigned u = __float_as_uint(a);
    return (u + 0x7FFFu + ((u >> 16) & 1u)) >> 16;
}
__device__ __forceinline__ unsigned packbf(float a, float b){ return f2bf(a) | (f2bf(b) << 16); }
__device__ __forceinline__ float bflo(unsigned p){ return __uint_as_float(p << 16); }
__device__ __forceinline__ float bfhi(unsigned p){ return __uint_as_float(p & 0xFFFF0000u); }
__device__ __forceinline__ float bfs(unsigned short s){ return __uint_as_float(((unsigned)s) << 16); }

__device__ __forceinline__ int wave_incl_scan(int v, int lane){
    #pragma unroll
    for (int d = 1; d < 64; d <<= 1){ int u = __shfl_up(v, (unsigned)d, 64); if (lane >= d) v += u; }
    return v;
}

// feat1 + bucket histogram + W2 transpose-to-bf16, grid-split.
__global__ __launch_bounds__(256) void pre_kernel(
    const float* __restrict__ xb, const float* __restrict__ xt,
    const float* __restrict__ W1b, const float* __restrict__ W1t,
    const float* __restrict__ a1sb, const float* __restrict__ a1st,
    const float* __restrict__ a1db, const float* __restrict__ a1dt,
    const int* __restrict__ eib, const int* __restrict__ eit,
    const float* __restrict__ W2b, const float* __restrict__ W2t,
    unsigned* __restrict__ xl1u, float* __restrict__ es1, float* __restrict__ ed1,
    int* __restrict__ bcnt, unsigned short* __restrict__ w2T,
    int N, int E, int NB, int nodeBlocks, int histBlocks){
    int bid = blockIdx.x;
    int tid = threadIdx.x;
    if (bid < 2 * histBlocks){
        int br = (bid >= histBlocks) ? 1 : 0;
        int cb = bid - br * histBlocks;
        const int* dstp = (br ? eit : eib) + E;
        __shared__ int hist[128];
        for (int i = tid; i < 128; i += 256) hist[i] = 0;
        __syncthreads();
        int start = cb * CHUNK, cnt = min(CHUNK, E - start);
        for (int i = tid; i < cnt; i += 256) atomicAdd(&hist[dstp[start + i] >> BSH], 1);
        __syncthreads();
        if (tid < NB && hist[tid]) atomicAdd(&bcnt[br * NB + tid], hist[tid]);
        return;
    }
    bid -= 2 * histBlocks;
    if (bid >= 2 * nodeBlocks){
        // W2T[c][k] = bf16(W2[k][c]), per branch
        int br = bid - 2 * nodeBlocks;
        const float* W2 = br ? W2t : W2b;
        for (int i = tid; i < 8192; i += 256){
            int c = i >> 7, k = i & 127;
            w2T[br * 8192 + i] = (unsigned short)f2bf(W2[k * 64 + c]);
        }
        return;
    }
    int br = (bid >= nodeBlocks) ? 1 : 0;
    int nb = bid - br * nodeBlocks;
    int n = (nb << 2) + (tid >> 6);
    int lane = tid & 63;
    if (n >= N) return;
    const float* x   = br ? xt   : xb;
    const float* W1  = br ? W1t  : W1b;
    const float* a1s = br ? a1st : a1sb;
    const float* a1d = br ? a1dt : a1db;
    float2 xv = ((const float2*)x)[n];
    float2 w0 = ((const float2*)W1)[lane];
    float2 w1 = ((const float2*)(W1 + 128))[lane];
    float xla = xv.x * w0.x + xv.y * w1.x;
    float xlb = xv.x * w0.y + xv.y * w1.y;
    xl1u[(size_t)br * N * 64 + (size_t)n * 64 + lane] = packbf(xla, xlb);
    float2 as = ((const float2*)a1s)[lane];
    float2 ad = ((const float2*)a1d)[lane];
    float ps = xla * as.x + xlb * as.y;
    float pd = xla * ad.x + xlb * ad.y;
    #pragma unroll
    for (int m = 16; m >= 1; m >>= 1){ ps += __shfl_xor(ps, m, 64); pd += __shfl_xor(pd, m, 64); }
    if ((lane & 31) == 0){
        int h = lane >> 5;
        es1[(size_t)br * N * 2 + n * 2 + h] = ps;
        ed1[(size_t)br * N * 2 + n * 2 + h] = pd;
    }
}

// slot = LDS hist atomic; packed (src<<9|dstlow) 4B scatter into bucket runs.
__global__ __launch_bounds__(256) void bin_kernel(
    const int* __restrict__ eib, const int* __restrict__ eit,
    const int* __restrict__ bcnt, int* __restrict__ bcur,
    unsigned* __restrict__ epair, int N, int E, int NB, int blocksPer){
    int bid = blockIdx.x;
    int br = (bid >= blocksPer) ? 1 : 0;
    int cb = bid - br * blocksPer;
    const int* ei = br ? eit : eib;
    int start = cb * CHUNK;
    int cnt = min(CHUNK, E - start);
    __shared__ int hist[128], gpos[128];
    __shared__ int slots[CHUNK];
    int tid = threadIdx.x, lane = tid & 63, wid = tid >> 6;
    for (int i = tid; i < 128; i += 256) hist[i] = 0;
    __syncthreads();
    const int* dstp = ei + E + start;
    const int* srcp = ei + start;
    for (int li = tid; li < cnt; li += 256){
        int b = dstp[li] >> BSH;
        slots[li] = atomicAdd(&hist[b], 1);
    }
    __syncthreads();
    if (wid == 0){
        int b0 = (lane < NB) ? bcnt[br * NB + lane] : 0;
        int b1 = (64 + lane < NB) ? bcnt[br * NB + 64 + lane] : 0;
        int g0 = wave_incl_scan(b0, lane); int gt = __shfl(g0, 63, 64);
        int g1 = wave_incl_scan(b1, lane);
        int base0 = g0 - b0, base1 = gt + g1 - b1;
        int h0 = hist[lane], h1v = hist[64 + lane];
        gpos[lane] = (h0 > 0) ? base0 + atomicAdd(&bcur[br * NB + lane], h0) : 0;
        gpos[64 + lane] = (h1v > 0) ? base1 + atomicAdd(&bcur[br * NB + 64 + lane], h1v) : 0;
    }
    __syncthreads();
    unsigned* ep = epair + (size_t)br * E;
    for (int li = tid; li < cnt; li += 256){
        int d = dstp[li];
        int b = d >> BSH;
        ep[gpos[b] + slots[li]] = ((unsigned)srcp[li] << BSH) | (unsigned)(d & ((1 << BSH) - 1));
    }
}

// per-bucket CSR: local degrees -> row starts (writes rs), scatter src.
__global__ __launch_bounds__(256) void csr_kernel(
    const int* __restrict__ bcnt, const unsigned* __restrict__ epair,
    int* __restrict__ rs, int* __restrict__ csr, int N, int E, int NB){
    int bid = blockIdx.x;
    int br = (bid >= NB) ? 1 : 0;
    int b = bid - br * NB;
    __shared__ int base2[128];
    __shared__ int deg[512], st[512];
    int tid = threadIdx.x, lane = tid & 63, wid = tid >> 6;
    if (wid == 0){
        int b0 = (lane < NB) ? bcnt[br * NB + lane] : 0;
        int b1 = (64 + lane < NB) ? bcnt[br * NB + 64 + lane] : 0;
        int g0 = wave_incl_scan(b0, lane); int gt = __shfl(g0, 63, 64);
        int g1 = wave_incl_scan(b1, lane);
        base2[lane] = g0 - b0; base2[64 + lane] = gt + g1 - b1;
    }
    for (int i = tid; i < 512; i += 256) deg[i] = 0;
    __syncthreads();
    int ebase = base2[b];
    int ecnt = bcnt[br * NB + b];
    int n0 = b << BSH;
    int nodes = min(512, N - n0);
    const unsigned* ep = epair + (size_t)br * E + ebase;
    for (int i = tid; i < ecnt; i += 256) atomicAdd(&deg[ep[i] & 511u], 1);
    __syncthreads();
    if (wid == 0){
        int carry = 0;
        #pragma unroll
        for (int c = 0; c < 8; ++c){
            int v = deg[c * 64 + lane];
            int s = wave_incl_scan(v, lane);
            st[c * 64 + lane] = carry + s - v;
            carry += __shfl(s, 63, 64);
        }
    }
    __syncthreads();
    int* rsb = rs + (size_t)br * (N + 1);
    for (int i = tid; i < nodes; i += 256) rsb[n0 + i] = ebase + st[i];
    if (b == NB - 1 && tid == 0) rsb[N] = ebase + ecnt;
    for (int i = tid; i < 512; i += 256) deg[i] = st[i];
    __syncthreads();
    int* csrb = csr + (size_t)br * E + ebase;
    for (int i = tid; i < ecnt; i += 256){
        unsigned p = ep[i];
        int pos = atomicAdd(&deg[p & 511u], 1);
        csrb[pos] = (int)(p >> BSH);
    }
}

// Fused GAT1 aggregation + (h1 @ W2T) MFMA + layer-2 logits.
// Block = 16 nodes: 4 waves x 4 nodes serial agg (h1 -> padded LDS), then each
// wave computes a 16-col tile of xl2 via mfma_f32_16x16x32_bf16 with B-frags
// loaded straight from the L1-resident bf16 W2T table.
__global__ __launch_bounds__(256) void a1f2_kernel(
    const unsigned* __restrict__ xl1u, const float* __restrict__ es1, const float* __restrict__ ed1,
    const int* __restrict__ csr, const int* __restrict__ rs,
    const float* __restrict__ b1b, const float* __restrict__ b1t,
    const unsigned short* __restrict__ w2T,
    const float* __restrict__ a2sb, const float* __restrict__ a2st,
    const float* __restrict__ a2db, const float* __restrict__ a2dt,
    unsigned short* __restrict__ xl2h, float* __restrict__ es2, float* __restrict__ ed2,
    int N, int E){
    int bid = blockIdx.x;
    int br = bid & 1;                 // branch parity == XCD parity class
    int n0 = (bid >> 1) << 4;
    const unsigned* xl = xl1u + (size_t)br * N * 64;
    const float* es = es1 + (size_t)br * N * 2;
    const float* ed = ed1 + (size_t)br * N * 2;
    const int* cs = csr + (size_t)br * E;
    const int* rsb = rs + (size_t)br * (N + 1);
    const float* b1 = br ? b1t : b1b;
    const float* a2s = br ? a2st : a2sb;
    const float* a2d = br ? a2dt : a2db;

    __shared__ unsigned hl[16][68];          // h1 tile, packed bf16 pairs, padded
    __shared__ float psa[4][16], pda[4][16];
    int tid = threadIdx.x, lane = tid & 63, w = tid >> 6;

    int h = lane >> 5;
    int c = lane << 1;
    float b1lo = b1[c], b1hi = b1[c + 1];
    #pragma unroll
    for (int nn = 0; nn < 4; ++nn){
        int row = w * 4 + nn;
        int n = n0 + row;
        if (n >= N){ hl[row][lane] = 0u; continue; }
        float edn = ed[n * 2 + h];
        float wself = __expf(leaky02(es[n * 2 + h] + edn));
        unsigned pself = xl[(size_t)n * 64 + lane];
        float denom = wself;
        float ax = wself * bflo(pself);
        float ay = wself * bfhi(pself);
        int beg = __builtin_amdgcn_readfirstlane(rsb[n]);
        int end = __builtin_amdgcn_readfirstlane(rsb[n + 1]);
        int j = beg;
        for (; j + 8 <= end; j += 8){
            int ss[8]; unsigned pp[8]; float ee[8];
            #pragma unroll
            for (int q = 0; q < 8; ++q) ss[q] = cs[j + q];
            #pragma unroll
            for (int q = 0; q < 8; ++q){
                ee[q] = es[ss[q] * 2 + h];
                pp[q] = xl[(size_t)ss[q] * 64 + lane];
            }
            #pragma unroll
            for (int q = 0; q < 8; ++q){
                float wq = __expf(leaky02(ee[q] + edn));
                denom += wq;
                ax += wq * bflo(pp[q]);
                ay += wq * bfhi(pp[q]);
            }
        }
        for (; j < end; ++j){
            int s = cs[j];
            float wq = __expf(leaky02(es[s * 2 + h] + edn));
            unsigned p = xl[(size_t)s * 64 + lane];
            denom += wq;
            ax += wq * bflo(p);
            ay += wq * bfhi(p);
        }
        float inv = 1.f / denom;
        hl[row][lane] = packbf(elu1(ax * inv + b1lo), elu1(ay * inv + b1hi));
    }

    int lr = lane & 15, lq = lane >> 4;
    // B fragments straight from global bf16 W2T (L1-resident 16KB/branch)
    const unsigned short* wtp = w2T + br * 8192 + (w * 16 + lr) * 128 + lq * 8;
    short8v bf0 = *(const short8v*)(wtp);
    short8v bf1 = *(const short8v*)(wtp + 32);
    short8v bf2 = *(const short8v*)(wtp + 64);
    short8v bf3 = *(const short8v*)(wtp + 96);
    __syncthreads();
    f32x4 ac = {0.f, 0.f, 0.f, 0.f};
    ac = __builtin_amdgcn_mfma_f32_16x16x32_bf16(*(const short8v*)&hl[lr][lq * 4], bf0, ac, 0, 0, 0);
    ac = __builtin_amdgcn_mfma_f32_16x16x32_bf16(*(const short8v*)&hl[lr][16 + lq * 4], bf1, ac, 0, 0, 0);
    ac = __builtin_amdgcn_mfma_f32_16x16x32_bf16(*(const short8v*)&hl[lr][32 + lq * 4], bf2, ac, 0, 0, 0);
    ac = __builtin_amdgcn_mfma_f32_16x16x32_bf16(*(const short8v*)&hl[lr][48 + lq * 4], bf3, ac, 0, 0, 0);
    float a2sv = a2s[w * 16 + lr];
    float a2dv = a2d[w * 16 + lr];
    #pragma unroll
    for (int reg = 0; reg < 4; ++reg){
        int r = lq * 4 + reg;
        int n = n0 + r;
        float v = ac[reg];
        if (n < N)
            xl2h[((size_t)br * N + n) * 64 + w * 16 + lr] = (unsigned short)f2bf(v);
        float ps = v * a2sv, pd = v * a2dv;
        ps += __shfl_xor(ps, 1, 64); ps += __shfl_xor(ps, 2, 64);
        ps += __shfl_xor(ps, 4, 64); ps += __shfl_xor(ps, 8, 64);
        pd += __shfl_xor(pd, 1, 64); pd += __shfl_xor(pd, 2, 64);
        pd += __shfl_xor(pd, 4, 64); pd += __shfl_xor(pd, 8, 64);
        if (lr == 0){ psa[w][r] = ps; pda[w][r] = pd; }
    }
    __syncthreads();
    if (tid < 16){
        int n = n0 + tid;
        if (n < N)
            es2[(size_t)br * N + n] = psa[0][tid] + psa[1][tid] + psa[2][tid] + psa[3][tid];
    } else if (tid < 32){
        int r = tid - 16;
        int n = n0 + r;
        if (n < N)
            ed2[(size_t)br * N + n] = pda[0][r] + pda[1][r] + pda[2][r] + pda[3][r];
    }
}

// Fused GAT2 aggregation + per-graph pooled sums (block-level atomics).
__global__ __launch_bounds__(256) void a2pl_kernel(
    const unsigned short* __restrict__ xl2h, const float* __restrict__ es2, const float* __restrict__ ed2,
    const int* __restrict__ csr, const int* __restrict__ rs,
    const float* __restrict__ b2b, const float* __restrict__ b2t,
    const int* __restrict__ batchb, const int* __restrict__ batcht,
    float* __restrict__ pooled, int N, int E){
    int bid = blockIdx.x;
    int br = bid & 1;                 // branch parity == XCD parity class
    int tid = threadIdx.x, lane = tid & 63, w = tid >> 6;
    int n = ((bid >> 1) << 2) + w;
    const unsigned short* xlt = xl2h + (size_t)br * N * 64;
    const float* es = es2 + (size_t)br * N;
    const float* ed = ed2 + (size_t)br * N;
    const int* cs = csr + (size_t)br * E;
    const int* rsb = rs + (size_t)br * (N + 1);
    const float* b2 = br ? b2t : b2b;
    const int* batch = br ? batcht : batchb;
    float hv = 0.f;
    int g = -1;
    if (n < N){
        float edn = ed[n];
        float wself = __expf(leaky02(es[n] + edn));
        float denom = wself;
        float acc = wself * bfs(xlt[(size_t)n * 64 + lane]);
        int beg = __builtin_amdgcn_readfirstlane(rsb[n]);
        int end = __builtin_amdgcn_readfirstlane(rsb[n + 1]);
        int j = beg;
        for (; j + 8 <= end; j += 8){
            int ss[8]; float ee[8], vv[8];
            #pragma unroll
            for (int q = 0; q < 8; ++q) ss[q] = cs[j + q];
            #pragma unroll
            for (int q = 0; q < 8; ++q){
                ee[q] = es[ss[q]];
                vv[q] = bfs(xlt[(size_t)ss[q] * 64 + lane]);
            }
            #pragma unroll
            for (int q = 0; q < 8; ++q){
                float wq = __expf(leaky02(ee[q] + edn));
                denom += wq;
                acc += wq * vv[q];
            }
        }
        for (; j < end; ++j){
            int s = cs[j];
            float wq = __expf(leaky02(es[s] + edn));
            denom += wq;
            acc += wq * bfs(xlt[(size_t)s * 64 + lane]);
        }
        hv = elu1(acc / denom + b2[lane]);
        g = batch[n];
    }
    __shared__ float red[4][64];
    __shared__ int gid[4];
    red[w][lane] = hv;
    if (lane == 0) gid[w] = g;
    __syncthreads();
    if (w == 0){
        int g0 = gid[0], g1 = gid[1], g2 = gid[2], g3 = gid[3];
        float* pb = pooled + (size_t)br * 4096;
        if (g0 >= 0 && g0 == g1 && g1 == g2 && g2 == g3){
            float s = (red[0][lane] + red[1][lane]) + (red[2][lane] + red[3][lane]);
            atomicAdd(&pb[g0 * 64 + lane], s);
        } else {
            #pragma unroll
            for (int q = 0; q < 4; ++q)
                if (gid[q] >= 0) atomicAdd(&pb[gid[q] * 64 + lane], red[q][lane]);
        }
    }
}

// counts (binary search on sorted batch) + branch MLPs + combine + final head
__global__ __launch_bounds__(1024) void tail_kernel(
    const float* __restrict__ pooled,
    const int* __restrict__ batchb, const int* __restrict__ batcht,
    const float* __restrict__ M1wb, const float* __restrict__ M1bb,
    const float* __restrict__ M2wb, const float* __restrict__ M2bb,
    const float* __restrict__ M1wt, const float* __restrict__ M1bt,
    const float* __restrict__ M2wt, const float* __restrict__ M2bt,
    const float* __restrict__ Fw1, const float* __restrict__ Fb1,
    const float* __restrict__ Fw2, const float* __restrict__ Fb2,
    float* __restrict__ out, int N){
    __shared__ float P[8192];
    __shared__ float H[8192];
    __shared__ float cl[128];
    int t = threadIdx.x;
    if (t < 128){
        int br = t >> 6, g = t & 63;
        const int* batch = br ? batcht : batchb;
        int lo = 0, hi = N;
        while (lo < hi){ int mid = (lo + hi) >> 1; if (batch[mid] < g) lo = mid + 1; else hi = mid; }
        int beg = lo;
        hi = N;
        while (lo < hi){ int mid = (lo + hi) >> 1; if (batch[mid] < g + 1) lo = mid + 1; else hi = mid; }
        cl[t] = (float)(lo - beg);
    }
    __syncthreads();
    for (int i = t; i < 8192; i += 1024)
        P[i] = pooled[i] / fmaxf(cl[i >> 6], 1.f);
    __syncthreads();
    for (int i = t; i < 8192; i += 1024){
        int br = i >> 12, r = (i >> 6) & 63, c = i & 63;
        const float* M1w = br ? M1wt : M1wb;
        const float* M1b = br ? M1bt : M1bb;
        float acc = M1b[c];
        int pb = (br << 12) + (r << 6);
        #pragma unroll 8
        for (int k = 0; k < 64; ++k) acc += P[pb + k] * M1w[(k << 6) + c];
        H[i] = fmaxf(acc, 0.f);
    }
    __syncthreads();
    for (int i = t; i < 8192; i += 1024){
        int br = i >> 12, r = (i >> 6) & 63, c = i & 63;
        const float* M2w = br ? M2wt : M2wb;
        const float* M2b = br ? M2bt : M2bb;
        float acc = M2b[c];
        int hb = (br << 12) + (r << 6);
        #pragma unroll 8
        for (int k = 0; k < 64; ++k) acc += H[hb + k] * M2w[(k << 6) + c];
        P[i] = acc;
    }
    __syncthreads();
    for (int i = t; i < 4096; i += 1024) H[i] = P[i] * P[4096 + i];
    __syncthreads();
    for (int i = t; i < 4096; i += 1024){
        int r = i >> 6, c = i & 63;
        float acc = Fb1[c];
        #pragma unroll 8
        for (int k = 0; k < 64; ++k) acc += H[(r << 6) + k] * Fw1[(k << 6) + c];
        P[i] = fmaxf(acc, 0.f);
    }
    __syncthreads();
    if (t < 128){
        int r = t >> 1, jc = t & 1;
        float acc = Fb2[jc];
        #pragma unroll 8
        for (int k = 0; k < 64; ++k) acc += P[(r << 6) + k] * Fw2[k * 2 + jc];
        out[t] = tanhf(acc);
    }
}

extern "C" void kernel_launch(void* const* d_in, const int* in_sizes, int n_in,
                              void* d_out, int out_size, void* d_ws, size_t ws_size,
                              hipStream_t stream){
    const int N = in_sizes[0] / 2;
    const int E = in_sizes[1] / 2;
    const int NB = (N + 511) >> BSH;   // nodes-per-bucket = 512, NB <= 128

    char* ws = (char*)d_ws;
    size_t off = 0;
    auto alloc = [&](size_t bytes) -> char* {
        char* p = ws + off;
        off += (bytes + 255) & ~(size_t)255;
        return p;
    };
    unsigned* XL1u = (unsigned*)alloc((size_t)2 * N * 64 * 4);
    unsigned short* XL2h = (unsigned short*)alloc((size_t)2 * N * 64 * 2);  // EPAIR aliases this
    float* ES1 = (float*)alloc((size_t)2 * N * 2 * 4);
    float* ED1 = (float*)alloc((size_t)2 * N * 2 * 4);
    float* ES2 = (float*)alloc((size_t)2 * N * 4);
    float* ED2 = (float*)alloc((size_t)2 * N * 4);
    int* RS  = (int*)alloc((size_t)2 * (N + 1) * 4);
    int* CSR = (int*)alloc((size_t)2 * E * 4);
    int* BC  = (int*)alloc((size_t)4 * NB * 4);       // BCNT(2*NB) + BCUR(2*NB)
    int* BCNT = BC;
    int* BCUR = BC + 2 * NB;
    float* POOLED = (float*)alloc(8192 * 4);
    unsigned short* W2T = (unsigned short*)alloc(2 * 8192 * 2);
    unsigned* EPAIR = (unsigned*)XL2h;   // dead after csr; xl2h written later

    const float* xb   = (const float*)d_in[0];
    const int*   eib  = (const int*)  d_in[1];
    const int*   batchb = (const int*)d_in[2];
    const float* W1b  = (const float*)d_in[3];
    const float* a1sb = (const float*)d_in[4];
    const float* a1db = (const float*)d_in[5];
    const float* b1b  = (const float*)d_in[6];
    const float* W2b  = (const float*)d_in[7];
    const float* a2sb = (const float*)d_in[8];
    const float* a2db = (const float*)d_in[9];
    const float* b2b  = (const float*)d_in[10];
    const float* M1wb = (const float*)d_in[11];
    const float* M1bb = (const float*)d_in[12];
    const float* M2wb = (const float*)d_in[13];
    const float* M2bb = (const float*)d_in[14];
    const float* xt   = (const float*)d_in[15];
    const int*   eit  = (const int*)  d_in[16];
    const int*   batcht = (const int*)d_in[17];
    const float* W1t  = (const float*)d_in[18];
    const float* a1st = (const float*)d_in[19];
    const float* a1dt = (const float*)d_in[20];
    const float* b1t  = (const float*)d_in[21];
    const float* W2t  = (const float*)d_in[22];
    const float* a2st = (const float*)d_in[23];
    const float* a2dt = (const float*)d_in[24];
    const float* b2t  = (const float*)d_in[25];
    const float* M1wt = (const float*)d_in[26];
    const float* M1bt = (const float*)d_in[27];
    const float* M2wt = (const float*)d_in[28];
    const float* M2bt = (const float*)d_in[29];
    const float* Fw1  = (const float*)d_in[30];
    const float* Fb1  = (const float*)d_in[31];
    const float* Fw2  = (const float*)d_in[32];
    const float* Fb2  = (const float*)d_in[33];

    const int nodeBlocks = (N + 3) / 4;
    const int histBlocks = (E + CHUNK - 1) / CHUNK;
    const int tilesPer   = (N + 15) / 16;

    hipMemsetAsync(BC, 0, (size_t)4 * NB * 4, stream);
    hipMemsetAsync(POOLED, 0, 8192 * 4, stream);
    pre_kernel<<<2 * histBlocks + 2 * nodeBlocks + 2, 256, 0, stream>>>(
        xb, xt, W1b, W1t, a1sb, a1st, a1db, a1dt, eib, eit, W2b, W2t,
        XL1u, ES1, ED1, BCNT, W2T, N, E, NB, nodeBlocks, histBlocks);
    bin_kernel<<<2 * histBlocks, 256, 0, stream>>>(
        eib, eit, BCNT, BCUR, EPAIR, N, E, NB, histBlocks);
    csr_kernel<<<2 * NB, 256, 0, stream>>>(BCNT, EPAIR, RS, CSR, N, E, NB);
    a1f2_kernel<<<2 * tilesPer, 256, 0, stream>>>(
        XL1u, ES1, ED1, CSR, RS, b1b, b1t, W2T,
        a2sb, a2st, a2db, a2dt, XL2h, ES2, ED2, N, E);
    a2pl_kernel<<<2 * nodeBlocks, 256, 0, stream>>>(
        XL2h, ES2, ED2, CSR, RS, b2b, b2t, batchb, batcht, POOLED, N, E);
    tail_kernel<<<1, 1024, 0, stream>>>(POOLED, batchb, batcht,
        M1wb, M1bb, M2wb, M2bb, M1wt, M1bt, M2wt, M2bt,
        Fw1, Fb1, Fw2, Fb2, (float*)d_out, N);
}

// Round 7
// 282.268 us; speedup vs baseline: 3.2692x; 1.0259x over previous
//
#include <hip/hip_runtime.h>
#include <math.h>

// ---------------------------------------------------------------------------
// DeepONet/GAT, fused pipeline (R7):
//   memset: BCUR (tiny)
//   preb  : feat1 (x@W1 -> xl1 bf16, logits pre-scaled by log2e) + W2->bf16^T
//           + POOLED zero + bin (edge bucket-sort into fixed arenas, no hist)
//   csr   : per-bucket CSR build (compact, window-local scatter)
//   a1f2  : GAT1 aggregation (exp2) -> h1 in LDS -> MFMA h1@W2T -> xl2+logits2
//   a2pl  : GAT2 aggregation (paired-edge dword gathers) -> per-graph pools
//   tail  : counts + branch MLPs + combine + final head
// Buckets: 512 nodes (BSH=9), NB <= 128 (N <= 65536), arena 12288 edges.
// ---------------------------------------------------------------------------

#define BSH 9
#define CHUNK 4096
#define ARENA 12288
#define LOG2E 1.44269504088896f

using short8v = __attribute__((ext_vector_type(8))) short;
using f32x4  = __attribute__((ext_vector_type(4))) float;

__device__ __forceinline__ float leaky02(float x){ return fmaxf(x, 0.2f * x); }
__device__ __forceinline__ float elu1(float x){ return x > 0.f ? x : expm1f(x); }
__device__ __forceinline__ unsigned f2bf(float a){
    unsigned u = __float_as_uint(a);
    return (u + 0x7FFFu + ((u >> 16) & 1u)) >> 16;
}
__device__ __forceinline__ unsigned packbf(float a, float b){ return f2bf(a) | (f2bf(b) << 16); }
__device__ __forceinline__ float bflo(unsigned p){ return __uint_as_float(p << 16); }
__device__ __forceinline__ float bfhi(unsigned p){ return __uint_as_float(p & 0xFFFF0000u); }

__device__ __forceinline__ int wave_incl_scan(int v, int lane){
    #pragma unroll
    for (int d = 1; d < 64; d <<= 1){ int u = __shfl_up(v, (unsigned)d, 64); if (lane >= d) v += u; }
    return v;
}

// feat1 + W2 transpose + POOLED zero + edge binning, grid-split.
__global__ __launch_bounds__(256) void preb_kernel(
    const float* __restrict__ xb, const float* __restrict__ xt,
    const float* __restrict__ W1b, const float* __restrict__ W1t,
    const float* __restrict__ a1sb, const float* __restrict__ a1st,
    const float* __restrict__ a1db, const float* __restrict__ a1dt,
    const int* __restrict__ eib, const int* __restrict__ eit,
    const float* __restrict__ W2b, const float* __restrict__ W2t,
    unsigned* __restrict__ xl1u, float* __restrict__ es1, float* __restrict__ ed1,
    int* __restrict__ bcur, unsigned* __restrict__ epair,
    unsigned short* __restrict__ w2T, float* __restrict__ pooled,
    int N, int E, int NB, int nodeBlocks, int histBlocks){
    int bid = blockIdx.x;
    int tid = threadIdx.x;
    __shared__ int hist[128], gpos[128];
    __shared__ int slots[CHUNK];
    if (bid < 2 * histBlocks){
        // ---- bin: bucket-sort one 4096-edge chunk into fixed arenas ----
        int br = (bid >= histBlocks) ? 1 : 0;
        int cb = bid - br * histBlocks;
        const int* ei = br ? eit : eib;
        int start = cb * CHUNK;
        int cnt = min(CHUNK, E - start);
        for (int i = tid; i < 128; i += 256) hist[i] = 0;
        __syncthreads();
        const int* dstp = ei + E + start;
        const int* srcp = ei + start;
        for (int li = tid; li < cnt; li += 256){
            int b = dstp[li] >> BSH;
            slots[li] = atomicAdd(&hist[b], 1);
        }
        __syncthreads();
        if (tid < NB){
            int h0 = hist[tid];
            gpos[tid] = (h0 > 0) ? atomicAdd(&bcur[br * NB + tid], h0) : 0;
        }
        __syncthreads();
        unsigned* ep = epair + (size_t)br * NB * ARENA;
        for (int li = tid; li < cnt; li += 256){
            int d = dstp[li];
            int b = d >> BSH;
            ep[(size_t)b * ARENA + gpos[b] + slots[li]] =
                ((unsigned)srcp[li] << BSH) | (unsigned)(d & ((1 << BSH) - 1));
        }
        return;
    }
    bid -= 2 * histBlocks;
    if (bid >= 2 * nodeBlocks){
        int xb2 = bid - 2 * nodeBlocks;
        if (xb2 < 2){
            // W2T[c][k] = bf16(W2[k][c]), per branch
            const float* W2 = xb2 ? W2t : W2b;
            for (int i = tid; i < 8192; i += 256){
                int c = i >> 7, k = i & 127;
                w2T[xb2 * 8192 + i] = (unsigned short)f2bf(W2[k * 64 + c]);
            }
        } else {
            for (int i = tid; i < 8192; i += 256) pooled[i] = 0.f;
        }
        return;
    }
    // ---- feat1 ----
    int br = (bid >= nodeBlocks) ? 1 : 0;
    int nb = bid - br * nodeBlocks;
    int n = (nb << 2) + (tid >> 6);
    int lane = tid & 63;
    if (n >= N) return;
    const float* x   = br ? xt   : xb;
    const float* W1  = br ? W1t  : W1b;
    const float* a1s = br ? a1st : a1sb;
    const float* a1d = br ? a1dt : a1db;
    float2 xv = ((const float2*)x)[n];
    float2 w0 = ((const float2*)W1)[lane];
    float2 w1 = ((const float2*)(W1 + 128))[lane];
    float xla = xv.x * w0.x + xv.y * w1.x;
    float xlb = xv.x * w0.y + xv.y * w1.y;
    xl1u[(size_t)br * N * 64 + (size_t)n * 64 + lane] = packbf(xla, xlb);
    float2 as = ((const float2*)a1s)[lane];
    float2 ad = ((const float2*)a1d)[lane];
    float ps = xla * as.x + xlb * as.y;
    float pd = xla * ad.x + xlb * ad.y;
    #pragma unroll
    for (int m = 16; m >= 1; m >>= 1){ ps += __shfl_xor(ps, m, 64); pd += __shfl_xor(pd, m, 64); }
    if ((lane & 31) == 0){
        int h = lane >> 5;
        es1[(size_t)br * N * 2 + n * 2 + h] = LOG2E * ps;
        ed1[(size_t)br * N * 2 + n * 2 + h] = LOG2E * pd;
    }
}

// per-bucket CSR: compact bases from bcur scan, local degrees, scatter src.
__global__ __launch_bounds__(256) void csr_kernel(
    const int* __restrict__ bcur, const unsigned* __restrict__ epair,
    int* __restrict__ rs, int* __restrict__ csr, int N, int E, int NB){
    int bid = blockIdx.x;
    int br = (bid >= NB) ? 1 : 0;
    int b = bid - br * NB;
    __shared__ int base2[128];
    __shared__ int deg[512], st[512];
    int tid = threadIdx.x, lane = tid & 63, wid = tid >> 6;
    if (wid == 0){
        int b0 = (lane < NB) ? bcur[br * NB + lane] : 0;
        int b1 = (64 + lane < NB) ? bcur[br * NB + 64 + lane] : 0;
        int g0 = wave_incl_scan(b0, lane); int gt = __shfl(g0, 63, 64);
        int g1 = wave_incl_scan(b1, lane);
        base2[lane] = g0 - b0; base2[64 + lane] = gt + g1 - b1;
    }
    for (int i = tid; i < 512; i += 256) deg[i] = 0;
    __syncthreads();
    int ebase = base2[b];
    int ecnt = bcur[br * NB + b];
    int n0 = b << BSH;
    int nodes = min(512, N - n0);
    const unsigned* ep = epair + ((size_t)br * NB + b) * ARENA;
    for (int i = tid; i < ecnt; i += 256) atomicAdd(&deg[ep[i] & 511u], 1);
    __syncthreads();
    if (wid == 0){
        int carry = 0;
        #pragma unroll
        for (int c = 0; c < 8; ++c){
            int v = deg[c * 64 + lane];
            int s = wave_incl_scan(v, lane);
            st[c * 64 + lane] = carry + s - v;
            carry += __shfl(s, 63, 64);
        }
    }
    __syncthreads();
    int* rsb = rs + (size_t)br * (N + 1);
    for (int i = tid; i < nodes; i += 256) rsb[n0 + i] = ebase + st[i];
    if (b == NB - 1 && tid == 0) rsb[N] = ebase + ecnt;
    for (int i = tid; i < 512; i += 256) deg[i] = st[i];
    __syncthreads();
    int* csrb = csr + (size_t)br * E + ebase;
    for (int i = tid; i < ecnt; i += 256){
        unsigned p = ep[i];
        int pos = atomicAdd(&deg[p & 511u], 1);
        csrb[pos] = (int)(p >> BSH);
    }
}

// Fused GAT1 aggregation + (h1 @ W2T) MFMA + layer-2 logits. exp2-based.
__global__ __launch_bounds__(256) void a1f2_kernel(
    const unsigned* __restrict__ xl1u, const float* __restrict__ es1, const float* __restrict__ ed1,
    const int* __restrict__ csr, const int* __restrict__ rs,
    const float* __restrict__ b1b, const float* __restrict__ b1t,
    const unsigned short* __restrict__ w2T,
    const float* __restrict__ a2sb, const float* __restrict__ a2st,
    const float* __restrict__ a2db, const float* __restrict__ a2dt,
    unsigned short* __restrict__ xl2h, float* __restrict__ es2, float* __restrict__ ed2,
    int N, int E){
    int bid = blockIdx.x;
    int br = bid & 1;                 // branch parity == XCD parity class
    int n0 = (bid >> 1) << 4;
    const unsigned* xl = xl1u + (size_t)br * N * 64;
    const float* es = es1 + (size_t)br * N * 2;
    const float* ed = ed1 + (size_t)br * N * 2;
    const int* cs = csr + (size_t)br * E;
    const int* rsb = rs + (size_t)br * (N + 1);
    const float* b1 = br ? b1t : b1b;
    const float* a2s = br ? a2st : a2sb;
    const float* a2d = br ? a2dt : a2db;

    __shared__ unsigned hl[16][68];          // h1 tile, packed bf16 pairs, padded
    __shared__ float psa[4][16], pda[4][16];
    int tid = threadIdx.x, lane = tid & 63, w = tid >> 6;

    int h = lane >> 5;
    int c = lane << 1;
    float b1lo = b1[c], b1hi = b1[c + 1];
    #pragma unroll
    for (int nn = 0; nn < 4; ++nn){
        int row = w * 4 + nn;
        int n = n0 + row;
        if (n >= N){ hl[row][lane] = 0u; continue; }
        float edn = ed[n * 2 + h];
        float wself = exp2f(leaky02(es[n * 2 + h] + edn));
        unsigned pself = xl[(size_t)n * 64 + lane];
        float denom = wself;
        float ax = wself * bflo(pself);
        float ay = wself * bfhi(pself);
        int beg = __builtin_amdgcn_readfirstlane(rsb[n]);
        int end = __builtin_amdgcn_readfirstlane(rsb[n + 1]);
        int j = beg;
        for (; j + 8 <= end; j += 8){
            int ss[8]; unsigned pp[8]; float ee[8];
            #pragma unroll
            for (int q = 0; q < 8; ++q) ss[q] = cs[j + q];
            #pragma unroll
            for (int q = 0; q < 8; ++q){
                ee[q] = es[ss[q] * 2 + h];
                pp[q] = xl[(size_t)ss[q] * 64 + lane];
            }
            #pragma unroll
            for (int q = 0; q < 8; ++q){
                float wq = exp2f(leaky02(ee[q] + edn));
                denom += wq;
                ax += wq * bflo(pp[q]);
                ay += wq * bfhi(pp[q]);
            }
        }
        for (; j < end; ++j){
            int s = cs[j];
            float wq = exp2f(leaky02(es[s * 2 + h] + edn));
            unsigned p = xl[(size_t)s * 64 + lane];
            denom += wq;
            ax += wq * bflo(p);
            ay += wq * bfhi(p);
        }
        float inv = 1.f / denom;
        hl[row][lane] = packbf(elu1(ax * inv + b1lo), elu1(ay * inv + b1hi));
    }

    int lr = lane & 15, lq = lane >> 4;
    // B fragments straight from global bf16 W2T (L1-resident 16KB/branch)
    const unsigned short* wtp = w2T + br * 8192 + (w * 16 + lr) * 128 + lq * 8;
    short8v bf0 = *(const short8v*)(wtp);
    short8v bf1 = *(const short8v*)(wtp + 32);
    short8v bf2 = *(const short8v*)(wtp + 64);
    short8v bf3 = *(const short8v*)(wtp + 96);
    __syncthreads();
    f32x4 ac = {0.f, 0.f, 0.f, 0.f};
    ac = __builtin_amdgcn_mfma_f32_16x16x32_bf16(*(const short8v*)&hl[lr][lq * 4], bf0, ac, 0, 0, 0);
    ac = __builtin_amdgcn_mfma_f32_16x16x32_bf16(*(const short8v*)&hl[lr][16 + lq * 4], bf1, ac, 0, 0, 0);
    ac = __builtin_amdgcn_mfma_f32_16x16x32_bf16(*(const short8v*)&hl[lr][32 + lq * 4], bf2, ac, 0, 0, 0);
    ac = __builtin_amdgcn_mfma_f32_16x16x32_bf16(*(const short8v*)&hl[lr][48 + lq * 4], bf3, ac, 0, 0, 0);
    float a2sv = a2s[w * 16 + lr];
    float a2dv = a2d[w * 16 + lr];
    #pragma unroll
    for (int reg = 0; reg < 4; ++reg){
        int r = lq * 4 + reg;
        int n = n0 + r;
        float v = ac[reg];
        if (n < N)
            xl2h[((size_t)br * N + n) * 64 + w * 16 + lr] = (unsigned short)f2bf(v);
        float ps = v * a2sv, pd = v * a2dv;
        ps += __shfl_xor(ps, 1, 64); ps += __shfl_xor(ps, 2, 64);
        ps += __shfl_xor(ps, 4, 64); ps += __shfl_xor(ps, 8, 64);
        pd += __shfl_xor(pd, 1, 64); pd += __shfl_xor(pd, 2, 64);
        pd += __shfl_xor(pd, 4, 64); pd += __shfl_xor(pd, 8, 64);
        if (lr == 0){ psa[w][r] = ps; pda[w][r] = pd; }
    }
    __syncthreads();
    if (tid < 16){
        int n = n0 + tid;
        if (n < N)
            es2[(size_t)br * N + n] = LOG2E * (psa[0][tid] + psa[1][tid] + psa[2][tid] + psa[3][tid]);
    } else if (tid < 32){
        int r = tid - 16;
        int n = n0 + r;
        if (n < N)
            ed2[(size_t)br * N + n] = LOG2E * (pda[0][r] + pda[1][r] + pda[2][r] + pda[3][r]);
    }
}

// Fused GAT2 aggregation + per-graph pooled sums.
// Paired-edge gathers: lanes 0-31 take edge j, lanes 32-63 take edge j+1;
// each lane loads one dword (2 channels) of the 128B row.
__global__ __launch_bounds__(256) void a2pl_kernel(
    const unsigned short* __restrict__ xl2h, const float* __restrict__ es2, const float* __restrict__ ed2,
    const int* __restrict__ csr, const int* __restrict__ rs,
    const float* __restrict__ b2b, const float* __restrict__ b2t,
    const int* __restrict__ batchb, const int* __restrict__ batcht,
    float* __restrict__ pooled, int N, int E){
    int bid = blockIdx.x;
    int br = bid & 1;                 // branch parity == XCD parity class
    int tid = threadIdx.x, lane = tid & 63, w = tid >> 6;
    int n = ((bid >> 1) << 2) + w;
    const unsigned* xlu = (const unsigned*)(xl2h + (size_t)br * N * 64);  // 32 words/row
    const float* es = es2 + (size_t)br * N;
    const float* ed = ed2 + (size_t)br * N;
    const int* cs = csr + (size_t)br * E;
    const int* rsb = rs + (size_t)br * (N + 1);
    const float* b2 = br ? b2t : b2b;
    const int* batch = br ? batcht : batchb;
    int hw = lane >> 5;        // which edge of the pair
    int cp = lane & 31;        // channel-pair index
    float accLo = 0.f, accHi = 0.f, dn = 0.f;
    float hv0 = 0.f, hv1 = 0.f;
    int g = -1;
    if (n < N){
        float edn = ed[n];
        if (hw == 0){
            float wself = exp2f(leaky02(es[n] + edn));
            unsigned pself = xlu[(size_t)n * 32 + cp];
            accLo = wself * bflo(pself);
            accHi = wself * bfhi(pself);
            if (cp == 0) dn = wself;
        }
        int beg = __builtin_amdgcn_readfirstlane(rsb[n]);
        int end = __builtin_amdgcn_readfirstlane(rsb[n + 1]);
        int j = beg;
        for (; j + 8 <= end; j += 8){
            int ss[4]; float ee[4]; unsigned pp[4];
            #pragma unroll
            for (int q = 0; q < 4; ++q) ss[q] = cs[j + 2 * q + hw];
            #pragma unroll
            for (int q = 0; q < 4; ++q){
                ee[q] = es[ss[q]];
                pp[q] = xlu[(size_t)ss[q] * 32 + cp];
            }
            #pragma unroll
            for (int q = 0; q < 4; ++q){
                float wq = exp2f(leaky02(ee[q] + edn));
                if (cp == 0) dn += wq;
                accLo += wq * bflo(pp[q]);
                accHi += wq * bfhi(pp[q]);
            }
        }
        for (; j < end; j += 2){
            int eidx = j + hw;
            bool ok = eidx < end;
            int s = cs[ok ? eidx : (end - 1)];
            float e = es[s];
            unsigned p = xlu[(size_t)s * 32 + cp];
            float wq = ok ? exp2f(leaky02(e + edn)) : 0.f;
            if (cp == 0) dn += wq;
            accLo += wq * bflo(p);
            accHi += wq * bfhi(p);
        }
        // combine edge-pair halves
        accLo += __shfl_down(accLo, 32, 64);
        accHi += __shfl_down(accHi, 32, 64);
        dn    += __shfl_down(dn, 32, 64);
        float denom = __shfl(dn, 0, 64);
        if (hw == 0){
            float inv = 1.f / denom;
            hv0 = elu1(accLo * inv + b2[2 * cp]);
            hv1 = elu1(accHi * inv + b2[2 * cp + 1]);
        }
        g = batch[n];
    }
    __shared__ float red[4][64];
    __shared__ int gid[4];
    if (hw == 0){
        red[w][2 * cp]     = hv0;
        red[w][2 * cp + 1] = hv1;
    }
    if (lane == 0) gid[w] = g;
    __syncthreads();
    if (w == 0){
        int g0 = gid[0], g1 = gid[1], g2 = gid[2], g3 = gid[3];
        float* pb = pooled + (size_t)br * 4096;
        if (g0 >= 0 && g0 == g1 && g1 == g2 && g2 == g3){
            float s = (red[0][lane] + red[1][lane]) + (red[2][lane] + red[3][lane]);
            atomicAdd(&pb[g0 * 64 + lane], s);
        } else {
            #pragma unroll
            for (int q = 0; q < 4; ++q)
                if (gid[q] >= 0) atomicAdd(&pb[gid[q] * 64 + lane], red[q][lane]);
        }
    }
}

// counts (binary search on sorted batch) + branch MLPs + combine + final head
__global__ __launch_bounds__(1024) void tail_kernel(
    const float* __restrict__ pooled,
    const int* __restrict__ batchb, const int* __restrict__ batcht,
    const float* __restrict__ M1wb, const float* __restrict__ M1bb,
    const float* __restrict__ M2wb, const float* __restrict__ M2bb,
    const float* __restrict__ M1wt, const float* __restrict__ M1bt,
    const float* __restrict__ M2wt, const float* __restrict__ M2bt,
    const float* __restrict__ Fw1, const float* __restrict__ Fb1,
    const float* __restrict__ Fw2, const float* __restrict__ Fb2,
    float* __restrict__ out, int N){
    __shared__ float P[8192];
    __shared__ float H[8192];
    __shared__ float cl[128];
    int t = threadIdx.x;
    if (t < 128){
        int br = t >> 6, g = t & 63;
        const int* batch = br ? batcht : batchb;
        int lo = 0, hi = N;
        while (lo < hi){ int mid = (lo + hi) >> 1; if (batch[mid] < g) lo = mid + 1; else hi = mid; }
        int beg = lo;
        hi = N;
        while (lo < hi){ int mid = (lo + hi) >> 1; if (batch[mid] < g + 1) lo = mid + 1; else hi = mid; }
        cl[t] = (float)(lo - beg);
    }
    __syncthreads();
    for (int i = t; i < 8192; i += 1024)
        P[i] = pooled[i] / fmaxf(cl[i >> 6], 1.f);
    __syncthreads();
    for (int i = t; i < 8192; i += 1024){
        int br = i >> 12, r = (i >> 6) & 63, c = i & 63;
        const float* M1w = br ? M1wt : M1wb;
        const float* M1b = br ? M1bt : M1bb;
        float acc = M1b[c];
        int pb = (br << 12) + (r << 6);
        #pragma unroll 8
        for (int k = 0; k < 64; ++k) acc += P[pb + k] * M1w[(k << 6) + c];
        H[i] = fmaxf(acc, 0.f);
    }
    __syncthreads();
    for (int i = t; i < 8192; i += 1024){
        int br = i >> 12, r = (i >> 6) & 63, c = i & 63;
        const float* M2w = br ? M2wt : M2wb;
        const float* M2b = br ? M2bt : M2bb;
        float acc = M2b[c];
        int hb = (br << 12) + (r << 6);
        #pragma unroll 8
        for (int k = 0; k < 64; ++k) acc += H[hb + k] * M2w[(k << 6) + c];
        P[i] = acc;
    }
    __syncthreads();
    for (int i = t; i < 4096; i += 1024) H[i] = P[i] * P[4096 + i];
    __syncthreads();
    for (int i = t; i < 4096; i += 1024){
        int r = i >> 6, c = i & 63;
        float acc = Fb1[c];
        #pragma unroll 8
        for (int k = 0; k < 64; ++k) acc += H[(r << 6) + k] * Fw1[(k << 6) + c];
        P[i] = fmaxf(acc, 0.f);
    }
    __syncthreads();
    if (t < 128){
        int r = t >> 1, jc = t & 1;
        float acc = Fb2[jc];
        #pragma unroll 8
        for (int k = 0; k < 64; ++k) acc += P[(r << 6) + k] * Fw2[k * 2 + jc];
        out[t] = tanhf(acc);
    }
}

extern "C" void kernel_launch(void* const* d_in, const int* in_sizes, int n_in,
                              void* d_out, int out_size, void* d_ws, size_t ws_size,
                              hipStream_t stream){
    const int N = in_sizes[0] / 2;
    const int E = in_sizes[1] / 2;
    const int NB = (N + 511) >> BSH;   // nodes-per-bucket = 512, NB <= 128

    char* ws = (char*)d_ws;
    size_t off = 0;
    auto alloc = [&](size_t bytes) -> char* {
        char* p = ws + off;
        off += (bytes + 255) & ~(size_t)255;
        return p;
    };
    unsigned* XL1u = (unsigned*)alloc((size_t)2 * N * 64 * 4);
    unsigned short* XL2h = (unsigned short*)alloc((size_t)2 * N * 64 * 2);  // EPAIR aliases this
    float* ES1 = (float*)alloc((size_t)2 * N * 2 * 4);
    float* ED1 = (float*)alloc((size_t)2 * N * 2 * 4);
    float* ES2 = (float*)alloc((size_t)2 * N * 4);
    float* ED2 = (float*)alloc((size_t)2 * N * 4);
    int* RS  = (int*)alloc((size_t)2 * (N + 1) * 4);
    int* CSR = (int*)alloc((size_t)2 * E * 4);
    int* BCUR = (int*)alloc((size_t)2 * NB * 4);
    float* POOLED = (float*)alloc(8192 * 4);
    unsigned short* W2T = (unsigned short*)alloc(2 * 8192 * 2);
    unsigned* EPAIR = (unsigned*)XL2h;   // 2*NB*ARENA*4 <= 2*N*128 bytes; dead after csr

    const float* xb   = (const float*)d_in[0];
    const int*   eib  = (const int*)  d_in[1];
    const int*   batchb = (const int*)d_in[2];
    const float* W1b  = (const float*)d_in[3];
    const float* a1sb = (const float*)d_in[4];
    const float* a1db = (const float*)d_in[5];
    const float* b1b  = (const float*)d_in[6];
    const float* W2b  = (const float*)d_in[7];
    const float* a2sb = (const float*)d_in[8];
    const float* a2db = (const float*)d_in[9];
    const float* b2b  = (const float*)d_in[10];
    const float* M1wb = (const float*)d_in[11];
    const float* M1bb = (const float*)d_in[12];
    const float* M2wb = (const float*)d_in[13];
    const float* M2bb = (const float*)d_in[14];
    const float* xt   = (const float*)d_in[15];
    const int*   eit  = (const int*)  d_in[16];
    const int*   batcht = (const int*)d_in[17];
    const float* W1t  = (const float*)d_in[18];
    const float* a1st = (const float*)d_in[19];
    const float* a1dt = (const float*)d_in[20];
    const float* b1t  = (const float*)d_in[21];
    const float* W2t  = (const float*)d_in[22];
    const float* a2st = (const float*)d_in[23];
    const float* a2dt = (const float*)d_in[24];
    const float* b2t  = (const float*)d_in[25];
    const float* M1wt = (const float*)d_in[26];
    const float* M1bt = (const float*)d_in[27];
    const float* M2wt = (const float*)d_in[28];
    const float* M2bt = (const float*)d_in[29];
    const float* Fw1  = (const float*)d_in[30];
    const float* Fb1  = (const float*)d_in[31];
    const float* Fw2  = (const float*)d_in[32];
    const float* Fb2  = (const float*)d_in[33];

    const int nodeBlocks = (N + 3) / 4;
    const int histBlocks = (E + CHUNK - 1) / CHUNK;
    const int tilesPer   = (N + 15) / 16;

    hipMemsetAsync(BCUR, 0, (size_t)2 * NB * 4, stream);
    preb_kernel<<<2 * histBlocks + 2 * nodeBlocks + 3, 256, 0, stream>>>(
        xb, xt, W1b, W1t, a1sb, a1st, a1db, a1dt, eib, eit, W2b, W2t,
        XL1u, ES1, ED1, BCUR, EPAIR, W2T, POOLED, N, E, NB, nodeBlocks, histBlocks);
    csr_kernel<<<2 * NB, 256, 0, stream>>>(BCUR, EPAIR, RS, CSR, N, E, NB);
    a1f2_kernel<<<2 * tilesPer, 256, 0, stream>>>(
        XL1u, ES1, ED1, CSR, RS, b1b, b1t, W2T,
        a2sb, a2st, a2db, a2dt, XL2h, ES2, ED2, N, E);
    a2pl_kernel<<<2 * nodeBlocks, 256, 0, stream>>>(
        XL2h, ES2, ED2, CSR, RS, b2b, b2t, batchb, batcht, POOLED, N, E);
    tail_kernel<<<1, 1024, 0, stream>>>(POOLED, batchb, batcht,
        M1wb, M1bb, M2wb, M2bb, M1wt, M1bt, M2wt, M2bt,
        Fw1, Fb1, Fw2, Fb2, (float*)d_out, N);
}

// Round 8
// 277.865 us; speedup vs baseline: 3.3210x; 1.0158x over previous
//
#include <hip/hip_runtime.h>
#include <math.h>

// ---------------------------------------------------------------------------
// DeepONet/GAT, fused pipeline (R8):
//   memset: BCUR (tiny)
//   preb  : feat1 (x@W1 -> xl1 bf16, logits pre-scaled by log2e) + W2->bf16^T
//           + POOLED zero + bin (edge bucket-sort into fixed arenas)
//   csr   : per-bucket CSR build (compact, window-local scatter)
//   a1f2  : GAT1 aggregation (exp2, scalar indices) -> h1 in LDS -> MFMA -> xl2
//   a2pl  : GAT2 aggregation (full-row gathers, scalar indices) -> pools
//   tail  : counts + branch MLPs + combine + final head
// Buckets: 512 nodes (BSH=9), NB <= 128 (N <= 65536), arena 12288 edges.
// ---------------------------------------------------------------------------

#define BSH 9
#define CHUNK 4096
#define ARENA 12288
#define LOG2E 1.44269504088896f

using short8v = __attribute__((ext_vector_type(8))) short;
using f32x4  = __attribute__((ext_vector_type(4))) float;

__device__ __forceinline__ float leaky02(float x){ return fmaxf(x, 0.2f * x); }
__device__ __forceinline__ float elu1(float x){ return x > 0.f ? x : expm1f(x); }
__device__ __forceinline__ unsigned f2bf(float a){
    unsigned u = __float_as_uint(a);
    return (u + 0x7FFFu + ((u >> 16) & 1u)) >> 16;
}
__device__ __forceinline__ unsigned packbf(float a, float b){ return f2bf(a) | (f2bf(b) << 16); }
__device__ __forceinline__ float bflo(unsigned p){ return __uint_as_float(p << 16); }
__device__ __forceinline__ float bfhi(unsigned p){ return __uint_as_float(p & 0xFFFF0000u); }
__device__ __forceinline__ float bfs(unsigned short s){ return __uint_as_float(((unsigned)s) << 16); }

__device__ __forceinline__ int wave_incl_scan(int v, int lane){
    #pragma unroll
    for (int d = 1; d < 64; d <<= 1){ int u = __shfl_up(v, (unsigned)d, 64); if (lane >= d) v += u; }
    return v;
}

// feat1 + W2 transpose + POOLED zero + edge binning, grid-split.
__global__ __launch_bounds__(256) void preb_kernel(
    const float* __restrict__ xb, const float* __restrict__ xt,
    const float* __restrict__ W1b, const float* __restrict__ W1t,
    const float* __restrict__ a1sb, const float* __restrict__ a1st,
    const float* __restrict__ a1db, const float* __restrict__ a1dt,
    const int* __restrict__ eib, const int* __restrict__ eit,
    const float* __restrict__ W2b, const float* __restrict__ W2t,
    unsigned* __restrict__ xl1u, float* __restrict__ es1, float* __restrict__ ed1,
    int* __restrict__ bcur, unsigned* __restrict__ epair,
    unsigned short* __restrict__ w2T, float* __restrict__ pooled,
    int N, int E, int NB, int nodeBlocks, int histBlocks){
    int bid = blockIdx.x;
    int tid = threadIdx.x;
    __shared__ int hist[128], gpos[128];
    __shared__ int slots[CHUNK];
    if (bid < 2 * histBlocks){
        // ---- bin: bucket-sort one 4096-edge chunk into fixed arenas ----
        int br = (bid >= histBlocks) ? 1 : 0;
        int cb = bid - br * histBlocks;
        const int* ei = br ? eit : eib;
        int start = cb * CHUNK;
        int cnt = min(CHUNK, E - start);
        for (int i = tid; i < 128; i += 256) hist[i] = 0;
        __syncthreads();
        const int* dstp = ei + E + start;
        const int* srcp = ei + start;
        for (int li = tid; li < cnt; li += 256){
            int b = dstp[li] >> BSH;
            slots[li] = atomicAdd(&hist[b], 1);
        }
        __syncthreads();
        if (tid < NB){
            int h0 = hist[tid];
            gpos[tid] = (h0 > 0) ? atomicAdd(&bcur[br * NB + tid], h0) : 0;
        }
        __syncthreads();
        unsigned* ep = epair + (size_t)br * NB * ARENA;
        for (int li = tid; li < cnt; li += 256){
            int d = dstp[li];
            int b = d >> BSH;
            ep[(size_t)b * ARENA + gpos[b] + slots[li]] =
                ((unsigned)srcp[li] << BSH) | (unsigned)(d & ((1 << BSH) - 1));
        }
        return;
    }
    bid -= 2 * histBlocks;
    if (bid >= 2 * nodeBlocks){
        int xb2 = bid - 2 * nodeBlocks;
        if (xb2 < 2){
            // W2T[c][k] = bf16(W2[k][c]), per branch
            const float* W2 = xb2 ? W2t : W2b;
            for (int i = tid; i < 8192; i += 256){
                int c = i >> 7, k = i & 127;
                w2T[xb2 * 8192 + i] = (unsigned short)f2bf(W2[k * 64 + c]);
            }
        } else {
            for (int i = tid; i < 8192; i += 256) pooled[i] = 0.f;
        }
        return;
    }
    // ---- feat1 ----
    int br = (bid >= nodeBlocks) ? 1 : 0;
    int nb = bid - br * nodeBlocks;
    int n = (nb << 2) + (tid >> 6);
    int lane = tid & 63;
    if (n >= N) return;
    const float* x   = br ? xt   : xb;
    const float* W1  = br ? W1t  : W1b;
    const float* a1s = br ? a1st : a1sb;
    const float* a1d = br ? a1dt : a1db;
    float2 xv = ((const float2*)x)[n];
    float2 w0 = ((const float2*)W1)[lane];
    float2 w1 = ((const float2*)(W1 + 128))[lane];
    float xla = xv.x * w0.x + xv.y * w1.x;
    float xlb = xv.x * w0.y + xv.y * w1.y;
    xl1u[(size_t)br * N * 64 + (size_t)n * 64 + lane] = packbf(xla, xlb);
    float2 as = ((const float2*)a1s)[lane];
    float2 ad = ((const float2*)a1d)[lane];
    float ps = xla * as.x + xlb * as.y;
    float pd = xla * ad.x + xlb * ad.y;
    #pragma unroll
    for (int m = 16; m >= 1; m >>= 1){ ps += __shfl_xor(ps, m, 64); pd += __shfl_xor(pd, m, 64); }
    if ((lane & 31) == 0){
        int h = lane >> 5;
        es1[(size_t)br * N * 2 + n * 2 + h] = LOG2E * ps;
        ed1[(size_t)br * N * 2 + n * 2 + h] = LOG2E * pd;
    }
}

// per-bucket CSR: compact bases from bcur scan, local degrees, scatter src.
__global__ __launch_bounds__(256) void csr_kernel(
    const int* __restrict__ bcur, const unsigned* __restrict__ epair,
    int* __restrict__ rs, int* __restrict__ csr, int N, int E, int NB){
    int bid = blockIdx.x;
    int br = (bid >= NB) ? 1 : 0;
    int b = bid - br * NB;
    __shared__ int base2[128];
    __shared__ int deg[512], st[512];
    int tid = threadIdx.x, lane = tid & 63, wid = tid >> 6;
    if (wid == 0){
        int b0 = (lane < NB) ? bcur[br * NB + lane] : 0;
        int b1 = (64 + lane < NB) ? bcur[br * NB + 64 + lane] : 0;
        int g0 = wave_incl_scan(b0, lane); int gt = __shfl(g0, 63, 64);
        int g1 = wave_incl_scan(b1, lane);
        base2[lane] = g0 - b0; base2[64 + lane] = gt + g1 - b1;
    }
    for (int i = tid; i < 512; i += 256) deg[i] = 0;
    __syncthreads();
    int ebase = base2[b];
    int ecnt = bcur[br * NB + b];
    int n0 = b << BSH;
    int nodes = min(512, N - n0);
    const unsigned* ep = epair + ((size_t)br * NB + b) * ARENA;
    for (int i = tid; i < ecnt; i += 256) atomicAdd(&deg[ep[i] & 511u], 1);
    __syncthreads();
    if (wid == 0){
        int carry = 0;
        #pragma unroll
        for (int c = 0; c < 8; ++c){
            int v = deg[c * 64 + lane];
            int s = wave_incl_scan(v, lane);
            st[c * 64 + lane] = carry + s - v;
            carry += __shfl(s, 63, 64);
        }
    }
    __syncthreads();
    int* rsb = rs + (size_t)br * (N + 1);
    for (int i = tid; i < nodes; i += 256) rsb[n0 + i] = ebase + st[i];
    if (b == NB - 1 && tid == 0) rsb[N] = ebase + ecnt;
    for (int i = tid; i < 512; i += 256) deg[i] = st[i];
    __syncthreads();
    int* csrb = csr + (size_t)br * E + ebase;
    for (int i = tid; i < ecnt; i += 256){
        unsigned p = ep[i];
        int pos = atomicAdd(&deg[p & 511u], 1);
        csrb[pos] = (int)(p >> BSH);
    }
}

// Fused GAT1 aggregation + (h1 @ W2T) MFMA + layer-2 logits. exp2-based,
// wave-uniform CSR indices forced to SGPRs, 32-bit gather addressing.
__global__ __launch_bounds__(256) void a1f2_kernel(
    const unsigned* __restrict__ xl1u, const float* __restrict__ es1, const float* __restrict__ ed1,
    const int* __restrict__ csr, const int* __restrict__ rs,
    const float* __restrict__ b1b, const float* __restrict__ b1t,
    const unsigned short* __restrict__ w2T,
    const float* __restrict__ a2sb, const float* __restrict__ a2st,
    const float* __restrict__ a2db, const float* __restrict__ a2dt,
    unsigned short* __restrict__ xl2h, float* __restrict__ es2, float* __restrict__ ed2,
    int N, int E){
    int bid = blockIdx.x;
    int br = bid & 1;                 // branch parity == XCD parity class
    int n0 = (bid >> 1) << 4;
    const unsigned* xl = xl1u + (size_t)br * N * 64;
    const float* es = es1 + (size_t)br * N * 2;
    const float* ed = ed1 + (size_t)br * N * 2;
    const int* cs = csr + (size_t)br * E;
    const int* rsb = rs + (size_t)br * (N + 1);
    const float* b1 = br ? b1t : b1b;
    const float* a2s = br ? a2st : a2sb;
    const float* a2d = br ? a2dt : a2db;

    __shared__ unsigned hl[16][68];          // h1 tile, packed bf16 pairs, padded
    __shared__ float psa[4][16], pda[4][16];
    int tid = threadIdx.x, lane = tid & 63, w = tid >> 6;

    int h = lane >> 5;
    int c = lane << 1;
    float b1lo = b1[c], b1hi = b1[c + 1];
    #pragma unroll
    for (int nn = 0; nn < 4; ++nn){
        int row = w * 4 + nn;
        int n = n0 + row;
        if (n >= N){ hl[row][lane] = 0u; continue; }
        float edn = ed[n * 2 + h];
        float wself = exp2f(leaky02(es[n * 2 + h] + edn));
        unsigned pself = xl[(unsigned)(n * 64) + lane];
        float denom = wself;
        float ax = wself * bflo(pself);
        float ay = wself * bfhi(pself);
        int beg = __builtin_amdgcn_readfirstlane(rsb[n]);
        int end = __builtin_amdgcn_readfirstlane(rsb[n + 1]);
        int j = beg;
        for (; j + 8 <= end; j += 8){
            int ss[8]; unsigned pp[8]; float ee[8];
            #pragma unroll
            for (int q = 0; q < 8; ++q) ss[q] = __builtin_amdgcn_readfirstlane(cs[j + q]);
            #pragma unroll
            for (int q = 0; q < 8; ++q){
                ee[q] = es[ss[q] * 2 + h];
                pp[q] = xl[(unsigned)(ss[q] * 64) + lane];
            }
            #pragma unroll
            for (int q = 0; q < 8; ++q){
                float wq = exp2f(leaky02(ee[q] + edn));
                denom += wq;
                ax += wq * bflo(pp[q]);
                ay += wq * bfhi(pp[q]);
            }
        }
        for (; j < end; ++j){
            int s = __builtin_amdgcn_readfirstlane(cs[j]);
            float wq = exp2f(leaky02(es[s * 2 + h] + edn));
            unsigned p = xl[(unsigned)(s * 64) + lane];
            denom += wq;
            ax += wq * bflo(p);
            ay += wq * bfhi(p);
        }
        float inv = 1.f / denom;
        hl[row][lane] = packbf(elu1(ax * inv + b1lo), elu1(ay * inv + b1hi));
    }

    int lr = lane & 15, lq = lane >> 4;
    // B fragments straight from global bf16 W2T (L1-resident 16KB/branch)
    const unsigned short* wtp = w2T + br * 8192 + (w * 16 + lr) * 128 + lq * 8;
    short8v bf0 = *(const short8v*)(wtp);
    short8v bf1 = *(const short8v*)(wtp + 32);
    short8v bf2 = *(const short8v*)(wtp + 64);
    short8v bf3 = *(const short8v*)(wtp + 96);
    __syncthreads();
    f32x4 ac = {0.f, 0.f, 0.f, 0.f};
    ac = __builtin_amdgcn_mfma_f32_16x16x32_bf16(*(const short8v*)&hl[lr][lq * 4], bf0, ac, 0, 0, 0);
    ac = __builtin_amdgcn_mfma_f32_16x16x32_bf16(*(const short8v*)&hl[lr][16 + lq * 4], bf1, ac, 0, 0, 0);
    ac = __builtin_amdgcn_mfma_f32_16x16x32_bf16(*(const short8v*)&hl[lr][32 + lq * 4], bf2, ac, 0, 0, 0);
    ac = __builtin_amdgcn_mfma_f32_16x16x32_bf16(*(const short8v*)&hl[lr][48 + lq * 4], bf3, ac, 0, 0, 0);
    float a2sv = a2s[w * 16 + lr];
    float a2dv = a2d[w * 16 + lr];
    #pragma unroll
    for (int reg = 0; reg < 4; ++reg){
        int r = lq * 4 + reg;
        int n = n0 + r;
        float v = ac[reg];
        if (n < N)
            xl2h[((size_t)br * N + n) * 64 + w * 16 + lr] = (unsigned short)f2bf(v);
        float ps = v * a2sv, pd = v * a2dv;
        ps += __shfl_xor(ps, 1, 64); ps += __shfl_xor(ps, 2, 64);
        ps += __shfl_xor(ps, 4, 64); ps += __shfl_xor(ps, 8, 64);
        pd += __shfl_xor(pd, 1, 64); pd += __shfl_xor(pd, 2, 64);
        pd += __shfl_xor(pd, 4, 64); pd += __shfl_xor(pd, 8, 64);
        if (lr == 0){ psa[w][r] = ps; pda[w][r] = pd; }
    }
    __syncthreads();
    if (tid < 16){
        int n = n0 + tid;
        if (n < N)
            es2[(size_t)br * N + n] = LOG2E * (psa[0][tid] + psa[1][tid] + psa[2][tid] + psa[3][tid]);
    } else if (tid < 32){
        int r = tid - 16;
        int n = n0 + r;
        if (n < N)
            ed2[(size_t)br * N + n] = LOG2E * (pda[0][r] + pda[1][r] + pda[2][r] + pda[3][r]);
    }
}

// Fused GAT2 aggregation + per-graph pooled sums. Full-row ushort gathers,
// exp2, wave-uniform indices in SGPRs, 32-bit addressing.
__global__ __launch_bounds__(256) void a2pl_kernel(
    const unsigned short* __restrict__ xl2h, const float* __restrict__ es2, const float* __restrict__ ed2,
    const int* __restrict__ csr, const int* __restrict__ rs,
    const float* __restrict__ b2b, const float* __restrict__ b2t,
    const int* __restrict__ batchb, const int* __restrict__ batcht,
    float* __restrict__ pooled, int N, int E){
    int bid = blockIdx.x;
    int br = bid & 1;                 // branch parity == XCD parity class
    int tid = threadIdx.x, lane = tid & 63, w = tid >> 6;
    int n = ((bid >> 1) << 2) + w;
    const unsigned short* xlt = xl2h + (size_t)br * N * 64;
    const float* es = es2 + (size_t)br * N;
    const float* ed = ed2 + (size_t)br * N;
    const int* cs = csr + (size_t)br * E;
    const int* rsb = rs + (size_t)br * (N + 1);
    const float* b2 = br ? b2t : b2b;
    const int* batch = br ? batcht : batchb;
    float hv = 0.f;
    int g = -1;
    if (n < N){
        float edn = ed[n];
        float wself = exp2f(leaky02(es[n] + edn));
        float denom = wself;
        float acc = wself * bfs(xlt[(unsigned)(n * 64) + lane]);
        int beg = __builtin_amdgcn_readfirstlane(rsb[n]);
        int end = __builtin_amdgcn_readfirstlane(rsb[n + 1]);
        int j = beg;
        for (; j + 8 <= end; j += 8){
            int ss[8]; float ee[8], vv[8];
            #pragma unroll
            for (int q = 0; q < 8; ++q) ss[q] = __builtin_amdgcn_readfirstlane(cs[j + q]);
            #pragma unroll
            for (int q = 0; q < 8; ++q){
                ee[q] = es[ss[q]];
                vv[q] = bfs(xlt[(unsigned)(ss[q] * 64) + lane]);
            }
            #pragma unroll
            for (int q = 0; q < 8; ++q){
                float wq = exp2f(leaky02(ee[q] + edn));
                denom += wq;
                acc += wq * vv[q];
            }
        }
        for (; j < end; ++j){
            int s = __builtin_amdgcn_readfirstlane(cs[j]);
            float wq = exp2f(leaky02(es[s] + edn));
            denom += wq;
            acc += wq * bfs(xlt[(unsigned)(s * 64) + lane]);
        }
        hv = elu1(acc / denom + b2[lane]);
        g = batch[n];
    }
    __shared__ float red[4][64];
    __shared__ int gid[4];
    red[w][lane] = hv;
    if (lane == 0) gid[w] = g;
    __syncthreads();
    if (w == 0){
        int g0 = gid[0], g1 = gid[1], g2 = gid[2], g3 = gid[3];
        float* pb = pooled + (size_t)br * 4096;
        if (g0 >= 0 && g0 == g1 && g1 == g2 && g2 == g3){
            float s = (red[0][lane] + red[1][lane]) + (red[2][lane] + red[3][lane]);
            atomicAdd(&pb[g0 * 64 + lane], s);
        } else {
            #pragma unroll
            for (int q = 0; q < 4; ++q)
                if (gid[q] >= 0) atomicAdd(&pb[gid[q] * 64 + lane], red[q][lane]);
        }
    }
}

// counts (binary search on sorted batch) + branch MLPs + combine + final head
__global__ __launch_bounds__(1024) void tail_kernel(
    const float* __restrict__ pooled,
    const int* __restrict__ batchb, const int* __restrict__ batcht,
    const float* __restrict__ M1wb, const float* __restrict__ M1bb,
    const float* __restrict__ M2wb, const float* __restrict__ M2bb,
    const float* __restrict__ M1wt, const float* __restrict__ M1bt,
    const float* __restrict__ M2wt, const float* __restrict__ M2bt,
    const float* __restrict__ Fw1, const float* __restrict__ Fb1,
    const float* __restrict__ Fw2, const float* __restrict__ Fb2,
    float* __restrict__ out, int N){
    __shared__ float P[8192];
    __shared__ float H[8192];
    __shared__ float cl[128];
    int t = threadIdx.x;
    if (t < 128){
        int br = t >> 6, g = t & 63;
        const int* batch = br ? batcht : batchb;
        int lo = 0, hi = N;
        while (lo < hi){ int mid = (lo + hi) >> 1; if (batch[mid] < g) lo = mid + 1; else hi = mid; }
        int beg = lo;
        hi = N;
        while (lo < hi){ int mid = (lo + hi) >> 1; if (batch[mid] < g + 1) lo = mid + 1; else hi = mid; }
        cl[t] = (float)(lo - beg);
    }
    __syncthreads();
    for (int i = t; i < 8192; i += 1024)
        P[i] = pooled[i] / fmaxf(cl[i >> 6], 1.f);
    __syncthreads();
    for (int i = t; i < 8192; i += 1024){
        int br = i >> 12, r = (i >> 6) & 63, c = i & 63;
        const float* M1w = br ? M1wt : M1wb;
        const float* M1b = br ? M1bt : M1bb;
        float acc = M1b[c];
        int pb = (br << 12) + (r << 6);
        #pragma unroll 8
        for (int k = 0; k < 64; ++k) acc += P[pb + k] * M1w[(k << 6) + c];
        H[i] = fmaxf(acc, 0.f);
    }
    __syncthreads();
    for (int i = t; i < 8192; i += 1024){
        int br = i >> 12, r = (i >> 6) & 63, c = i & 63;
        const float* M2w = br ? M2wt : M2wb;
        const float* M2b = br ? M2bt : M2bb;
        float acc = M2b[c];
        int hb = (br << 12) + (r << 6);
        #pragma unroll 8
        for (int k = 0; k < 64; ++k) acc += H[hb + k] * M2w[(k << 6) + c];
        P[i] = acc;
    }
    __syncthreads();
    for (int i = t; i < 4096; i += 1024) H[i] = P[i] * P[4096 + i];
    __syncthreads();
    for (int i = t; i < 4096; i += 1024){
        int r = i >> 6, c = i & 63;
        float acc = Fb1[c];
        #pragma unroll 8
        for (int k = 0; k < 64; ++k) acc += H[(r << 6) + k] * Fw1[(k << 6) + c];
        P[i] = fmaxf(acc, 0.f);
    }
    __syncthreads();
    if (t < 128){
        int r = t >> 1, jc = t & 1;
        float acc = Fb2[jc];
        #pragma unroll 8
        for (int k = 0; k < 64; ++k) acc += P[(r << 6) + k] * Fw2[k * 2 + jc];
        out[t] = tanhf(acc);
    }
}

extern "C" void kernel_launch(void* const* d_in, const int* in_sizes, int n_in,
                              void* d_out, int out_size, void* d_ws, size_t ws_size,
                              hipStream_t stream){
    const int N = in_sizes[0] / 2;
    const int E = in_sizes[1] / 2;
    const int NB = (N + 511) >> BSH;   // nodes-per-bucket = 512, NB <= 128

    char* ws = (char*)d_ws;
    size_t off = 0;
    auto alloc = [&](size_t bytes) -> char* {
        char* p = ws + off;
        off += (bytes + 255) & ~(size_t)255;
        return p;
    };
    unsigned* XL1u = (unsigned*)alloc((size_t)2 * N * 64 * 4);
    unsigned short* XL2h = (unsigned short*)alloc((size_t)2 * N * 64 * 2);  // EPAIR aliases this
    float* ES1 = (float*)alloc((size_t)2 * N * 2 * 4);
    float* ED1 = (float*)alloc((size_t)2 * N * 2 * 4);
    float* ES2 = (float*)alloc((size_t)2 * N * 4);
    float* ED2 = (float*)alloc((size_t)2 * N * 4);
    int* RS  = (int*)alloc((size_t)2 * (N + 1) * 4);
    int* CSR = (int*)alloc((size_t)2 * E * 4);
    int* BCUR = (int*)alloc((size_t)2 * NB * 4);
    float* POOLED = (float*)alloc(8192 * 4);
    unsigned short* W2T = (unsigned short*)alloc(2 * 8192 * 2);
    unsigned* EPAIR = (unsigned*)XL2h;   // 2*NB*ARENA*4 <= 2*N*128 bytes; dead after csr

    const float* xb   = (const float*)d_in[0];
    const int*   eib  = (const int*)  d_in[1];
    const int*   batchb = (const int*)d_in[2];
    const float* W1b  = (const float*)d_in[3];
    const float* a1sb = (const float*)d_in[4];
    const float* a1db = (const float*)d_in[5];
    const float* b1b  = (const float*)d_in[6];
    const float* W2b  = (const float*)d_in[7];
    const float* a2sb = (const float*)d_in[8];
    const float* a2db = (const float*)d_in[9];
    const float* b2b  = (const float*)d_in[10];
    const float* M1wb = (const float*)d_in[11];
    const float* M1bb = (const float*)d_in[12];
    const float* M2wb = (const float*)d_in[13];
    const float* M2bb = (const float*)d_in[14];
    const float* xt   = (const float*)d_in[15];
    const int*   eit  = (const int*)  d_in[16];
    const int*   batcht = (const int*)d_in[17];
    const float* W1t  = (const float*)d_in[18];
    const float* a1st = (const float*)d_in[19];
    const float* a1dt = (const float*)d_in[20];
    const float* b1t  = (const float*)d_in[21];
    const float* W2t  = (const float*)d_in[22];
    const float* a2st = (const float*)d_in[23];
    const float* a2dt = (const float*)d_in[24];
    const float* b2t  = (const float*)d_in[25];
    const float* M1wt = (const float*)d_in[26];
    const float* M1bt = (const float*)d_in[27];
    const float* M2wt = (const float*)d_in[28];
    const float* M2bt = (const float*)d_in[29];
    const float* Fw1  = (const float*)d_in[30];
    const float* Fb1  = (const float*)d_in[31];
    const float* Fw2  = (const float*)d_in[32];
    const float* Fb2  = (const float*)d_in[33];

    const int nodeBlocks = (N + 3) / 4;
    const int histBlocks = (E + CHUNK - 1) / CHUNK;
    const int tilesPer   = (N + 15) / 16;

    hipMemsetAsync(BCUR, 0, (size_t)2 * NB * 4, stream);
    preb_kernel<<<2 * histBlocks + 2 * nodeBlocks + 3, 256, 0, stream>>>(
        xb, xt, W1b, W1t, a1sb, a1st, a1db, a1dt, eib, eit, W2b, W2t,
        XL1u, ES1, ED1, BCUR, EPAIR, W2T, POOLED, N, E, NB, nodeBlocks, histBlocks);
    csr_kernel<<<2 * NB, 256, 0, stream>>>(BCUR, EPAIR, RS, CSR, N, E, NB);
    a1f2_kernel<<<2 * tilesPer, 256, 0, stream>>>(
        XL1u, ES1, ED1, CSR, RS, b1b, b1t, W2T,
        a2sb, a2st, a2db, a2dt, XL2h, ES2, ED2, N, E);
    a2pl_kernel<<<2 * nodeBlocks, 256, 0, stream>>>(
        XL2h, ES2, ED2, CSR, RS, b2b, b2t, batchb, batcht, POOLED, N, E);
    tail_kernel<<<1, 1024, 0, stream>>>(POOLED, batchb, batcht,
        M1wb, M1bb, M2wb, M2bb, M1wt, M1bt, M2wt, M2bt,
        Fw1, Fb1, Fw2, Fb2, (float*)d_out, N);
}

// Round 9
// 269.652 us; speedup vs baseline: 3.4221x; 1.0305x over previous
//
#include <hip/hip_runtime.h>
#include <math.h>

// ---------------------------------------------------------------------------
// DeepONet/GAT, fused pipeline (R9):
//   memset: BCUR (tiny)
//   preb  : feat1 (x@W1 -> xl1 bf16, logits pre-scaled by log2e) + W2->bf16^T
//           + POOLED zero + bin (edge bucket-sort into fixed arenas)
//   csr   : per-bucket CSR build (compact, window-local scatter)
//   a1f2  : GAT1 agg (exp2, shared-weight shfl broadcast) -> h1 LDS -> MFMA
//   a2pl  : GAT2 agg (shared weights) -> per-graph pools
//   tail  : counts + branch MLPs + combine + final head
// Buckets: 512 nodes (BSH=9), NB <= 128 (N <= 65536), arena 12288 edges.
// ---------------------------------------------------------------------------

#define BSH 9
#define CHUNK 4096
#define ARENA 12288
#define LOG2E 1.44269504088896f

using short8v = __attribute__((ext_vector_type(8))) short;
using f32x4  = __attribute__((ext_vector_type(4))) float;

__device__ __forceinline__ float leaky02(float x){ return fmaxf(x, 0.2f * x); }
__device__ __forceinline__ float elu1(float x){ return x > 0.f ? x : expm1f(x); }
__device__ __forceinline__ unsigned f2bf(float a){
    unsigned u = __float_as_uint(a);
    return (u + 0x7FFFu + ((u >> 16) & 1u)) >> 16;
}
__device__ __forceinline__ unsigned packbf(float a, float b){ return f2bf(a) | (f2bf(b) << 16); }
__device__ __forceinline__ float bflo(unsigned p){ return __uint_as_float(p << 16); }
__device__ __forceinline__ float bfhi(unsigned p){ return __uint_as_float(p & 0xFFFF0000u); }
__device__ __forceinline__ float bfs(unsigned short s){ return __uint_as_float(((unsigned)s) << 16); }

__device__ __forceinline__ int wave_incl_scan(int v, int lane){
    #pragma unroll
    for (int d = 1; d < 64; d <<= 1){ int u = __shfl_up(v, (unsigned)d, 64); if (lane >= d) v += u; }
    return v;
}

// feat1 + W2 transpose + POOLED zero + edge binning, grid-split.
__global__ __launch_bounds__(256) void preb_kernel(
    const float* __restrict__ xb, const float* __restrict__ xt,
    const float* __restrict__ W1b, const float* __restrict__ W1t,
    const float* __restrict__ a1sb, const float* __restrict__ a1st,
    const float* __restrict__ a1db, const float* __restrict__ a1dt,
    const int* __restrict__ eib, const int* __restrict__ eit,
    const float* __restrict__ W2b, const float* __restrict__ W2t,
    unsigned* __restrict__ xl1u, float* __restrict__ es1, float* __restrict__ ed1,
    int* __restrict__ bcur, unsigned* __restrict__ epair,
    unsigned short* __restrict__ w2T, float* __restrict__ pooled,
    int N, int E, int NB, int nodeBlocks, int histBlocks){
    int bid = blockIdx.x;
    int tid = threadIdx.x;
    __shared__ int hist[128], gpos[128];
    __shared__ int slots[CHUNK];
    if (bid < 2 * histBlocks){
        // ---- bin: bucket-sort one 4096-edge chunk into fixed arenas ----
        int br = (bid >= histBlocks) ? 1 : 0;
        int cb = bid - br * histBlocks;
        const int* ei = br ? eit : eib;
        int start = cb * CHUNK;
        int cnt = min(CHUNK, E - start);
        for (int i = tid; i < 128; i += 256) hist[i] = 0;
        __syncthreads();
        const int* dstp = ei + E + start;
        const int* srcp = ei + start;
        for (int li = tid; li < cnt; li += 256){
            int b = dstp[li] >> BSH;
            slots[li] = atomicAdd(&hist[b], 1);
        }
        __syncthreads();
        if (tid < NB){
            int h0 = hist[tid];
            gpos[tid] = (h0 > 0) ? atomicAdd(&bcur[br * NB + tid], h0) : 0;
        }
        __syncthreads();
        unsigned* ep = epair + (size_t)br * NB * ARENA;
        for (int li = tid; li < cnt; li += 256){
            int d = dstp[li];
            int b = d >> BSH;
            ep[(size_t)b * ARENA + gpos[b] + slots[li]] =
                ((unsigned)srcp[li] << BSH) | (unsigned)(d & ((1 << BSH) - 1));
        }
        return;
    }
    bid -= 2 * histBlocks;
    if (bid >= 2 * nodeBlocks){
        int xb2 = bid - 2 * nodeBlocks;
        if (xb2 < 2){
            // W2T[c][k] = bf16(W2[k][c]), per branch
            const float* W2 = xb2 ? W2t : W2b;
            for (int i = tid; i < 8192; i += 256){
                int c = i >> 7, k = i & 127;
                w2T[xb2 * 8192 + i] = (unsigned short)f2bf(W2[k * 64 + c]);
            }
        } else {
            for (int i = tid; i < 8192; i += 256) pooled[i] = 0.f;
        }
        return;
    }
    // ---- feat1 ----
    int br = (bid >= nodeBlocks) ? 1 : 0;
    int nb = bid - br * nodeBlocks;
    int n = (nb << 2) + (tid >> 6);
    int lane = tid & 63;
    if (n >= N) return;
    const float* x   = br ? xt   : xb;
    const float* W1  = br ? W1t  : W1b;
    const float* a1s = br ? a1st : a1sb;
    const float* a1d = br ? a1dt : a1db;
    float2 xv = ((const float2*)x)[n];
    float2 w0 = ((const float2*)W1)[lane];
    float2 w1 = ((const float2*)(W1 + 128))[lane];
    float xla = xv.x * w0.x + xv.y * w1.x;
    float xlb = xv.x * w0.y + xv.y * w1.y;
    xl1u[(size_t)br * N * 64 + (size_t)n * 64 + lane] = packbf(xla, xlb);
    float2 as = ((const float2*)a1s)[lane];
    float2 ad = ((const float2*)a1d)[lane];
    float ps = xla * as.x + xlb * as.y;
    float pd = xla * ad.x + xlb * ad.y;
    #pragma unroll
    for (int m = 16; m >= 1; m >>= 1){ ps += __shfl_xor(ps, m, 64); pd += __shfl_xor(pd, m, 64); }
    if ((lane & 31) == 0){
        int h = lane >> 5;
        es1[(size_t)br * N * 2 + n * 2 + h] = LOG2E * ps;
        ed1[(size_t)br * N * 2 + n * 2 + h] = LOG2E * pd;
    }
}

// per-bucket CSR: compact bases from bcur scan, local degrees, scatter src.
__global__ __launch_bounds__(256) void csr_kernel(
    const int* __restrict__ bcur, const unsigned* __restrict__ epair,
    int* __restrict__ rs, int* __restrict__ csr, int N, int E, int NB){
    int bid = blockIdx.x;
    int br = (bid >= NB) ? 1 : 0;
    int b = bid - br * NB;
    __shared__ int base2[128];
    __shared__ int deg[512], st[512];
    int tid = threadIdx.x, lane = tid & 63, wid = tid >> 6;
    if (wid == 0){
        int b0 = (lane < NB) ? bcur[br * NB + lane] : 0;
        int b1 = (64 + lane < NB) ? bcur[br * NB + 64 + lane] : 0;
        int g0 = wave_incl_scan(b0, lane); int gt = __shfl(g0, 63, 64);
        int g1 = wave_incl_scan(b1, lane);
        base2[lane] = g0 - b0; base2[64 + lane] = gt + g1 - b1;
    }
    for (int i = tid; i < 512; i += 256) deg[i] = 0;
    __syncthreads();
    int ebase = base2[b];
    int ecnt = bcur[br * NB + b];
    int n0 = b << BSH;
    int nodes = min(512, N - n0);
    const unsigned* ep = epair + ((size_t)br * NB + b) * ARENA;
    for (int i = tid; i < ecnt; i += 256) atomicAdd(&deg[ep[i] & 511u], 1);
    __syncthreads();
    if (wid == 0){
        int carry = 0;
        #pragma unroll
        for (int c = 0; c < 8; ++c){
            int v = deg[c * 64 + lane];
            int s = wave_incl_scan(v, lane);
            st[c * 64 + lane] = carry + s - v;
            carry += __shfl(s, 63, 64);
        }
    }
    __syncthreads();
    int* rsb = rs + (size_t)br * (N + 1);
    for (int i = tid; i < nodes; i += 256) rsb[n0 + i] = ebase + st[i];
    if (b == NB - 1 && tid == 0) rsb[N] = ebase + ecnt;
    for (int i = tid; i < 512; i += 256) deg[i] = st[i];
    __syncthreads();
    int* csrb = csr + (size_t)br * E + ebase;
    for (int i = tid; i < ecnt; i += 256){
        unsigned p = ep[i];
        int pos = atomicAdd(&deg[p & 511u], 1);
        csrb[pos] = (int)(p >> BSH);
    }
}

// Fused GAT1 aggregation + (h1 @ W2T) MFMA + layer-2 logits. exp2-based,
// shared edge-weight computation (one producer lane per edge/head, shfl
// broadcast), scalar CSR indices, 32-bit gather addressing.
__global__ __launch_bounds__(256) void a1f2_kernel(
    const unsigned* __restrict__ xl1u, const float* __restrict__ es1, const float* __restrict__ ed1,
    const int* __restrict__ csr, const int* __restrict__ rs,
    const float* __restrict__ b1b, const float* __restrict__ b1t,
    const unsigned short* __restrict__ w2T,
    const float* __restrict__ a2sb, const float* __restrict__ a2st,
    const float* __restrict__ a2db, const float* __restrict__ a2dt,
    unsigned short* __restrict__ xl2h, float* __restrict__ es2, float* __restrict__ ed2,
    int N, int E){
    int bid = blockIdx.x;
    int br = bid & 1;                 // branch parity == XCD parity class
    int n0 = (bid >> 1) << 4;
    const unsigned* xl = xl1u + (size_t)br * N * 64;
    const float* es = es1 + (size_t)br * N * 2;
    const float* ed = ed1 + (size_t)br * N * 2;
    const int* cs = csr + (size_t)br * E;
    const int* rsb = rs + (size_t)br * (N + 1);
    const float* b1 = br ? b1t : b1b;
    const float* a2s = br ? a2st : a2sb;
    const float* a2d = br ? a2dt : a2db;

    __shared__ unsigned hl[16][68];          // h1 tile, packed bf16 pairs, padded
    __shared__ float psa[4][16], pda[4][16];
    int tid = threadIdx.x, lane = tid & 63, w = tid >> 6;

    int h = lane >> 5;
    int hsel = (lane >> 3) & 1;       // producer lanes 0-7: head0, 8-15: head1
    int qb = h << 3;                  // consumer base: 0 (head0) / 8 (head1)
    int c = lane << 1;
    float b1lo = b1[c], b1hi = b1[c + 1];
    #pragma unroll
    for (int nn = 0; nn < 4; ++nn){
        int row = w * 4 + nn;
        int n = n0 + row;
        if (n >= N){ hl[row][lane] = 0u; continue; }
        float edn = ed[n * 2 + h];
        float ednp = ed[n * 2 + hsel];       // producer-side edn
        float wself = exp2f(leaky02(es[n * 2 + h] + edn));
        unsigned pself = xl[(unsigned)(n * 64) + lane];
        float denom = wself;
        float ax = wself * bflo(pself);
        float ay = wself * bfhi(pself);
        int beg = __builtin_amdgcn_readfirstlane(rsb[n]);
        int end = __builtin_amdgcn_readfirstlane(rsb[n + 1]);
        int j = beg;
        for (; j + 8 <= end; j += 8){
            int svec = cs[j + (lane & 7)];
            float ev = es[svec * 2 + hsel];
            float wmine = exp2f(leaky02(ev + ednp));
            int ss[8]; unsigned pp[8]; float wq[8];
            #pragma unroll
            for (int q = 0; q < 8; ++q) ss[q] = __builtin_amdgcn_readfirstlane(cs[j + q]);
            #pragma unroll
            for (int q = 0; q < 8; ++q) pp[q] = xl[(unsigned)(ss[q] * 64) + lane];
            #pragma unroll
            for (int q = 0; q < 8; ++q) wq[q] = __shfl(wmine, qb + q, 64);
            #pragma unroll
            for (int q = 0; q < 8; ++q){
                denom += wq[q];
                ax += wq[q] * bflo(pp[q]);
                ay += wq[q] * bfhi(pp[q]);
            }
        }
        for (; j < end; ++j){
            int s = __builtin_amdgcn_readfirstlane(cs[j]);
            float wqv = exp2f(leaky02(es[s * 2 + h] + edn));
            unsigned p = xl[(unsigned)(s * 64) + lane];
            denom += wqv;
            ax += wqv * bflo(p);
            ay += wqv * bfhi(p);
        }
        float inv = 1.f / denom;
        hl[row][lane] = packbf(elu1(ax * inv + b1lo), elu1(ay * inv + b1hi));
    }

    int lr = lane & 15, lq = lane >> 4;
    // B fragments straight from global bf16 W2T (L1-resident 16KB/branch)
    const unsigned short* wtp = w2T + br * 8192 + (w * 16 + lr) * 128 + lq * 8;
    short8v bf0 = *(const short8v*)(wtp);
    short8v bf1 = *(const short8v*)(wtp + 32);
    short8v bf2 = *(const short8v*)(wtp + 64);
    short8v bf3 = *(const short8v*)(wtp + 96);
    __syncthreads();
    f32x4 ac = {0.f, 0.f, 0.f, 0.f};
    ac = __builtin_amdgcn_mfma_f32_16x16x32_bf16(*(const short8v*)&hl[lr][lq * 4], bf0, ac, 0, 0, 0);
    ac = __builtin_amdgcn_mfma_f32_16x16x32_bf16(*(const short8v*)&hl[lr][16 + lq * 4], bf1, ac, 0, 0, 0);
    ac = __builtin_amdgcn_mfma_f32_16x16x32_bf16(*(const short8v*)&hl[lr][32 + lq * 4], bf2, ac, 0, 0, 0);
    ac = __builtin_amdgcn_mfma_f32_16x16x32_bf16(*(const short8v*)&hl[lr][48 + lq * 4], bf3, ac, 0, 0, 0);
    float a2sv = a2s[w * 16 + lr];
    float a2dv = a2d[w * 16 + lr];
    #pragma unroll
    for (int reg = 0; reg < 4; ++reg){
        int r = lq * 4 + reg;
        int n = n0 + r;
        float v = ac[reg];
        if (n < N)
            xl2h[((size_t)br * N + n) * 64 + w * 16 + lr] = (unsigned short)f2bf(v);
        float ps = v * a2sv, pd = v * a2dv;
        ps += __shfl_xor(ps, 1, 64); ps += __shfl_xor(ps, 2, 64);
        ps += __shfl_xor(ps, 4, 64); ps += __shfl_xor(ps, 8, 64);
        pd += __shfl_xor(pd, 1, 64); pd += __shfl_xor(pd, 2, 64);
        pd += __shfl_xor(pd, 4, 64); pd += __shfl_xor(pd, 8, 64);
        if (lr == 0){ psa[w][r] = ps; pda[w][r] = pd; }
    }
    __syncthreads();
    if (tid < 16){
        int n = n0 + tid;
        if (n < N)
            es2[(size_t)br * N + n] = LOG2E * (psa[0][tid] + psa[1][tid] + psa[2][tid] + psa[3][tid]);
    } else if (tid < 32){
        int r = tid - 16;
        int n = n0 + r;
        if (n < N)
            ed2[(size_t)br * N + n] = LOG2E * (pda[0][r] + pda[1][r] + pda[2][r] + pda[3][r]);
    }
}

// Fused GAT2 aggregation + per-graph pooled sums. Full-row ushort gathers,
// shared edge-weight computation, scalar indices, 32-bit addressing.
__global__ __launch_bounds__(256) void a2pl_kernel(
    const unsigned short* __restrict__ xl2h, const float* __restrict__ es2, const float* __restrict__ ed2,
    const int* __restrict__ csr, const int* __restrict__ rs,
    const float* __restrict__ b2b, const float* __restrict__ b2t,
    const int* __restrict__ batchb, const int* __restrict__ batcht,
    float* __restrict__ pooled, int N, int E){
    int bid = blockIdx.x;
    int br = bid & 1;                 // branch parity == XCD parity class
    int tid = threadIdx.x, lane = tid & 63, w = tid >> 6;
    int n = ((bid >> 1) << 2) + w;
    const unsigned short* xlt = xl2h + (size_t)br * N * 64;
    const float* es = es2 + (size_t)br * N;
    const float* ed = ed2 + (size_t)br * N;
    const int* cs = csr + (size_t)br * E;
    const int* rsb = rs + (size_t)br * (N + 1);
    const float* b2 = br ? b2t : b2b;
    const int* batch = br ? batcht : batchb;
    float hv = 0.f;
    int g = -1;
    if (n < N){
        float edn = ed[n];
        float wself = exp2f(leaky02(es[n] + edn));
        float denom = wself;
        float acc = wself * bfs(xlt[(unsigned)(n * 64) + lane]);
        int beg = __builtin_amdgcn_readfirstlane(rsb[n]);
        int end = __builtin_amdgcn_readfirstlane(rsb[n + 1]);
        int j = beg;
        for (; j + 8 <= end; j += 8){
            int svec = cs[j + (lane & 7)];
            float ev = es[svec];
            float wmine = exp2f(leaky02(ev + edn));
            int ss[8]; float vv[8], wq[8];
            #pragma unroll
            for (int q = 0; q < 8; ++q) ss[q] = __builtin_amdgcn_readfirstlane(cs[j + q]);
            #pragma unroll
            for (int q = 0; q < 8; ++q) vv[q] = bfs(xlt[(unsigned)(ss[q] * 64) + lane]);
            #pragma unroll
            for (int q = 0; q < 8; ++q) wq[q] = __shfl(wmine, q, 64);
            #pragma unroll
            for (int q = 0; q < 8; ++q){
                denom += wq[q];
                acc += wq[q] * vv[q];
            }
        }
        for (; j < end; ++j){
            int s = __builtin_amdgcn_readfirstlane(cs[j]);
            float wqv = exp2f(leaky02(es[s] + edn));
            denom += wqv;
            acc += wqv * bfs(xlt[(unsigned)(s * 64) + lane]);
        }
        hv = elu1(acc / denom + b2[lane]);
        g = batch[n];
    }
    __shared__ float red[4][64];
    __shared__ int gid[4];
    red[w][lane] = hv;
    if (lane == 0) gid[w] = g;
    __syncthreads();
    if (w == 0){
        int g0 = gid[0], g1 = gid[1], g2 = gid[2], g3 = gid[3];
        float* pb = pooled + (size_t)br * 4096;
        if (g0 >= 0 && g0 == g1 && g1 == g2 && g2 == g3){
            float s = (red[0][lane] + red[1][lane]) + (red[2][lane] + red[3][lane]);
            atomicAdd(&pb[g0 * 64 + lane], s);
        } else {
            #pragma unroll
            for (int q = 0; q < 4; ++q)
                if (gid[q] >= 0) atomicAdd(&pb[gid[q] * 64 + lane], red[q][lane]);
        }
    }
}

// counts (binary search on sorted batch) + branch MLPs + combine + final head
__global__ __launch_bounds__(1024) void tail_kernel(
    const float* __restrict__ pooled,
    const int* __restrict__ batchb, const int* __restrict__ batcht,
    const float* __restrict__ M1wb, const float* __restrict__ M1bb,
    const float* __restrict__ M2wb, const float* __restrict__ M2bb,
    const float* __restrict__ M1wt, const float* __restrict__ M1bt,
    const float* __restrict__ M2wt, const float* __restrict__ M2bt,
    const float* __restrict__ Fw1, const float* __restrict__ Fb1,
    const float* __restrict__ Fw2, const float* __restrict__ Fb2,
    float* __restrict__ out, int N){
    __shared__ float P[8192];
    __shared__ float H[8192];
    __shared__ float cl[128];
    int t = threadIdx.x;
    if (t < 128){
        int br = t >> 6, g = t & 63;
        const int* batch = br ? batcht : batchb;
        int lo = 0, hi = N;
        while (lo < hi){ int mid = (lo + hi) >> 1; if (batch[mid] < g) lo = mid + 1; else hi = mid; }
        int beg = lo;
        hi = N;
        while (lo < hi){ int mid = (lo + hi) >> 1; if (batch[mid] < g + 1) lo = mid + 1; else hi = mid; }
        cl[t] = (float)(lo - beg);
    }
    __syncthreads();
    for (int i = t; i < 8192; i += 1024)
        P[i] = pooled[i] / fmaxf(cl[i >> 6], 1.f);
    __syncthreads();
    for (int i = t; i < 8192; i += 1024){
        int br = i >> 12, r = (i >> 6) & 63, c = i & 63;
        const float* M1w = br ? M1wt : M1wb;
        const float* M1b = br ? M1bt : M1bb;
        float acc = M1b[c];
        int pb = (br << 12) + (r << 6);
        #pragma unroll 8
        for (int k = 0; k < 64; ++k) acc += P[pb + k] * M1w[(k << 6) + c];
        H[i] = fmaxf(acc, 0.f);
    }
    __syncthreads();
    for (int i = t; i < 8192; i += 1024){
        int br = i >> 12, r = (i >> 6) & 63, c = i & 63;
        const float* M2w = br ? M2wt : M2wb;
        const float* M2b = br ? M2bt : M2bb;
        float acc = M2b[c];
        int hb = (br << 12) + (r << 6);
        #pragma unroll 8
        for (int k = 0; k < 64; ++k) acc += H[hb + k] * M2w[(k << 6) + c];
        P[i] = acc;
    }
    __syncthreads();
    for (int i = t; i < 4096; i += 1024) H[i] = P[i] * P[4096 + i];
    __syncthreads();
    for (int i = t; i < 4096; i += 1024){
        int r = i >> 6, c = i & 63;
        float acc = Fb1[c];
        #pragma unroll 8
        for (int k = 0; k < 64; ++k) acc += H[(r << 6) + k] * Fw1[(k << 6) + c];
        P[i] = fmaxf(acc, 0.f);
    }
    __syncthreads();
    if (t < 128){
        int r = t >> 1, jc = t & 1;
        float acc = Fb2[jc];
        #pragma unroll 8
        for (int k = 0; k < 64; ++k) acc += P[(r << 6) + k] * Fw2[k * 2 + jc];
        out[t] = tanhf(acc);
    }
}

extern "C" void kernel_launch(void* const* d_in, const int* in_sizes, int n_in,
                              void* d_out, int out_size, void* d_ws, size_t ws_size,
                              hipStream_t stream){
    const int N = in_sizes[0] / 2;
    const int E = in_sizes[1] / 2;
    const int NB = (N + 511) >> BSH;   // nodes-per-bucket = 512, NB <= 128

    char* ws = (char*)d_ws;
    size_t off = 0;
    auto alloc = [&](size_t bytes) -> char* {
        char* p = ws + off;
        off += (bytes + 255) & ~(size_t)255;
        return p;
    };
    unsigned* XL1u = (unsigned*)alloc((size_t)2 * N * 64 * 4);
    unsigned short* XL2h = (unsigned short*)alloc((size_t)2 * N * 64 * 2);  // EPAIR aliases this
    float* ES1 = (float*)alloc((size_t)2 * N * 2 * 4);
    float* ED1 = (float*)alloc((size_t)2 * N * 2 * 4);
    float* ES2 = (float*)alloc((size_t)2 * N * 4);
    float* ED2 = (float*)alloc((size_t)2 * N * 4);
    int* RS  = (int*)alloc((size_t)2 * (N + 1) * 4);
    int* CSR = (int*)alloc((size_t)2 * E * 4);
    int* BCUR = (int*)alloc((size_t)2 * NB * 4);
    float* POOLED = (float*)alloc(8192 * 4);
    unsigned short* W2T = (unsigned short*)alloc(2 * 8192 * 2);
    unsigned* EPAIR = (unsigned*)XL2h;   // 2*NB*ARENA*4 <= 2*N*128 bytes; dead after csr

    const float* xb   = (const float*)d_in[0];
    const int*   eib  = (const int*)  d_in[1];
    const int*   batchb = (const int*)d_in[2];
    const float* W1b  = (const float*)d_in[3];
    const float* a1sb = (const float*)d_in[4];
    const float* a1db = (const float*)d_in[5];
    const float* b1b  = (const float*)d_in[6];
    const float* W2b  = (const float*)d_in[7];
    const float* a2sb = (const float*)d_in[8];
    const float* a2db = (const float*)d_in[9];
    const float* b2b  = (const float*)d_in[10];
    const float* M1wb = (const float*)d_in[11];
    const float* M1bb = (const float*)d_in[12];
    const float* M2wb = (const float*)d_in[13];
    const float* M2bb = (const float*)d_in[14];
    const float* xt   = (const float*)d_in[15];
    const int*   eit  = (const int*)  d_in[16];
    const int*   batcht = (const int*)d_in[17];
    const float* W1t  = (const float*)d_in[18];
    const float* a1st = (const float*)d_in[19];
    const float* a1dt = (const float*)d_in[20];
    const float* b1t  = (const float*)d_in[21];
    const float* W2t  = (const float*)d_in[22];
    const float* a2st = (const float*)d_in[23];
    const float* a2dt = (const float*)d_in[24];
    const float* b2t  = (const float*)d_in[25];
    const float* M1wt = (const float*)d_in[26];
    const float* M1bt = (const float*)d_in[27];
    const float* M2wt = (const float*)d_in[28];
    const float* M2bt = (const float*)d_in[29];
    const float* Fw1  = (const float*)d_in[30];
    const float* Fb1  = (const float*)d_in[31];
    const float* Fw2  = (const float*)d_in[32];
    const float* Fb2  = (const float*)d_in[33];

    const int nodeBlocks = (N + 3) / 4;
    const int histBlocks = (E + CHUNK - 1) / CHUNK;
    const int tilesPer   = (N + 15) / 16;

    hipMemsetAsync(BCUR, 0, (size_t)2 * NB * 4, stream);
    preb_kernel<<<2 * histBlocks + 2 * nodeBlocks + 3, 256, 0, stream>>>(
        xb, xt, W1b, W1t, a1sb, a1st, a1db, a1dt, eib, eit, W2b, W2t,
        XL1u, ES1, ED1, BCUR, EPAIR, W2T, POOLED, N, E, NB, nodeBlocks, histBlocks);
    csr_kernel<<<2 * NB, 256, 0, stream>>>(BCUR, EPAIR, RS, CSR, N, E, NB);
    a1f2_kernel<<<2 * tilesPer, 256, 0, stream>>>(
        XL1u, ES1, ED1, CSR, RS, b1b, b1t, W2T,
        a2sb, a2st, a2db, a2dt, XL2h, ES2, ED2, N, E);
    a2pl_kernel<<<2 * nodeBlocks, 256, 0, stream>>>(
        XL2h, ES2, ED2, CSR, RS, b2b, b2t, batchb, batcht, POOLED, N, E);
    tail_kernel<<<1, 1024, 0, stream>>>(POOLED, batchb, batcht,
        M1wb, M1bb, M2wb, M2bb, M1wt, M1bt, M2wt, M2bt,
        Fw1, Fb1, Fw2, Fb2, (float*)d_out, N);
}